// Round 6
// baseline (1031.740 us; speedup 1.0000x reference)
//
#include <hip/hip_runtime.h>
#include <hip/hip_bf16.h>

typedef __hip_bfloat16 bf16;
typedef __attribute__((ext_vector_type(8))) short bfrag8;   // 8 bf16 (4 VGPR) MFMA A/B frag
typedef __attribute__((ext_vector_type(4))) float facc4;    // MFMA C/D frag
typedef __attribute__((ext_vector_type(4))) unsigned short us4;
typedef __attribute__((ext_vector_type(8))) unsigned short us8;
typedef __attribute__((ext_vector_type(4))) float f32x4;    // true clang vector (for nontemporal)

#define AS1C const __attribute__((address_space(1))) void
#define AS3  __attribute__((address_space(3))) void

__device__ __forceinline__ void gload_lds16(const void* src, void* dst) {
    __builtin_amdgcn_global_load_lds((AS1C*)src, (AS3*)dst, 16, 0, 0);
}

__device__ __forceinline__ unsigned short f2bf(float f) {   // RNE, finite inputs
    unsigned u = __float_as_uint(f);
    unsigned r = u + 0x7FFFu + ((u >> 16) & 1u);
    return (unsigned short)(r >> 16);
}

// ------- merged prep+cvt kernel: pe | xin | wemb | whead | all weight cvt -------
// bid [0,512): pe | [512,4608): xin | [4608,5632): wemb | [5632,6272): whead
// bid [6272,8576): weight fp32->bf16, 384 blocks/layer (192 qkv, 64 wo/w1/w2),
//   thread converts 8 float4-PAIRS (16B nontemporal loads, 16B us8 stores) for ILP.
__global__ void prep_cvt_kernel(const float* __restrict__ input, const float* __restrict__ targets,
                                const float* __restrict__ sos, const float* __restrict__ W_emb,
                                const float* __restrict__ Wm, const float* __restrict__ Wpi_m,
                                const float* __restrict__ Wmu_m, const float* __restrict__ Wsg_m,
                                const float* __restrict__ Wpi_v, const float* __restrict__ Wmu_v,
                                const float* __restrict__ Wsg_v,
                                const float* __restrict__ bm, const float* __restrict__ bpi_m,
                                const float* __restrict__ bmu_m, const float* __restrict__ bsg_m,
                                const float* __restrict__ bpi_v, const float* __restrict__ bmu_v,
                                const float* __restrict__ bsg_v,
                                const float* __restrict__ Wqkv, const float* __restrict__ Wo,
                                const float* __restrict__ W1, const float* __restrict__ W2,
                                float* __restrict__ pe, bf16* __restrict__ xin,
                                bf16* __restrict__ wemb, bf16* __restrict__ whead,
                                float* __restrict__ bhead,
                                bf16* __restrict__ wqb, bf16* __restrict__ wob,
                                bf16* __restrict__ w1b, bf16* __restrict__ w2b) {
    int bid = blockIdx.x;
    if (bid < 512) {                                     // pe [128][1024]
        int idx = bid * 256 + threadIdx.x;
        int s = idx >> 10, c = idx & 1023;
        int i = c >> 1;
        float div = expf(-9.210340371976184f * (float)(2 * i) * (1.f / 1024.f));
        float a = (float)s * div;
        pe[idx] = (c & 1) ? cosf(a) : sinf(a);
    } else if (bid < 512 + 4096) {                       // xin row (b*128+s), pad K->576
        int row = bid - 512;
        int b = row >> 7, s = row & 127;
        for (int c = threadIdx.x; c < 576; c += 256) {
            float v = 0.f;
            if (c < 512) v = input[b * 512 + c];
            else if (c < 545) {
                int j = c - 512;
                v = (s == 0) ? sos[j] : targets[((size_t)b * 127 + (s - 1)) * 33 + j];
            }
            xin[(size_t)row * 576 + c] = __float2bfloat16(v);
        }
    } else if (bid < 512 + 4096 + 1024) {                // wemb row, pad 545->576
        int row = bid - (512 + 4096);
        for (int c = threadIdx.x; c < 576; c += 256)
            wemb[(size_t)row * 576 + c] = __float2bfloat16(c < 545 ? W_emb[(size_t)row * 545 + c] : 0.f);
    } else if (bid < 6272) {                             // whead row (640 = 529 real + pad)
        int r = bid - (512 + 4096 + 1024);
        const float* wsrc = nullptr; const float* bsrc = nullptr; int off = 0;
        if (r == 0)        { wsrc = Wm;    bsrc = bm;    off = 0; }
        else if (r < 9)    { wsrc = Wpi_m; bsrc = bpi_m; off = r - 1; }
        else if (r < 137)  { wsrc = Wmu_m; bsrc = bmu_m; off = r - 9; }
        else if (r < 265)  { wsrc = Wsg_m; bsrc = bsg_m; off = r - 137; }
        else if (r < 273)  { wsrc = Wpi_v; bsrc = bpi_v; off = r - 265; }
        else if (r < 401)  { wsrc = Wmu_v; bsrc = bmu_v; off = r - 273; }
        else if (r < 529)  { wsrc = Wsg_v; bsrc = bsg_v; off = r - 401; }
        for (int c = threadIdx.x; c < 1024; c += 256)
            whead[(size_t)r * 1024 + c] = __float2bfloat16(wsrc ? wsrc[(size_t)off * 1024 + c] : 0.f);
        if (threadIdx.x == 0 && wsrc) bhead[r] = bsrc[off];
    } else {                                             // weight cvt
        int bid2 = bid - 6272;                           // [0,2304)
        int l = bid2 / 384;
        int s = bid2 - l * 384;
        const float* src; bf16* dst;
        if (s < 192)      { src = Wqkv + (size_t)l * 3145728; dst = wqb + (size_t)l * 3145728; }
        else if (s < 256) { src = Wo + (size_t)l * 1048576; dst = wob + (size_t)l * 1048576; s -= 192; }
        else if (s < 320) { src = W1 + (size_t)l * 1048576; dst = w1b + (size_t)l * 1048576; s -= 256; }
        else              { src = W2 + (size_t)l * 1048576; dst = w2b + (size_t)l * 1048576; s -= 320; }
        size_t pbase = (size_t)s * 2048 + threadIdx.x;
#pragma unroll
        for (int it = 0; it < 8; ++it) {
            size_t o = (pbase + it * 256) * 8;           // 8 floats per pair
            const f32x4* p = (const f32x4*)(src + o);
            f32x4 v1 = __builtin_nontemporal_load(p);
            f32x4 v2 = __builtin_nontemporal_load(p + 1);
            us8 w8;
            w8[0] = f2bf(v1.x); w8[1] = f2bf(v1.y); w8[2] = f2bf(v1.z); w8[3] = f2bf(v1.w);
            w8[4] = f2bf(v2.x); w8[5] = f2bf(v2.y); w8[6] = f2bf(v2.z); w8[7] = f2bf(v2.w);
            *(us8*)(dst + o) = w8;
        }
    }
}

// ---------------- main GEMM: C[M,N] = A[M,K] @ B[N,K]^T (+epilogue) ----------------
// 128x128 tile, BK=64, 4 waves. Operand-swapped MFMA (C^T frags -> vectorized epilogue).
// DBUF=1: 2-deep counted-vmcnt pipeline (raw s_barrier, vmcnt(8) not 0 -> tile k+2's
//         loads stay in flight across barriers; T4 mechanism, m218/m233).
// DBUF=0: single-buffer, 3 blocks/CU (cross-block overlap regime) for QKV (768 blocks).
// EPI: 0 bias->bf16 | 1 bias+relu->bf16 | 2 bias+res->f32 | 3 bias->f32 scalar | 4 bias+pe->f32+bf16
template<int EPI, int DBUF>
__global__ __launch_bounds__(256, DBUF ? 2 : 3) void gemm_bt(
    const bf16* __restrict__ A, const bf16* __restrict__ Bw,
    float* __restrict__ Cf, bf16* __restrict__ Cb,
    const float* __restrict__ bias, const float* __restrict__ res, const float* __restrict__ pe,
    int M, int N, int K, int lda, int ldb, int ldc, long long Az, long long Cz)
{
    __shared__ __align__(16) bf16 sA[DBUF ? 2 : 1][128 * 64];
    __shared__ __align__(16) bf16 sB[DBUF ? 2 : 1][128 * 64];
    const int t = threadIdx.x;
    const int w = t >> 6, la = t & 63;
    const int wm = (w >> 1) * 64, wn = (w & 1) * 64;
    const int m0 = blockIdx.y * 128, n0 = blockIdx.x * 128;
    const int z = blockIdx.z;
    A += (long long)z * Az;

    const int c0 = w * 64 + la;
    facc4 zero4 = {0.f, 0.f, 0.f, 0.f};
    facc4 acc[4][4];
#pragma unroll
    for (int mi = 0; mi < 4; ++mi)
#pragma unroll
        for (int ni = 0; ni < 4; ++ni) acc[mi][ni] = zero4;

    auto stage = [&](int buf, int kt) {                 // 8 gload_lds (4 A + 4 B)
#pragma unroll
        for (int i = 0; i < 4; ++i) {
            int c = i * 256 + c0;
            int r = c >> 3;
            int bc = ((c & 7) * 16) ^ ((r & 7) << 4);   // pre-swizzled source byte col
            gload_lds16(A + (size_t)(m0 + r) * lda + kt + (bc >> 1),
                        (char*)sA[buf] + (size_t)(i * 256 + c0) * 16);
            gload_lds16(Bw + (size_t)(n0 + r) * ldb + kt + (bc >> 1),
                        (char*)sB[buf] + (size_t)(i * 256 + c0) * 16);
        }
    };
    auto compute = [&](int buf) {
#pragma unroll
        for (int ks = 0; ks < 2; ++ks) {
            bfrag8 af[4], bfv[4];
            const int koffb = (ks * 32 + (la >> 4) * 8) * 2;
#pragma unroll
            for (int i = 0; i < 4; ++i) {
                int rowa = wm + i * 16 + (la & 15);
                af[i] = *(const bfrag8*)((const char*)sA[buf] + rowa * 128 + (koffb ^ ((rowa & 7) << 4)));
                int rowb = wn + i * 16 + (la & 15);
                bfv[i] = *(const bfrag8*)((const char*)sB[buf] + rowb * 128 + (koffb ^ ((rowb & 7) << 4)));
            }
#pragma unroll
            for (int mi = 0; mi < 4; ++mi)
#pragma unroll
                for (int ni = 0; ni < 4; ++ni)     // swapped operands -> C^T fragment
                    acc[mi][ni] = __builtin_amdgcn_mfma_f32_16x16x32_bf16(bfv[ni], af[mi], acc[mi][ni], 0, 0, 0);
        }
    };

    const int nk = K >> 6;
    if constexpr (DBUF) {
        // 2-deep counted pipeline: outstanding 16 loads steady-state; vmcnt(8)
        // retires exactly the compute-tile's 8. stage(kt+2) only after the second
        // barrier (its buffer freed); "memory"-clobbered asm + sched_barrier(0)
        // pin ordering (rule #18).
        stage(0, 0);
        if (nk > 1) stage(1, 64);
        for (int kt = 0; kt < nk; ++kt) {
            if (kt + 1 < nk) { asm volatile("s_waitcnt vmcnt(8)" ::: "memory"); }
            else             { asm volatile("s_waitcnt vmcnt(0)" ::: "memory"); }
            __builtin_amdgcn_sched_barrier(0);
            __builtin_amdgcn_s_barrier();               // everyone's tile-kt loads landed
            __builtin_amdgcn_sched_barrier(0);
            compute(kt & 1);
            __builtin_amdgcn_sched_barrier(0);
            __builtin_amdgcn_s_barrier();               // everyone done reading buf kt&1
            __builtin_amdgcn_sched_barrier(0);
            if (kt + 2 < nk) stage(kt & 1, (kt + 2) << 6);
        }
    } else {
        for (int kt = 0; kt < nk; ++kt) {
            stage(0, kt << 6);
            __syncthreads();
            compute(0);
            __syncthreads();
        }
    }
    // epilogue: thread holds C[row][colb..colb+3]
#pragma unroll
    for (int mi = 0; mi < 4; ++mi) {
        int row = m0 + wm + mi * 16 + (la & 15);
#pragma unroll
        for (int ni = 0; ni < 4; ++ni) {
            int colb = n0 + wn + ni * 16 + (la >> 4) * 4;
            if constexpr (EPI == 3) {               // scalar path (odd ldc / edge guards)
                if (row >= M) continue;
#pragma unroll
                for (int j = 0; j < 4; ++j) {
                    int col = colb + j;
                    if (col < N)
                        Cf[(size_t)z * Cz + (size_t)row * ldc + col] = acc[mi][ni][j] + bias[col];
                }
            } else {
                float4 bv = *(const float4*)(bias + colb);
                facc4 v = acc[mi][ni];
                v[0] += bv.x; v[1] += bv.y; v[2] += bv.z; v[3] += bv.w;
                size_t cidx = (size_t)row * ldc + colb;
                if constexpr (EPI == 0) {
                    us4 o; o.x = f2bf(v[0]); o.y = f2bf(v[1]); o.z = f2bf(v[2]); o.w = f2bf(v[3]);
                    *(us4*)(Cb + cidx) = o;
                } else if constexpr (EPI == 1) {
                    us4 o;
                    o.x = f2bf(v[0] > 0.f ? v[0] : 0.f); o.y = f2bf(v[1] > 0.f ? v[1] : 0.f);
                    o.z = f2bf(v[2] > 0.f ? v[2] : 0.f); o.w = f2bf(v[3] > 0.f ? v[3] : 0.f);
                    *(us4*)(Cb + cidx) = o;
                } else if constexpr (EPI == 2) {
                    float4 r = *(const float4*)(res + cidx);
                    float4 o = {v[0] + r.x, v[1] + r.y, v[2] + r.z, v[3] + r.w};
                    *(float4*)(Cf + cidx) = o;
                } else {                            // EPI == 4
                    float4 p = *(const float4*)(pe + (size_t)(row & 127) * 1024 + colb);
                    float4 o = {v[0] + p.x, v[1] + p.y, v[2] + p.z, v[3] + p.w};
                    *(float4*)(Cf + cidx) = o;
                    us4 ob;
                    ob.x = f2bf(o.x); ob.y = f2bf(o.y); ob.z = f2bf(o.z); ob.w = f2bf(o.w);
                    *(us4*)(Cb + cidx) = ob;
                }
            }
        }
    }
}

// ---------------- fused attention: one block per (b,h) ----------------
// S=128, D=64. QK^T -> causal softmax (fp32 math, bf16 storage) -> PV. 64KB LDS.
// Operand-swapped MFMA throughout: packed 8B S-writes and O-stores.
__global__ __launch_bounds__(256) void attn_fused(const bf16* __restrict__ qkv, bf16* __restrict__ obf)
{
    __shared__ __align__(16) char lds[65536];
    char* sQ  = lds;            // [128] rows x 128B, swizzled
    char* sK  = lds + 16384;    // [128] rows x 128B
    char* sS  = lds + 32768;    // [128] rows x 256B bf16 (scores, then P)
    char* sVT = lds;            // [64] rows x 256B (V transposed), overlaps sQ

    const int t = threadIdx.x, w = t >> 6, la = t & 63;
    const int b = blockIdx.x >> 4, h = blockIdx.x & 15;
    const size_t base = (size_t)b * 128 * 3072 + (size_t)h * 64;

    // phase 1: stage Q, K (swizzled via pre-swizzled source)
#pragma unroll
    for (int i = 0; i < 4; ++i) {
        int c = i * 256 + w * 64 + la;
        int r = c >> 3;
        int bc = ((c & 7) * 16) ^ ((r & 7) << 4);
        gload_lds16(qkv + base + (size_t)r * 3072 + (bc >> 1),
                    sQ + (size_t)(i * 256 + w * 64) * 16);
        gload_lds16(qkv + base + 1024 + (size_t)r * 3072 + (bc >> 1),
                    sK + (size_t)(i * 256 + w * 64) * 16);
    }
    __syncthreads();

    // phase 2: S = Q K^T * 0.125 (swapped mfma -> thread holds S[q][kb..kb+3])
    const int wm = (w >> 1) * 64, wn = (w & 1) * 64;
    facc4 zero4 = {0.f, 0.f, 0.f, 0.f};
    {
        facc4 acc[4][4];
#pragma unroll
        for (int mi = 0; mi < 4; ++mi)
#pragma unroll
            for (int ni = 0; ni < 4; ++ni) acc[mi][ni] = zero4;
#pragma unroll
        for (int ks = 0; ks < 2; ++ks) {
            bfrag8 af[4], bfv[4];
            const int koffb = (ks * 32 + (la >> 4) * 8) * 2;
#pragma unroll
            for (int i = 0; i < 4; ++i) {
                int rowa = wm + i * 16 + (la & 15);
                af[i] = *(const bfrag8*)(sQ + rowa * 128 + (koffb ^ ((rowa & 7) << 4)));
                int rowb = wn + i * 16 + (la & 15);
                bfv[i] = *(const bfrag8*)(sK + rowb * 128 + (koffb ^ ((rowb & 7) << 4)));
            }
#pragma unroll
            for (int mi = 0; mi < 4; ++mi)
#pragma unroll
                for (int ni = 0; ni < 4; ++ni)
                    acc[mi][ni] = __builtin_amdgcn_mfma_f32_16x16x32_bf16(bfv[ni], af[mi], acc[mi][ni], 0, 0, 0);
        }
#pragma unroll
        for (int mi = 0; mi < 4; ++mi) {
            int q = wm + mi * 16 + (la & 15);
#pragma unroll
            for (int ni = 0; ni < 4; ++ni) {
                int kb = wn + ni * 16 + (la >> 4) * 4;
                us4 sv;
                sv.x = f2bf(acc[mi][ni][0] * 0.125f); sv.y = f2bf(acc[mi][ni][1] * 0.125f);
                sv.z = f2bf(acc[mi][ni][2] * 0.125f); sv.w = f2bf(acc[mi][ni][3] * 0.125f);
                *(us4*)(sS + q * 256 + ((2 * kb) ^ ((q & 7) << 4))) = sv;
            }
        }
    }
    __syncthreads();

    // phase 3a: stage V transposed into sVT (sQ space, free now)
#pragma unroll
    for (int i = 0; i < 4; ++i) {
        int c = i * 256 + t;
        int r = c >> 3;             // key index s'
        int d0 = (c & 7) * 8;
        bfrag8 vv = *(const bfrag8*)(qkv + base + 2048 + (size_t)r * 3072 + d0);
#pragma unroll
        for (int j = 0; j < 8; ++j) {
            int d = d0 + j;
            *(short*)(sVT + d * 256 + ((2 * r) ^ ((d & 7) << 4))) = vv[j];
        }
    }
    // phase 3b: causal softmax, in place on sS (wave w owns rows w*32..w*32+31)
    for (int ri = 0; ri < 32; ++ri) {
        int r = w * 32 + ri;
        int c1 = la, c2 = la + 64;
        float v1 = (c1 <= r) ? __bfloat162float(*(const bf16*)(sS + r * 256 + ((2 * c1) ^ ((r & 7) << 4)))) : -1e30f;
        float v2 = (c2 <= r) ? __bfloat162float(*(const bf16*)(sS + r * 256 + ((2 * c2) ^ ((r & 7) << 4)))) : -1e30f;
        float mx = fmaxf(v1, v2);
#pragma unroll
        for (int off = 32; off; off >>= 1) mx = fmaxf(mx, __shfl_xor(mx, off));
        float e1 = (c1 <= r) ? __expf(v1 - mx) : 0.f;
        float e2 = (c2 <= r) ? __expf(v2 - mx) : 0.f;
        float sm = e1 + e2;
#pragma unroll
        for (int off = 32; off; off >>= 1) sm += __shfl_xor(sm, off);
        float inv = 1.f / sm;
        *(bf16*)(sS + r * 256 + ((2 * c1) ^ ((r & 7) << 4))) = __float2bfloat16(e1 * inv);
        *(bf16*)(sS + r * 256 + ((2 * c2) ^ ((r & 7) << 4))) = __float2bfloat16(e2 * inv);
    }
    __syncthreads();

    // phase 4: O = P V  (wave tile 64M x 32N, K=128; swapped mfma -> packed O stores)
    const int wm2 = (w >> 1) * 64, wn2 = (w & 1) * 32;
    facc4 a2[4][2];
#pragma unroll
    for (int mi = 0; mi < 4; ++mi) { a2[mi][0] = zero4; a2[mi][1] = zero4; }
#pragma unroll
    for (int ks = 0; ks < 4; ++ks) {
        bfrag8 pa[4], vb[2];
        const int koffb = (ks * 32 + (la >> 4) * 8) * 2;
#pragma unroll
        for (int mi = 0; mi < 4; ++mi) {
            int rowa = wm2 + mi * 16 + (la & 15);
            pa[mi] = *(const bfrag8*)(sS + rowa * 256 + (koffb ^ ((rowa & 7) << 4)));
        }
#pragma unroll
        for (int ni = 0; ni < 2; ++ni) {
            int rowb = wn2 + ni * 16 + (la & 15);
            vb[ni] = *(const bfrag8*)(sVT + rowb * 256 + (koffb ^ ((rowb & 7) << 4)));
        }
#pragma unroll
        for (int mi = 0; mi < 4; ++mi)
#pragma unroll
            for (int ni = 0; ni < 2; ++ni)
                a2[mi][ni] = __builtin_amdgcn_mfma_f32_16x16x32_bf16(vb[ni], pa[mi], a2[mi][ni], 0, 0, 0);
    }
#pragma unroll
    for (int mi = 0; mi < 4; ++mi) {
        int s = wm2 + mi * 16 + (la & 15);
#pragma unroll
        for (int ni = 0; ni < 2; ++ni) {
            int db = wn2 + ni * 16 + (la >> 4) * 4;
            us4 ov;
            ov.x = f2bf(a2[mi][ni][0]); ov.y = f2bf(a2[mi][ni][1]);
            ov.z = f2bf(a2[mi][ni][2]); ov.w = f2bf(a2[mi][ni][3]);
            *(us4*)(obf + ((size_t)(b * 128 + s)) * 1024 + h * 64 + db) = ov;
        }
    }
}

// ---------------- LayerNorm (one block per row of 1024) ----------------
__global__ __launch_bounds__(256) void ln_kernel(const float* __restrict__ in, const float* __restrict__ g,
                                                 const float* __restrict__ be,
                                                 float* __restrict__ outf, bf16* __restrict__ outb)
{
    const int row = blockIdx.x, t = threadIdx.x;
    const float* x = in + (size_t)row * 1024;
    float4 v = *(const float4*)(x + t * 4);
    float s = v.x + v.y + v.z + v.w;
    float q = v.x * v.x + v.y * v.y + v.z * v.z + v.w * v.w;
#pragma unroll
    for (int off = 32; off; off >>= 1) {
        s += __shfl_xor(s, off);
        q += __shfl_xor(q, off);
    }
    __shared__ float ssum[4], sqs[4];
    if ((t & 63) == 0) { ssum[t >> 6] = s; sqs[t >> 6] = q; }
    __syncthreads();
    s = ssum[0] + ssum[1] + ssum[2] + ssum[3];
    q = sqs[0] + sqs[1] + sqs[2] + sqs[3];
    float mean = s * (1.f / 1024.f);
    float var = q * (1.f / 1024.f) - mean * mean;
    float rstd = rsqrtf(var + 1e-5f);
    float4 gv = *(const float4*)(g + t * 4);
    float4 bv = *(const float4*)(be + t * 4);
    size_t o = (size_t)row * 1024 + t * 4;
    float o0 = (v.x - mean) * rstd * gv.x + bv.x;
    float o1 = (v.y - mean) * rstd * gv.y + bv.y;
    float o2 = (v.z - mean) * rstd * gv.z + bv.z;
    float o3 = (v.w - mean) * rstd * gv.w + bv.w;
    float4 of = {o0, o1, o2, o3};
    *(float4*)(outf + o) = of;
    us4 obv; obv.x = f2bf(o0); obv.y = f2bf(o1); obv.z = f2bf(o2); obv.w = f2bf(o3);
    *(us4*)(outb + o) = obv;
}

// ---------------- MDN finalize / scatter ----------------
__global__ void finalize_kernel(const float* __restrict__ hout, float* __restrict__ out) {
    const size_t O_PI_M = 0, O_MU_M = 32512, O_VAR_M = 552704, O_PI_V = 1072896,
                 O_MU_V = 1105408, O_VAR_V = 1625600, O_MASK = 2145792;
    int rm = blockIdx.x;                    // b*127+m, 4064 rows
    const float* hrow = hout + (size_t)rm * 529;
    int t = threadIdx.x;
    if (t < 128) {
        out[O_MU_M  + (size_t)rm * 128 + t] = hrow[9 + t];
        out[O_VAR_M + (size_t)rm * 128 + t] = expf(hrow[137 + t]);
        out[O_MU_V  + (size_t)rm * 128 + t] = hrow[273 + t];
        out[O_VAR_V + (size_t)rm * 128 + t] = expf(hrow[401 + t]);
    } else if (t == 128) {
        out[O_MASK + rm] = hrow[0];
    } else if (t == 129 || t == 130) {
        int boff = (t == 129) ? 1 : 265;
        size_t oo = ((t == 129) ? O_PI_M : O_PI_V) + (size_t)rm * 8;
        float v[8], mx = -1e30f;
#pragma unroll
        for (int j = 0; j < 8; ++j) { v[j] = hrow[boff + j]; mx = fmaxf(mx, v[j]); }
        float sm = 0.f;
#pragma unroll
        for (int j = 0; j < 8; ++j) { v[j] = expf(v[j] - mx); sm += v[j]; }
        float inv = 1.f / sm;
#pragma unroll
        for (int j = 0; j < 8; ++j) out[oo + j] = v[j] * inv;
    }
}

// ---------------- launcher ----------------
extern "C" void kernel_launch(void* const* d_in, const int* in_sizes, int n_in,
                              void* d_out, int out_size, void* d_ws, size_t ws_size,
                              hipStream_t stream) {
    (void)in_sizes; (void)n_in; (void)out_size; (void)ws_size;
    const float* input   = (const float*)d_in[0];
    const float* targets = (const float*)d_in[1];
    const float* W_emb   = (const float*)d_in[2];
    const float* b_emb   = (const float*)d_in[3];
    const float* sos     = (const float*)d_in[4];
    const float* Wqkv    = (const float*)d_in[5];
    const float* bqkv    = (const float*)d_in[6];
    const float* Wo      = (const float*)d_in[7];
    const float* bo      = (const float*)d_in[8];
    const float* W1      = (const float*)d_in[9];
    const float* b1      = (const float*)d_in[10];
    const float* W2      = (const float*)d_in[11];
    const float* b2      = (const float*)d_in[12];
    const float* g1      = (const float*)d_in[13];
    const float* be1     = (const float*)d_in[14];
    const float* g2      = (const float*)d_in[15];
    const float* be2     = (const float*)d_in[16];
    const float* Wm      = (const float*)d_in[17];
    const float* bm      = (const float*)d_in[18];
    const float* Wpi_m   = (const float*)d_in[19];
    const float* bpi_m   = (const float*)d_in[20];
    const float* Wmu_m   = (const float*)d_in[21];
    const float* bmu_m   = (const float*)d_in[22];
    const float* Wsg_m   = (const float*)d_in[23];
    const float* bsg_m   = (const float*)d_in[24];
    const float* Wpi_v   = (const float*)d_in[25];
    const float* bpi_v   = (const float*)d_in[26];
    const float* Wmu_v   = (const float*)d_in[27];
    const float* bmu_v   = (const float*)d_in[28];
    const float* Wsg_v   = (const float*)d_in[29];
    const float* bsg_v   = (const float*)d_in[30];
    float* out = (float*)d_out;

    char* ws = (char*)d_ws;                            // ~167 MB total
    float* pe      = (float*)(ws + 0);                 // 0.5 MB
    bf16*  xin     = (bf16*)(ws + 524288);             // 4.72 MB
    bf16*  wemb    = (bf16*)(ws + 5242880);            // 1.18 MB
    bf16*  whead   = (bf16*)(ws + 6422528);            // 1.31 MB (640 rows)
    float* bhead   = (float*)(ws + 7733248);           // 2.5 KB
    float* xf      = (float*)(ws + 7735808);           // 16.8 MB
    bf16*  xb      = (bf16*)(ws + 24513024);           // 8.4 MB
    bf16*  qkvb    = (bf16*)(ws + 32901632);           // 25.2 MB
    bf16*  ob      = (bf16*)(ws + 58067456);           // 8.4 MB (attn out, reused as FF hidden)
    float* tmp     = (float*)(ws + 66456064);          // 16.8 MB
    bf16*  wqb_all = (bf16*)(ws + 83233280);           // 37.7 MB (6 layers)
    bf16*  wob_all = (bf16*)(ws + 120982016);          // 12.6 MB
    bf16*  w1b_all = (bf16*)(ws + 133564928);          // 12.6 MB
    bf16*  w2b_all = (bf16*)(ws + 146147840);          // 12.6 MB
    float* hout    = (float*)(ws + 158730752);         // 8.6 MB

    prep_cvt_kernel<<<8576, 256, 0, stream>>>(input, targets, sos, W_emb,
                                              Wm, Wpi_m, Wmu_m, Wsg_m, Wpi_v, Wmu_v, Wsg_v,
                                              bm, bpi_m, bmu_m, bsg_m, bpi_v, bmu_v, bsg_v,
                                              Wqkv, Wo, W1, W2,
                                              pe, xin, wemb, whead, bhead,
                                              wqb_all, wob_all, w1b_all, w2b_all);
    // x = XIN @ Wemb^T + b + pe   -> xf (f32) + xb (bf16)
    gemm_bt<4, 1><<<dim3(8, 32, 1), 256, 0, stream>>>(xin, wemb, xf, xb, b_emb, nullptr, pe,
                                                      4096, 1024, 576, 576, 576, 1024, 0, 0);
    for (int l = 0; l < 6; ++l) {
        const bf16* wqb = wqb_all + (size_t)l * 3145728;
        const bf16* wob = wob_all + (size_t)l * 1048576;
        const bf16* w1b = w1b_all + (size_t)l * 1048576;
        const bf16* w2b = w2b_all + (size_t)l * 1048576;
        // qkv = x @ Wqkv^T + b  (bf16 out) -- 768 blocks, single-buffer, 3 blocks/CU
        gemm_bt<0, 0><<<dim3(24, 32, 1), 256, 0, stream>>>(xb, wqb, nullptr, qkvb, bqkv + l * 3072,
                                                           nullptr, nullptr, 4096, 3072, 1024, 1024, 1024, 3072, 0, 0);
        attn_fused<<<512, 256, 0, stream>>>(qkvb, ob);
        // tmp = x + o @ Wo^T + bo -- 256 blocks, counted-dbuf pipeline
        gemm_bt<2, 1><<<dim3(8, 32, 1), 256, 0, stream>>>(ob, wob, tmp, nullptr, bo + l * 1024,
                                                          xf, nullptr, 4096, 1024, 1024, 1024, 1024, 1024, 0, 0);
        ln_kernel<<<4096, 256, 0, stream>>>(tmp, g1 + l * 1024, be1 + l * 1024, xf, xb);
        // t1 = relu(x @ W1^T + b1) (bf16, reuse ob)
        gemm_bt<1, 1><<<dim3(8, 32, 1), 256, 0, stream>>>(xb, w1b, nullptr, ob, b1 + l * 1024,
                                                          nullptr, nullptr, 4096, 1024, 1024, 1024, 1024, 1024, 0, 0);
        // tmp = x + t1 @ W2^T + b2
        gemm_bt<2, 1><<<dim3(8, 32, 1), 256, 0, stream>>>(ob, w2b, tmp, nullptr, b2 + l * 1024,
                                                          xf, nullptr, 4096, 1024, 1024, 1024, 1024, 1024, 0, 0);
        ln_kernel<<<4096, 256, 0, stream>>>(tmp, g2 + l * 1024, be2 + l * 1024, xf, xb);
    }
    // heads: per-batch M=127 rows of x -> hout (B,127,529) -- 160 blocks, counted-dbuf
    gemm_bt<3, 1><<<dim3(5, 1, 32), 256, 0, stream>>>(xb, whead, hout, nullptr, bhead, nullptr, nullptr,
                                                      127, 529, 1024, 1024, 1024, 529, 131072LL, 67183LL);
    finalize_kernel<<<4064, 256, 0, stream>>>(hout, out);
}

// Round 7
// 922.285 us; speedup vs baseline: 1.1187x; 1.1187x over previous
//
#include <hip/hip_runtime.h>
#include <hip/hip_bf16.h>

typedef __hip_bfloat16 bf16;
typedef __attribute__((ext_vector_type(8))) short bfrag8;   // 8 bf16 (4 VGPR) MFMA A/B frag
typedef __attribute__((ext_vector_type(4))) float facc4;    // MFMA C/D frag
typedef __attribute__((ext_vector_type(4))) unsigned short us4;
typedef __attribute__((ext_vector_type(8))) unsigned short us8;
typedef __attribute__((ext_vector_type(4))) float f32x4;    // true clang vector (for nontemporal)

#define AS1C const __attribute__((address_space(1))) void
#define AS3  __attribute__((address_space(3))) void

__device__ __forceinline__ void gload_lds16(const void* src, void* dst) {
    __builtin_amdgcn_global_load_lds((AS1C*)src, (AS3*)dst, 16, 0, 0);
}

__device__ __forceinline__ unsigned short f2bf(float f) {   // RNE, finite inputs
    unsigned u = __float_as_uint(f);
    unsigned r = u + 0x7FFFu + ((u >> 16) & 1u);
    return (unsigned short)(r >> 16);
}
__device__ __forceinline__ float bf2f(unsigned short u) {   // exact
    return __uint_as_float((unsigned)u << 16);
}

// ------- merged prep+cvt kernel: pe | xin | wemb | whead | all weight cvt -------
__global__ void prep_cvt_kernel(const float* __restrict__ input, const float* __restrict__ targets,
                                const float* __restrict__ sos, const float* __restrict__ W_emb,
                                const float* __restrict__ Wm, const float* __restrict__ Wpi_m,
                                const float* __restrict__ Wmu_m, const float* __restrict__ Wsg_m,
                                const float* __restrict__ Wpi_v, const float* __restrict__ Wmu_v,
                                const float* __restrict__ Wsg_v,
                                const float* __restrict__ bm, const float* __restrict__ bpi_m,
                                const float* __restrict__ bmu_m, const float* __restrict__ bsg_m,
                                const float* __restrict__ bpi_v, const float* __restrict__ bmu_v,
                                const float* __restrict__ bsg_v,
                                const float* __restrict__ Wqkv, const float* __restrict__ Wo,
                                const float* __restrict__ W1, const float* __restrict__ W2,
                                float* __restrict__ pe, bf16* __restrict__ xin,
                                bf16* __restrict__ wemb, bf16* __restrict__ whead,
                                float* __restrict__ bhead,
                                bf16* __restrict__ wqb, bf16* __restrict__ wob,
                                bf16* __restrict__ w1b, bf16* __restrict__ w2b) {
    int bid = blockIdx.x;
    if (bid < 512) {                                     // pe [128][1024]
        int idx = bid * 256 + threadIdx.x;
        int s = idx >> 10, c = idx & 1023;
        int i = c >> 1;
        float div = expf(-9.210340371976184f * (float)(2 * i) * (1.f / 1024.f));
        float a = (float)s * div;
        pe[idx] = (c & 1) ? cosf(a) : sinf(a);
    } else if (bid < 512 + 4096) {                       // xin row (b*128+s), pad K->576
        int row = bid - 512;
        int b = row >> 7, s = row & 127;
        for (int c = threadIdx.x; c < 576; c += 256) {
            float v = 0.f;
            if (c < 512) v = input[b * 512 + c];
            else if (c < 545) {
                int j = c - 512;
                v = (s == 0) ? sos[j] : targets[((size_t)b * 127 + (s - 1)) * 33 + j];
            }
            xin[(size_t)row * 576 + c] = __float2bfloat16(v);
        }
    } else if (bid < 512 + 4096 + 1024) {                // wemb row, pad 545->576
        int row = bid - (512 + 4096);
        for (int c = threadIdx.x; c < 576; c += 256)
            wemb[(size_t)row * 576 + c] = __float2bfloat16(c < 545 ? W_emb[(size_t)row * 545 + c] : 0.f);
    } else if (bid < 6272) {                             // whead row (640 = 529 real + pad)
        int r = bid - (512 + 4096 + 1024);
        const float* wsrc = nullptr; const float* bsrc = nullptr; int off = 0;
        if (r == 0)        { wsrc = Wm;    bsrc = bm;    off = 0; }
        else if (r < 9)    { wsrc = Wpi_m; bsrc = bpi_m; off = r - 1; }
        else if (r < 137)  { wsrc = Wmu_m; bsrc = bmu_m; off = r - 9; }
        else if (r < 265)  { wsrc = Wsg_m; bsrc = bsg_m; off = r - 137; }
        else if (r < 273)  { wsrc = Wpi_v; bsrc = bpi_v; off = r - 265; }
        else if (r < 401)  { wsrc = Wmu_v; bsrc = bmu_v; off = r - 273; }
        else if (r < 529)  { wsrc = Wsg_v; bsrc = bsg_v; off = r - 401; }
        for (int c = threadIdx.x; c < 1024; c += 256)
            whead[(size_t)r * 1024 + c] = __float2bfloat16(wsrc ? wsrc[(size_t)off * 1024 + c] : 0.f);
        if (threadIdx.x == 0 && wsrc) bhead[r] = bsrc[off];
    } else {                                             // weight cvt (NT loads, 16B stores)
        int bid2 = bid - 6272;                           // [0,2304)
        int l = bid2 / 384;
        int s = bid2 - l * 384;
        const float* src; bf16* dst;
        if (s < 192)      { src = Wqkv + (size_t)l * 3145728; dst = wqb + (size_t)l * 3145728; }
        else if (s < 256) { src = Wo + (size_t)l * 1048576; dst = wob + (size_t)l * 1048576; s -= 192; }
        else if (s < 320) { src = W1 + (size_t)l * 1048576; dst = w1b + (size_t)l * 1048576; s -= 256; }
        else              { src = W2 + (size_t)l * 1048576; dst = w2b + (size_t)l * 1048576; s -= 320; }
        size_t pbase = (size_t)s * 2048 + threadIdx.x;
#pragma unroll
        for (int it = 0; it < 8; ++it) {
            size_t o = (pbase + it * 256) * 8;           // 8 floats per pair
            const f32x4* p = (const f32x4*)(src + o);
            f32x4 v1 = __builtin_nontemporal_load(p);
            f32x4 v2 = __builtin_nontemporal_load(p + 1);
            us8 w8;
            w8[0] = f2bf(v1.x); w8[1] = f2bf(v1.y); w8[2] = f2bf(v1.z); w8[3] = f2bf(v1.w);
            w8[4] = f2bf(v2.x); w8[5] = f2bf(v2.y); w8[6] = f2bf(v2.z); w8[7] = f2bf(v2.w);
            *(us8*)(dst + o) = w8;
        }
    }
}

// ---------------- main GEMM: C[M,N] = A[M,K] @ B[N,K]^T (+epilogue) ----------------
// 128x128 tile, BK=64, 4 waves. Operand-swapped MFMA (C^T frags -> vectorized epilogue).
// DBUF=1: simple prefetch dbuf (stage(k+1) before compute(k), one __syncthreads/tile)
//         for grid-limited (<=256-block) launches. [round-6 counted-vmcnt variant
//         regressed ~90us: m141 failure mode -- sched_barrier pinning defeats compiler]
// DBUF=0: single-buffer, 3 blocks/CU (cross-block overlap regime) for QKV (768 blocks).
// EPI: 0 bias->bf16 | 1 bias+relu->bf16 | 2 bias+res->f32 | 3 bias->f32 scalar | 4 bias+pe->f32+bf16
template<int EPI, int DBUF>
__global__ __launch_bounds__(256, DBUF ? 2 : 3) void gemm_bt(
    const bf16* __restrict__ A, const bf16* __restrict__ Bw,
    float* __restrict__ Cf, bf16* __restrict__ Cb,
    const float* __restrict__ bias, const float* __restrict__ res, const float* __restrict__ pe,
    int M, int N, int K, int lda, int ldb, int ldc, long long Az, long long Cz)
{
    __shared__ __align__(16) bf16 sA[DBUF ? 2 : 1][128 * 64];
    __shared__ __align__(16) bf16 sB[DBUF ? 2 : 1][128 * 64];
    const int t = threadIdx.x;
    const int w = t >> 6, la = t & 63;
    const int wm = (w >> 1) * 64, wn = (w & 1) * 64;
    const int m0 = blockIdx.y * 128, n0 = blockIdx.x * 128;
    const int z = blockIdx.z;
    A += (long long)z * Az;

    const int c0 = w * 64 + la;
    facc4 zero4 = {0.f, 0.f, 0.f, 0.f};
    facc4 acc[4][4];
#pragma unroll
    for (int mi = 0; mi < 4; ++mi)
#pragma unroll
        for (int ni = 0; ni < 4; ++ni) acc[mi][ni] = zero4;

    auto stage = [&](int buf, int kt) {                 // 8 gload_lds (4 A + 4 B)
#pragma unroll
        for (int i = 0; i < 4; ++i) {
            int c = i * 256 + c0;
            int r = c >> 3;
            int bc = ((c & 7) * 16) ^ ((r & 7) << 4);   // pre-swizzled source byte col
            gload_lds16(A + (size_t)(m0 + r) * lda + kt + (bc >> 1),
                        (char*)sA[buf] + (size_t)(i * 256 + c0) * 16);
            gload_lds16(Bw + (size_t)(n0 + r) * ldb + kt + (bc >> 1),
                        (char*)sB[buf] + (size_t)(i * 256 + c0) * 16);
        }
    };
    auto compute = [&](int buf) {
#pragma unroll
        for (int ks = 0; ks < 2; ++ks) {
            bfrag8 af[4], bfv[4];
            const int koffb = (ks * 32 + (la >> 4) * 8) * 2;
#pragma unroll
            for (int i = 0; i < 4; ++i) {
                int rowa = wm + i * 16 + (la & 15);
                af[i] = *(const bfrag8*)((const char*)sA[buf] + rowa * 128 + (koffb ^ ((rowa & 7) << 4)));
                int rowb = wn + i * 16 + (la & 15);
                bfv[i] = *(const bfrag8*)((const char*)sB[buf] + rowb * 128 + (koffb ^ ((rowb & 7) << 4)));
            }
#pragma unroll
            for (int mi = 0; mi < 4; ++mi)
#pragma unroll
                for (int ni = 0; ni < 4; ++ni)     // swapped operands -> C^T fragment
                    acc[mi][ni] = __builtin_amdgcn_mfma_f32_16x16x32_bf16(bfv[ni], af[mi], acc[mi][ni], 0, 0, 0);
        }
    };

    const int nk = K >> 6;
    if constexpr (DBUF) {
        stage(0, 0);
        __syncthreads();
        int cur = 0;
        for (int kt = 0; kt < nk; ++kt) {
            if (kt + 1 < nk) stage(cur ^ 1, (kt + 1) << 6);
            compute(cur);
            __syncthreads();        // drains stage(k+1) vmcnt; frees cur
            cur ^= 1;
        }
    } else {
        for (int kt = 0; kt < nk; ++kt) {
            stage(0, kt << 6);
            __syncthreads();
            compute(0);
            __syncthreads();
        }
    }
    // epilogue: thread holds C[row][colb..colb+3]
#pragma unroll
    for (int mi = 0; mi < 4; ++mi) {
        int row = m0 + wm + mi * 16 + (la & 15);
#pragma unroll
        for (int ni = 0; ni < 4; ++ni) {
            int colb = n0 + wn + ni * 16 + (la >> 4) * 4;
            if constexpr (EPI == 3) {               // scalar path (odd ldc / edge guards)
                if (row >= M) continue;
#pragma unroll
                for (int j = 0; j < 4; ++j) {
                    int col = colb + j;
                    if (col < N)
                        Cf[(size_t)z * Cz + (size_t)row * ldc + col] = acc[mi][ni][j] + bias[col];
                }
            } else {
                float4 bv = *(const float4*)(bias + colb);
                facc4 v = acc[mi][ni];
                v[0] += bv.x; v[1] += bv.y; v[2] += bv.z; v[3] += bv.w;
                size_t cidx = (size_t)row * ldc + colb;
                if constexpr (EPI == 0) {
                    us4 o; o.x = f2bf(v[0]); o.y = f2bf(v[1]); o.z = f2bf(v[2]); o.w = f2bf(v[3]);
                    *(us4*)(Cb + cidx) = o;
                } else if constexpr (EPI == 1) {
                    us4 o;
                    o.x = f2bf(v[0] > 0.f ? v[0] : 0.f); o.y = f2bf(v[1] > 0.f ? v[1] : 0.f);
                    o.z = f2bf(v[2] > 0.f ? v[2] : 0.f); o.w = f2bf(v[3] > 0.f ? v[3] : 0.f);
                    *(us4*)(Cb + cidx) = o;
                } else if constexpr (EPI == 2) {
                    float4 r = *(const float4*)(res + cidx);
                    float4 o = {v[0] + r.x, v[1] + r.y, v[2] + r.z, v[3] + r.w};
                    *(float4*)(Cf + cidx) = o;
                } else {                            // EPI == 4
                    float4 p = *(const float4*)(pe + (size_t)(row & 127) * 1024 + colb);
                    float4 o = {v[0] + p.x, v[1] + p.y, v[2] + p.z, v[3] + p.w};
                    *(float4*)(Cf + cidx) = o;
                    us4 ob;
                    ob.x = f2bf(o.x); ob.y = f2bf(o.y); ob.z = f2bf(o.z); ob.w = f2bf(o.w);
                    *(us4*)(Cb + cidx) = ob;
                }
            }
        }
    }
}

// ---------------- fused attention: one block per (b,h) ----------------
__global__ __launch_bounds__(256) void attn_fused(const bf16* __restrict__ qkv, bf16* __restrict__ obf)
{
    __shared__ __align__(16) char lds[65536];
    char* sQ  = lds;            // [128] rows x 128B, swizzled
    char* sK  = lds + 16384;    // [128] rows x 128B
    char* sS  = lds + 32768;    // [128] rows x 256B bf16 (scores, then P)
    char* sVT = lds;            // [64] rows x 256B (V transposed), overlaps sQ

    const int t = threadIdx.x, w = t >> 6, la = t & 63;
    const int b = blockIdx.x >> 4, h = blockIdx.x & 15;
    const size_t base = (size_t)b * 128 * 3072 + (size_t)h * 64;

    // phase 1: stage Q, K (swizzled via pre-swizzled source)
#pragma unroll
    for (int i = 0; i < 4; ++i) {
        int c = i * 256 + w * 64 + la;
        int r = c >> 3;
        int bc = ((c & 7) * 16) ^ ((r & 7) << 4);
        gload_lds16(qkv + base + (size_t)r * 3072 + (bc >> 1),
                    sQ + (size_t)(i * 256 + w * 64) * 16);
        gload_lds16(qkv + base + 1024 + (size_t)r * 3072 + (bc >> 1),
                    sK + (size_t)(i * 256 + w * 64) * 16);
    }
    __syncthreads();

    // phase 2: S = Q K^T * 0.125 (swapped mfma -> thread holds S[q][kb..kb+3])
    const int wm = (w >> 1) * 64, wn = (w & 1) * 64;
    facc4 zero4 = {0.f, 0.f, 0.f, 0.f};
    {
        facc4 acc[4][4];
#pragma unroll
        for (int mi = 0; mi < 4; ++mi)
#pragma unroll
            for (int ni = 0; ni < 4; ++ni) acc[mi][ni] = zero4;
#pragma unroll
        for (int ks = 0; ks < 2; ++ks) {
            bfrag8 af[4], bfv[4];
            const int koffb = (ks * 32 + (la >> 4) * 8) * 2;
#pragma unroll
            for (int i = 0; i < 4; ++i) {
                int rowa = wm + i * 16 + (la & 15);
                af[i] = *(const bfrag8*)(sQ + rowa * 128 + (koffb ^ ((rowa & 7) << 4)));
                int rowb = wn + i * 16 + (la & 15);
                bfv[i] = *(const bfrag8*)(sK + rowb * 128 + (koffb ^ ((rowb & 7) << 4)));
            }
#pragma unroll
            for (int mi = 0; mi < 4; ++mi)
#pragma unroll
                for (int ni = 0; ni < 4; ++ni)
                    acc[mi][ni] = __builtin_amdgcn_mfma_f32_16x16x32_bf16(bfv[ni], af[mi], acc[mi][ni], 0, 0, 0);
        }
#pragma unroll
        for (int mi = 0; mi < 4; ++mi) {
            int q = wm + mi * 16 + (la & 15);
#pragma unroll
            for (int ni = 0; ni < 4; ++ni) {
                int kb = wn + ni * 16 + (la >> 4) * 4;
                us4 sv;
                sv.x = f2bf(acc[mi][ni][0] * 0.125f); sv.y = f2bf(acc[mi][ni][1] * 0.125f);
                sv.z = f2bf(acc[mi][ni][2] * 0.125f); sv.w = f2bf(acc[mi][ni][3] * 0.125f);
                *(us4*)(sS + q * 256 + ((2 * kb) ^ ((q & 7) << 4))) = sv;
            }
        }
    }
    __syncthreads();

    // phase 3a: stage V transposed into sVT (sQ space, free now)
#pragma unroll
    for (int i = 0; i < 4; ++i) {
        int c = i * 256 + t;
        int r = c >> 3;             // key index s'
        int d0 = (c & 7) * 8;
        bfrag8 vv = *(const bfrag8*)(qkv + base + 2048 + (size_t)r * 3072 + d0);
#pragma unroll
        for (int j = 0; j < 8; ++j) {
            int d = d0 + j;
            *(short*)(sVT + d * 256 + ((2 * r) ^ ((d & 7) << 4))) = vv[j];
        }
    }
    // phase 3b: causal softmax, in place on sS (wave w owns rows w*32..w*32+31)
    for (int ri = 0; ri < 32; ++ri) {
        int r = w * 32 + ri;
        int c1 = la, c2 = la + 64;
        float v1 = (c1 <= r) ? bf2f(*(const unsigned short*)(sS + r * 256 + ((2 * c1) ^ ((r & 7) << 4)))) : -1e30f;
        float v2 = (c2 <= r) ? bf2f(*(const unsigned short*)(sS + r * 256 + ((2 * c2) ^ ((r & 7) << 4)))) : -1e30f;
        float mx = fmaxf(v1, v2);
#pragma unroll
        for (int off = 32; off; off >>= 1) mx = fmaxf(mx, __shfl_xor(mx, off));
        float e1 = (c1 <= r) ? __expf(v1 - mx) : 0.f;
        float e2 = (c2 <= r) ? __expf(v2 - mx) : 0.f;
        float sm = e1 + e2;
#pragma unroll
        for (int off = 32; off; off >>= 1) sm += __shfl_xor(sm, off);
        float inv = 1.f / sm;
        *(unsigned short*)(sS + r * 256 + ((2 * c1) ^ ((r & 7) << 4))) = f2bf(e1 * inv);
        *(unsigned short*)(sS + r * 256 + ((2 * c2) ^ ((r & 7) << 4))) = f2bf(e2 * inv);
    }
    __syncthreads();

    // phase 4: O = P V  (wave tile 64M x 32N, K=128; swapped mfma -> packed O stores)
    const int wm2 = (w >> 1) * 64, wn2 = (w & 1) * 32;
    facc4 a2[4][2];
#pragma unroll
    for (int mi = 0; mi < 4; ++mi) { a2[mi][0] = zero4; a2[mi][1] = zero4; }
#pragma unroll
    for (int ks = 0; ks < 4; ++ks) {
        bfrag8 pa[4], vb[2];
        const int koffb = (ks * 32 + (la >> 4) * 8) * 2;
#pragma unroll
        for (int mi = 0; mi < 4; ++mi) {
            int rowa = wm2 + mi * 16 + (la & 15);
            pa[mi] = *(const bfrag8*)(sS + rowa * 256 + (koffb ^ ((rowa & 7) << 4)));
        }
#pragma unroll
        for (int ni = 0; ni < 2; ++ni) {
            int rowb = wn2 + ni * 16 + (la & 15);
            vb[ni] = *(const bfrag8*)(sVT + rowb * 256 + (koffb ^ ((rowb & 7) << 4)));
        }
#pragma unroll
        for (int mi = 0; mi < 4; ++mi)
#pragma unroll
            for (int ni = 0; ni < 2; ++ni)
                a2[mi][ni] = __builtin_amdgcn_mfma_f32_16x16x32_bf16(vb[ni], pa[mi], a2[mi][ni], 0, 0, 0);
    }
#pragma unroll
    for (int mi = 0; mi < 4; ++mi) {
        int s = wm2 + mi * 16 + (la & 15);
#pragma unroll
        for (int ni = 0; ni < 2; ++ni) {
            int db = wn2 + ni * 16 + (la >> 4) * 4;
            us4 ov;
            ov.x = f2bf(a2[mi][ni][0]); ov.y = f2bf(a2[mi][ni][1]);
            ov.z = f2bf(a2[mi][ni][2]); ov.w = f2bf(a2[mi][ni][3]);
            *(us4*)(obf + ((size_t)(b * 128 + s)) * 1024 + h * 64 + db) = ov;
        }
    }
}

// ------- fused residual + LayerNorm: t = xf + go(bf16); LN(t) -> xf, xb -------
__global__ __launch_bounds__(256) void ln_res_kernel(const bf16* __restrict__ go,
                                                     const float* __restrict__ xf_in,
                                                     const float* __restrict__ g, const float* __restrict__ be,
                                                     float* __restrict__ xf_out, bf16* __restrict__ xb_out)
{
    const int row = blockIdx.x, t = threadIdx.x;
    size_t o = (size_t)row * 1024 + t * 4;
    us4 gv4 = *(const us4*)(go + o);
    float4 xv = *(const float4*)(xf_in + o);
    float t0 = xv.x + bf2f(gv4.x);
    float t1 = xv.y + bf2f(gv4.y);
    float t2 = xv.z + bf2f(gv4.z);
    float t3 = xv.w + bf2f(gv4.w);
    float s = t0 + t1 + t2 + t3;
    float q = t0 * t0 + t1 * t1 + t2 * t2 + t3 * t3;
#pragma unroll
    for (int off = 32; off; off >>= 1) {
        s += __shfl_xor(s, off);
        q += __shfl_xor(q, off);
    }
    __shared__ float ssum[4], sqs[4];
    if ((t & 63) == 0) { ssum[t >> 6] = s; sqs[t >> 6] = q; }
    __syncthreads();
    s = ssum[0] + ssum[1] + ssum[2] + ssum[3];
    q = sqs[0] + sqs[1] + sqs[2] + sqs[3];
    float mean = s * (1.f / 1024.f);
    float var = q * (1.f / 1024.f) - mean * mean;
    float rstd = rsqrtf(var + 1e-5f);
    float4 gv = *(const float4*)(g + t * 4);
    float4 bv = *(const float4*)(be + t * 4);
    float o0 = (t0 - mean) * rstd * gv.x + bv.x;
    float o1 = (t1 - mean) * rstd * gv.y + bv.y;
    float o2 = (t2 - mean) * rstd * gv.z + bv.z;
    float o3 = (t3 - mean) * rstd * gv.w + bv.w;
    float4 of = {o0, o1, o2, o3};
    *(float4*)(xf_out + o) = of;
    us4 obv; obv.x = f2bf(o0); obv.y = f2bf(o1); obv.z = f2bf(o2); obv.w = f2bf(o3);
    *(us4*)(xb_out + o) = obv;
}

// ---------------- MDN finalize / scatter ----------------
__global__ void finalize_kernel(const float* __restrict__ hout, float* __restrict__ out) {
    const size_t O_PI_M = 0, O_MU_M = 32512, O_VAR_M = 552704, O_PI_V = 1072896,
                 O_MU_V = 1105408, O_VAR_V = 1625600, O_MASK = 2145792;
    int rm = blockIdx.x;                    // b*127+m, 4064 rows
    const float* hrow = hout + (size_t)rm * 529;
    int t = threadIdx.x;
    if (t < 128) {
        out[O_MU_M  + (size_t)rm * 128 + t] = hrow[9 + t];
        out[O_VAR_M + (size_t)rm * 128 + t] = expf(hrow[137 + t]);
        out[O_MU_V  + (size_t)rm * 128 + t] = hrow[273 + t];
        out[O_VAR_V + (size_t)rm * 128 + t] = expf(hrow[401 + t]);
    } else if (t == 128) {
        out[O_MASK + rm] = hrow[0];
    } else if (t == 129 || t == 130) {
        int boff = (t == 129) ? 1 : 265;
        size_t oo = ((t == 129) ? O_PI_M : O_PI_V) + (size_t)rm * 8;
        float v[8], mx = -1e30f;
#pragma unroll
        for (int j = 0; j < 8; ++j) { v[j] = hrow[boff + j]; mx = fmaxf(mx, v[j]); }
        float sm = 0.f;
#pragma unroll
        for (int j = 0; j < 8; ++j) { v[j] = expf(v[j] - mx); sm += v[j]; }
        float inv = 1.f / sm;
#pragma unroll
        for (int j = 0; j < 8; ++j) out[oo + j] = v[j] * inv;
    }
}

// ---------------- launcher ----------------
extern "C" void kernel_launch(void* const* d_in, const int* in_sizes, int n_in,
                              void* d_out, int out_size, void* d_ws, size_t ws_size,
                              hipStream_t stream) {
    (void)in_sizes; (void)n_in; (void)out_size; (void)ws_size;
    const float* input   = (const float*)d_in[0];
    const float* targets = (const float*)d_in[1];
    const float* W_emb   = (const float*)d_in[2];
    const float* b_emb   = (const float*)d_in[3];
    const float* sos     = (const float*)d_in[4];
    const float* Wqkv    = (const float*)d_in[5];
    const float* bqkv    = (const float*)d_in[6];
    const float* Wo      = (const float*)d_in[7];
    const float* bo      = (const float*)d_in[8];
    const float* W1      = (const float*)d_in[9];
    const float* b1      = (const float*)d_in[10];
    const float* W2      = (const float*)d_in[11];
    const float* b2      = (const float*)d_in[12];
    const float* g1      = (const float*)d_in[13];
    const float* be1     = (const float*)d_in[14];
    const float* g2      = (const float*)d_in[15];
    const float* be2     = (const float*)d_in[16];
    const float* Wm      = (const float*)d_in[17];
    const float* bm      = (const float*)d_in[18];
    const float* Wpi_m   = (const float*)d_in[19];
    const float* bpi_m   = (const float*)d_in[20];
    const float* Wmu_m   = (const float*)d_in[21];
    const float* bmu_m   = (const float*)d_in[22];
    const float* Wsg_m   = (const float*)d_in[23];
    const float* bsg_m   = (const float*)d_in[24];
    const float* Wpi_v   = (const float*)d_in[25];
    const float* bpi_v   = (const float*)d_in[26];
    const float* Wmu_v   = (const float*)d_in[27];
    const float* bmu_v   = (const float*)d_in[28];
    const float* Wsg_v   = (const float*)d_in[29];
    const float* bsg_v   = (const float*)d_in[30];
    float* out = (float*)d_out;

    char* ws = (char*)d_ws;                            // ~167 MB total
    float* pe      = (float*)(ws + 0);                 // 0.5 MB
    bf16*  xin     = (bf16*)(ws + 524288);             // 4.72 MB
    bf16*  wemb    = (bf16*)(ws + 5242880);            // 1.18 MB
    bf16*  whead   = (bf16*)(ws + 6422528);            // 1.31 MB (640 rows)
    float* bhead   = (float*)(ws + 7733248);           // 2.5 KB
    float* xf      = (float*)(ws + 7735808);           // 16.8 MB
    bf16*  xb      = (bf16*)(ws + 24513024);           // 8.4 MB
    bf16*  qkvb    = (bf16*)(ws + 32901632);           // 25.2 MB
    bf16*  ob      = (bf16*)(ws + 58067456);           // 8.4 MB (attn out, reused as FF hidden)
    bf16*  tmpb    = (bf16*)(ws + 66456064);           // 8.4 MB (gemm-out bf16, pre-LN)
    bf16*  wqb_all = (bf16*)(ws + 83233280);           // 37.7 MB (6 layers)
    bf16*  wob_all = (bf16*)(ws + 120982016);          // 12.6 MB
    bf16*  w1b_all = (bf16*)(ws + 133564928);          // 12.6 MB
    bf16*  w2b_all = (bf16*)(ws + 146147840);          // 12.6 MB
    float* hout    = (float*)(ws + 158730752);         // 8.6 MB

    prep_cvt_kernel<<<8576, 256, 0, stream>>>(input, targets, sos, W_emb,
                                              Wm, Wpi_m, Wmu_m, Wsg_m, Wpi_v, Wmu_v, Wsg_v,
                                              bm, bpi_m, bmu_m, bsg_m, bpi_v, bmu_v, bsg_v,
                                              Wqkv, Wo, W1, W2,
                                              pe, xin, wemb, whead, bhead,
                                              wqb_all, wob_all, w1b_all, w2b_all);
    // x = XIN @ Wemb^T + b + pe   -> xf (f32) + xb (bf16)
    gemm_bt<4, 1><<<dim3(8, 32, 1), 256, 0, stream>>>(xin, wemb, xf, xb, b_emb, nullptr, pe,
                                                      4096, 1024, 576, 576, 576, 1024, 0, 0);
    for (int l = 0; l < 6; ++l) {
        const bf16* wqb = wqb_all + (size_t)l * 3145728;
        const bf16* wob = wob_all + (size_t)l * 1048576;
        const bf16* w1b = w1b_all + (size_t)l * 1048576;
        const bf16* w2b = w2b_all + (size_t)l * 1048576;
        // qkv = x @ Wqkv^T + b  (bf16 out) -- 768 blocks, single-buffer, 3 blocks/CU
        gemm_bt<0, 0><<<dim3(24, 32, 1), 256, 0, stream>>>(xb, wqb, nullptr, qkvb, bqkv + l * 3072,
                                                           nullptr, nullptr, 4096, 3072, 1024, 1024, 1024, 3072, 0, 0);
        attn_fused<<<512, 256, 0, stream>>>(qkvb, ob);
        // go = o @ Wo^T + bo (bf16); residual folded into ln_res
        gemm_bt<0, 1><<<dim3(8, 32, 1), 256, 0, stream>>>(ob, wob, nullptr, tmpb, bo + l * 1024,
                                                          nullptr, nullptr, 4096, 1024, 1024, 1024, 1024, 1024, 0, 0);
        ln_res_kernel<<<4096, 256, 0, stream>>>(tmpb, xf, g1 + l * 1024, be1 + l * 1024, xf, xb);
        // t1 = relu(x @ W1^T + b1) (bf16, reuse ob)
        gemm_bt<1, 1><<<dim3(8, 32, 1), 256, 0, stream>>>(xb, w1b, nullptr, ob, b1 + l * 1024,
                                                          nullptr, nullptr, 4096, 1024, 1024, 1024, 1024, 1024, 0, 0);
        // go = t1 @ W2^T + b2 (bf16); residual folded into ln_res
        gemm_bt<0, 1><<<dim3(8, 32, 1), 256, 0, stream>>>(ob, w2b, nullptr, tmpb, b2 + l * 1024,
                                                          nullptr, nullptr, 4096, 1024, 1024, 1024, 1024, 1024, 0, 0);
        ln_res_kernel<<<4096, 256, 0, stream>>>(tmpb, xf, g2 + l * 1024, be2 + l * 1024, xf, xb);
    }
    // heads: per-batch M=127 rows of x -> hout (B,127,529) -- 160 blocks, dbuf
    gemm_bt<3, 1><<<dim3(5, 1, 32), 256, 0, stream>>>(xb, whead, hout, nullptr, bhead, nullptr, nullptr,
                                                      127, 529, 1024, 1024, 1024, 529, 131072LL, 67183LL);
    finalize_kernel<<<4064, 256, 0, stream>>>(hout, out);
}

// Round 8
// 816.554 us; speedup vs baseline: 1.2635x; 1.1295x over previous
//
#include <hip/hip_runtime.h>
#include <hip/hip_bf16.h>

typedef __hip_bfloat16 bf16;
typedef __attribute__((ext_vector_type(8))) short bfrag8;   // 8 bf16 (4 VGPR) MFMA A/B frag
typedef __attribute__((ext_vector_type(4))) float facc4;    // MFMA C/D frag
typedef __attribute__((ext_vector_type(4))) unsigned short us4;
typedef __attribute__((ext_vector_type(8))) unsigned short us8;
typedef __attribute__((ext_vector_type(4))) float f32x4;    // true clang vector (for nontemporal)

#define AS1C const __attribute__((address_space(1))) void
#define AS3  __attribute__((address_space(3))) void

__device__ __forceinline__ void gload_lds16(const void* src, void* dst) {
    __builtin_amdgcn_global_load_lds((AS1C*)src, (AS3*)dst, 16, 0, 0);
}

__device__ __forceinline__ unsigned short f2bf(float f) {   // RNE, finite inputs
    unsigned u = __float_as_uint(f);
    unsigned r = u + 0x7FFFu + ((u >> 16) & 1u);
    return (unsigned short)(r >> 16);
}
__device__ __forceinline__ float bf2f(unsigned short u) {   // exact
    return __uint_as_float((unsigned)u << 16);
}

// ------- merged prep+cvt kernel: pe | xin | wemb | whead | all weight cvt -------
__global__ void prep_cvt_kernel(const float* __restrict__ input, const float* __restrict__ targets,
                                const float* __restrict__ sos, const float* __restrict__ W_emb,
                                const float* __restrict__ Wm, const float* __restrict__ Wpi_m,
                                const float* __restrict__ Wmu_m, const float* __restrict__ Wsg_m,
                                const float* __restrict__ Wpi_v, const float* __restrict__ Wmu_v,
                                const float* __restrict__ Wsg_v,
                                const float* __restrict__ bm, const float* __restrict__ bpi_m,
                                const float* __restrict__ bmu_m, const float* __restrict__ bsg_m,
                                const float* __restrict__ bpi_v, const float* __restrict__ bmu_v,
                                const float* __restrict__ bsg_v,
                                const float* __restrict__ Wqkv, const float* __restrict__ Wo,
                                const float* __restrict__ W1, const float* __restrict__ W2,
                                float* __restrict__ pe, bf16* __restrict__ xin,
                                bf16* __restrict__ wemb, bf16* __restrict__ whead,
                                float* __restrict__ bhead,
                                bf16* __restrict__ wqb, bf16* __restrict__ wob,
                                bf16* __restrict__ w1b, bf16* __restrict__ w2b) {
    int bid = blockIdx.x;
    if (bid < 512) {                                     // pe [128][1024]
        int idx = bid * 256 + threadIdx.x;
        int s = idx >> 10, c = idx & 1023;
        int i = c >> 1;
        float div = expf(-9.210340371976184f * (float)(2 * i) * (1.f / 1024.f));
        float a = (float)s * div;
        pe[idx] = (c & 1) ? cosf(a) : sinf(a);
    } else if (bid < 512 + 4096) {                       // xin row (b*128+s), pad K->576
        int row = bid - 512;
        int b = row >> 7, s = row & 127;
        for (int c = threadIdx.x; c < 576; c += 256) {
            float v = 0.f;
            if (c < 512) v = input[b * 512 + c];
            else if (c < 545) {
                int j = c - 512;
                v = (s == 0) ? sos[j] : targets[((size_t)b * 127 + (s - 1)) * 33 + j];
            }
            xin[(size_t)row * 576 + c] = __float2bfloat16(v);
        }
    } else if (bid < 512 + 4096 + 1024) {                // wemb row, pad 545->576
        int row = bid - (512 + 4096);
        for (int c = threadIdx.x; c < 576; c += 256)
            wemb[(size_t)row * 576 + c] = __float2bfloat16(c < 545 ? W_emb[(size_t)row * 545 + c] : 0.f);
    } else if (bid < 6272) {                             // whead row (640 = 529 real + pad)
        int r = bid - (512 + 4096 + 1024);
        const float* wsrc = nullptr; const float* bsrc = nullptr; int off = 0;
        if (r == 0)        { wsrc = Wm;    bsrc = bm;    off = 0; }
        else if (r < 9)    { wsrc = Wpi_m; bsrc = bpi_m; off = r - 1; }
        else if (r < 137)  { wsrc = Wmu_m; bsrc = bmu_m; off = r - 9; }
        else if (r < 265)  { wsrc = Wsg_m; bsrc = bsg_m; off = r - 137; }
        else if (r < 273)  { wsrc = Wpi_v; bsrc = bpi_v; off = r - 265; }
        else if (r < 401)  { wsrc = Wmu_v; bsrc = bmu_v; off = r - 273; }
        else if (r < 529)  { wsrc = Wsg_v; bsrc = bsg_v; off = r - 401; }
        for (int c = threadIdx.x; c < 1024; c += 256)
            whead[(size_t)r * 1024 + c] = __float2bfloat16(wsrc ? wsrc[(size_t)off * 1024 + c] : 0.f);
        if (threadIdx.x == 0 && wsrc) bhead[r] = bsrc[off];
    } else {                                             // weight cvt (NT loads, 16B stores)
        int bid2 = bid - 6272;                           // [0,2304)
        int l = bid2 / 384;
        int s = bid2 - l * 384;
        const float* src; bf16* dst;
        if (s < 192)      { src = Wqkv + (size_t)l * 3145728; dst = wqb + (size_t)l * 3145728; }
        else if (s < 256) { src = Wo + (size_t)l * 1048576; dst = wob + (size_t)l * 1048576; s -= 192; }
        else if (s < 320) { src = W1 + (size_t)l * 1048576; dst = w1b + (size_t)l * 1048576; s -= 256; }
        else              { src = W2 + (size_t)l * 1048576; dst = w2b + (size_t)l * 1048576; s -= 320; }
        size_t pbase = (size_t)s * 2048 + threadIdx.x;
#pragma unroll
        for (int it = 0; it < 8; ++it) {
            size_t o = (pbase + it * 256) * 8;           // 8 floats per pair
            const f32x4* p = (const f32x4*)(src + o);
            f32x4 v1 = __builtin_nontemporal_load(p);
            f32x4 v2 = __builtin_nontemporal_load(p + 1);
            us8 w8;
            w8[0] = f2bf(v1.x); w8[1] = f2bf(v1.y); w8[2] = f2bf(v1.z); w8[3] = f2bf(v1.w);
            w8[4] = f2bf(v2.x); w8[5] = f2bf(v2.y); w8[6] = f2bf(v2.z); w8[7] = f2bf(v2.w);
            *(us8*)(dst + o) = w8;
        }
    }
}

// ---------------- main GEMM: C[M,N] = A[M,K] @ B[N,K]^T (+epilogue) ----------------
// 128x128 tile, BK=64, 4 waves. Operand-swapped MFMA (C^T frags -> vectorized epilogue).
// DBUF=1: simple prefetch dbuf for grid-limited (<=256-block) launches.
// DBUF=0: single-buffer, 3 blocks/CU (cross-block overlap regime) for QKV (768 blocks).
// EPI: 0 bias->bf16 | 1 bias+relu->bf16 | 2 bias+res->f32 | 3 bias->f32 scalar | 4 bias+pe->f32+bf16
template<int EPI, int DBUF>
__global__ __launch_bounds__(256, DBUF ? 2 : 3) void gemm_bt(
    const bf16* __restrict__ A, const bf16* __restrict__ Bw,
    float* __restrict__ Cf, bf16* __restrict__ Cb,
    const float* __restrict__ bias, const float* __restrict__ res, const float* __restrict__ pe,
    int M, int N, int K, int lda, int ldb, int ldc, long long Az, long long Cz)
{
    __shared__ __align__(16) bf16 sA[DBUF ? 2 : 1][128 * 64];
    __shared__ __align__(16) bf16 sB[DBUF ? 2 : 1][128 * 64];
    const int t = threadIdx.x;
    const int w = t >> 6, la = t & 63;
    const int wm = (w >> 1) * 64, wn = (w & 1) * 64;
    const int m0 = blockIdx.y * 128, n0 = blockIdx.x * 128;
    const int z = blockIdx.z;
    A += (long long)z * Az;

    const int c0 = w * 64 + la;
    facc4 zero4 = {0.f, 0.f, 0.f, 0.f};
    facc4 acc[4][4];
#pragma unroll
    for (int mi = 0; mi < 4; ++mi)
#pragma unroll
        for (int ni = 0; ni < 4; ++ni) acc[mi][ni] = zero4;

    auto stage = [&](int buf, int kt) {                 // 8 gload_lds (4 A + 4 B)
#pragma unroll
        for (int i = 0; i < 4; ++i) {
            int c = i * 256 + c0;
            int r = c >> 3;
            int bc = ((c & 7) * 16) ^ ((r & 7) << 4);   // pre-swizzled source byte col
            gload_lds16(A + (size_t)(m0 + r) * lda + kt + (bc >> 1),
                        (char*)sA[buf] + (size_t)(i * 256 + c0) * 16);
            gload_lds16(Bw + (size_t)(n0 + r) * ldb + kt + (bc >> 1),
                        (char*)sB[buf] + (size_t)(i * 256 + c0) * 16);
        }
    };
    auto compute = [&](int buf) {
#pragma unroll
        for (int ks = 0; ks < 2; ++ks) {
            bfrag8 af[4], bfv[4];
            const int koffb = (ks * 32 + (la >> 4) * 8) * 2;
#pragma unroll
            for (int i = 0; i < 4; ++i) {
                int rowa = wm + i * 16 + (la & 15);
                af[i] = *(const bfrag8*)((const char*)sA[buf] + rowa * 128 + (koffb ^ ((rowa & 7) << 4)));
                int rowb = wn + i * 16 + (la & 15);
                bfv[i] = *(const bfrag8*)((const char*)sB[buf] + rowb * 128 + (koffb ^ ((rowb & 7) << 4)));
            }
#pragma unroll
            for (int mi = 0; mi < 4; ++mi)
#pragma unroll
                for (int ni = 0; ni < 4; ++ni)     // swapped operands -> C^T fragment
                    acc[mi][ni] = __builtin_amdgcn_mfma_f32_16x16x32_bf16(bfv[ni], af[mi], acc[mi][ni], 0, 0, 0);
        }
    };

    const int nk = K >> 6;
    if constexpr (DBUF) {
        stage(0, 0);
        __syncthreads();
        int cur = 0;
        for (int kt = 0; kt < nk; ++kt) {
            if (kt + 1 < nk) stage(cur ^ 1, (kt + 1) << 6);
            compute(cur);
            __syncthreads();        // drains stage(k+1) vmcnt; frees cur
            cur ^= 1;
        }
    } else {
        for (int kt = 0; kt < nk; ++kt) {
            stage(0, kt << 6);
            __syncthreads();
            compute(0);
            __syncthreads();
        }
    }
    // epilogue: thread holds C[row][colb..colb+3]
#pragma unroll
    for (int mi = 0; mi < 4; ++mi) {
        int row = m0 + wm + mi * 16 + (la & 15);
#pragma unroll
        for (int ni = 0; ni < 4; ++ni) {
            int colb = n0 + wn + ni * 16 + (la >> 4) * 4;
            if constexpr (EPI == 3) {               // scalar path (odd ldc / edge guards)
                if (row >= M) continue;
#pragma unroll
                for (int j = 0; j < 4; ++j) {
                    int col = colb + j;
                    if (col < N)
                        Cf[(size_t)z * Cz + (size_t)row * ldc + col] = acc[mi][ni][j] + bias[col];
                }
            } else {
                float4 bv = *(const float4*)(bias + colb);
                facc4 v = acc[mi][ni];
                v[0] += bv.x; v[1] += bv.y; v[2] += bv.z; v[3] += bv.w;
                size_t cidx = (size_t)row * ldc + colb;
                if constexpr (EPI == 0) {
                    us4 o; o.x = f2bf(v[0]); o.y = f2bf(v[1]); o.z = f2bf(v[2]); o.w = f2bf(v[3]);
                    *(us4*)(Cb + cidx) = o;
                } else if constexpr (EPI == 1) {
                    us4 o;
                    o.x = f2bf(v[0] > 0.f ? v[0] : 0.f); o.y = f2bf(v[1] > 0.f ? v[1] : 0.f);
                    o.z = f2bf(v[2] > 0.f ? v[2] : 0.f); o.w = f2bf(v[3] > 0.f ? v[3] : 0.f);
                    *(us4*)(Cb + cidx) = o;
                } else if constexpr (EPI == 2) {
                    float4 r = *(const float4*)(res + cidx);
                    float4 o = {v[0] + r.x, v[1] + r.y, v[2] + r.z, v[3] + r.w};
                    *(float4*)(Cf + cidx) = o;
                } else {                            // EPI == 4
                    float4 p = *(const float4*)(pe + (size_t)(row & 127) * 1024 + colb);
                    float4 o = {v[0] + p.x, v[1] + p.y, v[2] + p.z, v[3] + p.w};
                    *(float4*)(Cf + cidx) = o;
                    us4 ob;
                    ob.x = f2bf(o.x); ob.y = f2bf(o.y); ob.z = f2bf(o.z); ob.w = f2bf(o.w);
                    *(us4*)(Cb + cidx) = ob;
                }
            }
        }
    }
}

// ---------------- fused attention: one block per (b,h) ----------------
// S=128, D=64. Swapped QK^T keeps S rows lane-local -> IN-REGISTER causal softmax
// (masked max -> shfl_xor(16,32) over the la>>4 axis -> tiny LDS cross-half
// exchange in the dead sK region -> exp+normalize in regs) -> packed bf16 P -> PV.
// Replaces the old 32-iteration serial per-row loop (Common-mistake #6).
__global__ __launch_bounds__(256) void attn_fused(const bf16* __restrict__ qkv, bf16* __restrict__ obf)
{
    __shared__ __align__(16) char lds[65536];
    char* sQ  = lds;            // [128] rows x 128B, swizzled
    char* sK  = lds + 16384;    // [128] rows x 128B (dead after QK^T -> red arrays)
    char* sS  = lds + 32768;    // [128] rows x 256B bf16 (P)
    char* sVT = lds;            // [64] rows x 256B (V transposed), overlaps sQ
    float* redm = (float*)(lds + 16384);            // [2][128] row max per col-half
    float* reds = (float*)(lds + 16384 + 1024);     // [2][128] row sum per col-half

    const int t = threadIdx.x, w = t >> 6, la = t & 63;
    const int b = blockIdx.x >> 4, h = blockIdx.x & 15;
    const size_t base = (size_t)b * 128 * 3072 + (size_t)h * 64;

    // phase 1: stage Q, K (swizzled via pre-swizzled source)
#pragma unroll
    for (int i = 0; i < 4; ++i) {
        int c = i * 256 + w * 64 + la;
        int r = c >> 3;
        int bc = ((c & 7) * 16) ^ ((r & 7) << 4);
        gload_lds16(qkv + base + (size_t)r * 3072 + (bc >> 1),
                    sQ + (size_t)(i * 256 + w * 64) * 16);
        gload_lds16(qkv + base + 1024 + (size_t)r * 3072 + (bc >> 1),
                    sK + (size_t)(i * 256 + w * 64) * 16);
    }
    __syncthreads();

    // phase 2: S = Q K^T (swapped mfma -> thread holds S[q][kb..kb+3], fp32)
    const int wm = (w >> 1) * 64, wn = (w & 1) * 64;
    facc4 zero4 = {0.f, 0.f, 0.f, 0.f};
    facc4 acc[4][4];
#pragma unroll
    for (int mi = 0; mi < 4; ++mi)
#pragma unroll
        for (int ni = 0; ni < 4; ++ni) acc[mi][ni] = zero4;
#pragma unroll
    for (int ks = 0; ks < 2; ++ks) {
        bfrag8 af[4], bfv[4];
        const int koffb = (ks * 32 + (la >> 4) * 8) * 2;
#pragma unroll
        for (int i = 0; i < 4; ++i) {
            int rowa = wm + i * 16 + (la & 15);
            af[i] = *(const bfrag8*)(sQ + rowa * 128 + (koffb ^ ((rowa & 7) << 4)));
            int rowb = wn + i * 16 + (la & 15);
            bfv[i] = *(const bfrag8*)(sK + rowb * 128 + (koffb ^ ((rowb & 7) << 4)));
        }
#pragma unroll
        for (int mi = 0; mi < 4; ++mi)
#pragma unroll
            for (int ni = 0; ni < 4; ++ni)
                acc[mi][ni] = __builtin_amdgcn_mfma_f32_16x16x32_bf16(bfv[ni], af[mi], acc[mi][ni], 0, 0, 0);
    }
    __syncthreads();        // all waves done reading sQ/sK

    // phase 3a: stage V transposed into sVT (overlaps softmax VALU below)
#pragma unroll
    for (int i = 0; i < 4; ++i) {
        int c = i * 256 + t;
        int r = c >> 3;             // key index s'
        int d0 = (c & 7) * 8;
        bfrag8 vv = *(const bfrag8*)(qkv + base + 2048 + (size_t)r * 3072 + d0);
#pragma unroll
        for (int j = 0; j < 8; ++j) {
            int d = d0 + j;
            *(short*)(sVT + d * 256 + ((2 * r) ^ ((d & 7) << 4))) = vv[j];
        }
    }

    // phase 3b: in-register causal softmax
    const int colh = (w & 1) * 128;
    float tmp4[4];
#pragma unroll
    for (int mi = 0; mi < 4; ++mi) {            // pass 1: scale, mask, wave-half max
        int q = wm + mi * 16 + (la & 15);
        float mx = -1e30f;
#pragma unroll
        for (int ni = 0; ni < 4; ++ni) {
            int kb = wn + ni * 16 + (la >> 4) * 4;
#pragma unroll
            for (int j = 0; j < 4; ++j) {
                float s = acc[mi][ni][j] * 0.125f;
                acc[mi][ni][j] = s;
                if (kb + j <= q) mx = fmaxf(mx, s);
            }
        }
        mx = fmaxf(mx, __shfl_xor(mx, 16));     // reduce over la>>4 (the k-axis lanes)
        mx = fmaxf(mx, __shfl_xor(mx, 32));
        tmp4[mi] = mx;
    }
    if ((la >> 4) == 0) {
#pragma unroll
        for (int mi = 0; mi < 4; ++mi) redm[colh + wm + mi * 16 + la] = tmp4[mi];
    }
    __syncthreads();
#pragma unroll
    for (int mi = 0; mi < 4; ++mi) {            // pass 2: exp, wave-half sum
        int q = wm + mi * 16 + (la & 15);
        float m = fmaxf(redm[q], redm[128 + q]);
        float sm = 0.f;
#pragma unroll
        for (int ni = 0; ni < 4; ++ni) {
            int kb = wn + ni * 16 + (la >> 4) * 4;
#pragma unroll
            for (int j = 0; j < 4; ++j) {
                float e = (kb + j <= q) ? __expf(acc[mi][ni][j] - m) : 0.f;
                acc[mi][ni][j] = e;
                sm += e;
            }
        }
        sm += __shfl_xor(sm, 16);
        sm += __shfl_xor(sm, 32);
        tmp4[mi] = sm;
    }
    __syncthreads();                             // redm reads done before reds write (same region distinct, but order waves)
    if ((la >> 4) == 0) {
#pragma unroll
        for (int mi = 0; mi < 4; ++mi) reds[colh + wm + mi * 16 + la] = tmp4[mi];
    }
    __syncthreads();
#pragma unroll
    for (int mi = 0; mi < 4; ++mi) {            // pass 3: normalize, pack P -> sS
        int q = wm + mi * 16 + (la & 15);
        float inv = 1.f / (reds[q] + reds[128 + q]);
#pragma unroll
        for (int ni = 0; ni < 4; ++ni) {
            int kb = wn + ni * 16 + (la >> 4) * 4;
            us4 sv;
            sv.x = f2bf(acc[mi][ni][0] * inv); sv.y = f2bf(acc[mi][ni][1] * inv);
            sv.z = f2bf(acc[mi][ni][2] * inv); sv.w = f2bf(acc[mi][ni][3] * inv);
            *(us4*)(sS + q * 256 + ((2 * kb) ^ ((q & 7) << 4))) = sv;
        }
    }
    __syncthreads();                             // sS + sVT complete before PV

    // phase 4: O = P V  (wave tile 64M x 32N, K=128; swapped mfma -> packed O stores)
    const int wm2 = (w >> 1) * 64, wn2 = (w & 1) * 32;
    facc4 a2[4][2];
#pragma unroll
    for (int mi = 0; mi < 4; ++mi) { a2[mi][0] = zero4; a2[mi][1] = zero4; }
#pragma unroll
    for (int ks = 0; ks < 4; ++ks) {
        bfrag8 pa[4], vb[2];
        const int koffb = (ks * 32 + (la >> 4) * 8) * 2;
#pragma unroll
        for (int mi = 0; mi < 4; ++mi) {
            int rowa = wm2 + mi * 16 + (la & 15);
            pa[mi] = *(const bfrag8*)(sS + rowa * 256 + (koffb ^ ((rowa & 7) << 4)));
        }
#pragma unroll
        for (int ni = 0; ni < 2; ++ni) {
            int rowb = wn2 + ni * 16 + (la & 15);
            vb[ni] = *(const bfrag8*)(sVT + rowb * 256 + (koffb ^ ((rowb & 7) << 4)));
        }
#pragma unroll
        for (int mi = 0; mi < 4; ++mi)
#pragma unroll
            for (int ni = 0; ni < 2; ++ni)
                a2[mi][ni] = __builtin_amdgcn_mfma_f32_16x16x32_bf16(vb[ni], pa[mi], a2[mi][ni], 0, 0, 0);
    }
#pragma unroll
    for (int mi = 0; mi < 4; ++mi) {
        int s = wm2 + mi * 16 + (la & 15);
#pragma unroll
        for (int ni = 0; ni < 2; ++ni) {
            int db = wn2 + ni * 16 + (la >> 4) * 4;
            us4 ov;
            ov.x = f2bf(a2[mi][ni][0]); ov.y = f2bf(a2[mi][ni][1]);
            ov.z = f2bf(a2[mi][ni][2]); ov.w = f2bf(a2[mi][ni][3]);
            *(us4*)(obf + ((size_t)(b * 128 + s)) * 1024 + h * 64 + db) = ov;
        }
    }
}

// ------- fused residual + LayerNorm: t = xf + go(bf16); LN(t) -> xf, xb -------
__global__ __launch_bounds__(256) void ln_res_kernel(const bf16* __restrict__ go,
                                                     const float* __restrict__ xf_in,
                                                     const float* __restrict__ g, const float* __restrict__ be,
                                                     float* __restrict__ xf_out, bf16* __restrict__ xb_out)
{
    const int row = blockIdx.x, t = threadIdx.x;
    size_t o = (size_t)row * 1024 + t * 4;
    us4 gv4 = *(const us4*)(go + o);
    float4 xv = *(const float4*)(xf_in + o);
    float t0 = xv.x + bf2f(gv4.x);
    float t1 = xv.y + bf2f(gv4.y);
    float t2 = xv.z + bf2f(gv4.z);
    float t3 = xv.w + bf2f(gv4.w);
    float s = t0 + t1 + t2 + t3;
    float q = t0 * t0 + t1 * t1 + t2 * t2 + t3 * t3;
#pragma unroll
    for (int off = 32; off; off >>= 1) {
        s += __shfl_xor(s, off);
        q += __shfl_xor(q, off);
    }
    __shared__ float ssum[4], sqs[4];
    if ((t & 63) == 0) { ssum[t >> 6] = s; sqs[t >> 6] = q; }
    __syncthreads();
    s = ssum[0] + ssum[1] + ssum[2] + ssum[3];
    q = sqs[0] + sqs[1] + sqs[2] + sqs[3];
    float mean = s * (1.f / 1024.f);
    float var = q * (1.f / 1024.f) - mean * mean;
    float rstd = rsqrtf(var + 1e-5f);
    float4 gv = *(const float4*)(g + t * 4);
    float4 bv = *(const float4*)(be + t * 4);
    float o0 = (t0 - mean) * rstd * gv.x + bv.x;
    float o1 = (t1 - mean) * rstd * gv.y + bv.y;
    float o2 = (t2 - mean) * rstd * gv.z + bv.z;
    float o3 = (t3 - mean) * rstd * gv.w + bv.w;
    float4 of = {o0, o1, o2, o3};
    *(float4*)(xf_out + o) = of;
    us4 obv; obv.x = f2bf(o0); obv.y = f2bf(o1); obv.z = f2bf(o2); obv.w = f2bf(o3);
    *(us4*)(xb_out + o) = obv;
}

// ---------------- MDN finalize / scatter ----------------
__global__ void finalize_kernel(const float* __restrict__ hout, float* __restrict__ out) {
    const size_t O_PI_M = 0, O_MU_M = 32512, O_VAR_M = 552704, O_PI_V = 1072896,
                 O_MU_V = 1105408, O_VAR_V = 1625600, O_MASK = 2145792;
    int rm = blockIdx.x;                    // b*127+m, 4064 rows
    const float* hrow = hout + (size_t)rm * 529;
    int t = threadIdx.x;
    if (t < 128) {
        out[O_MU_M  + (size_t)rm * 128 + t] = hrow[9 + t];
        out[O_VAR_M + (size_t)rm * 128 + t] = expf(hrow[137 + t]);
        out[O_MU_V  + (size_t)rm * 128 + t] = hrow[273 + t];
        out[O_VAR_V + (size_t)rm * 128 + t] = expf(hrow[401 + t]);
    } else if (t == 128) {
        out[O_MASK + rm] = hrow[0];
    } else if (t == 129 || t == 130) {
        int boff = (t == 129) ? 1 : 265;
        size_t oo = ((t == 129) ? O_PI_M : O_PI_V) + (size_t)rm * 8;
        float v[8], mx = -1e30f;
#pragma unroll
        for (int j = 0; j < 8; ++j) { v[j] = hrow[boff + j]; mx = fmaxf(mx, v[j]); }
        float sm = 0.f;
#pragma unroll
        for (int j = 0; j < 8; ++j) { v[j] = expf(v[j] - mx); sm += v[j]; }
        float inv = 1.f / sm;
#pragma unroll
        for (int j = 0; j < 8; ++j) out[oo + j] = v[j] * inv;
    }
}

// ---------------- launcher ----------------
extern "C" void kernel_launch(void* const* d_in, const int* in_sizes, int n_in,
                              void* d_out, int out_size, void* d_ws, size_t ws_size,
                              hipStream_t stream) {
    (void)in_sizes; (void)n_in; (void)out_size; (void)ws_size;
    const float* input   = (const float*)d_in[0];
    const float* targets = (const float*)d_in[1];
    const float* W_emb   = (const float*)d_in[2];
    const float* b_emb   = (const float*)d_in[3];
    const float* sos     = (const float*)d_in[4];
    const float* Wqkv    = (const float*)d_in[5];
    const float* bqkv    = (const float*)d_in[6];
    const float* Wo      = (const float*)d_in[7];
    const float* bo      = (const float*)d_in[8];
    const float* W1      = (const float*)d_in[9];
    const float* b1      = (const float*)d_in[10];
    const float* W2      = (const float*)d_in[11];
    const float* b2      = (const float*)d_in[12];
    const float* g1      = (const float*)d_in[13];
    const float* be1     = (const float*)d_in[14];
    const float* g2      = (const float*)d_in[15];
    const float* be2     = (const float*)d_in[16];
    const float* Wm      = (const float*)d_in[17];
    const float* bm      = (const float*)d_in[18];
    const float* Wpi_m   = (const float*)d_in[19];
    const float* bpi_m   = (const float*)d_in[20];
    const float* Wmu_m   = (const float*)d_in[21];
    const float* bmu_m   = (const float*)d_in[22];
    const float* Wsg_m   = (const float*)d_in[23];
    const float* bsg_m   = (const float*)d_in[24];
    const float* Wpi_v   = (const float*)d_in[25];
    const float* bpi_v   = (const float*)d_in[26];
    const float* Wmu_v   = (const float*)d_in[27];
    const float* bmu_v   = (const float*)d_in[28];
    const float* Wsg_v   = (const float*)d_in[29];
    const float* bsg_v   = (const float*)d_in[30];
    float* out = (float*)d_out;

    char* ws = (char*)d_ws;                            // ~167 MB total
    float* pe      = (float*)(ws + 0);                 // 0.5 MB
    bf16*  xin     = (bf16*)(ws + 524288);             // 4.72 MB
    bf16*  wemb    = (bf16*)(ws + 5242880);            // 1.18 MB
    bf16*  whead   = (bf16*)(ws + 6422528);            // 1.31 MB (640 rows)
    float* bhead   = (float*)(ws + 7733248);           // 2.5 KB
    float* xf      = (float*)(ws + 7735808);           // 16.8 MB
    bf16*  xb      = (bf16*)(ws + 24513024);           // 8.4 MB
    bf16*  qkvb    = (bf16*)(ws + 32901632);           // 25.2 MB
    bf16*  ob      = (bf16*)(ws + 58067456);           // 8.4 MB (attn out, reused as FF hidden)
    bf16*  tmpb    = (bf16*)(ws + 66456064);           // 8.4 MB (gemm-out bf16, pre-LN)
    bf16*  wqb_all = (bf16*)(ws + 83233280);           // 37.7 MB (6 layers)
    bf16*  wob_all = (bf16*)(ws + 120982016);          // 12.6 MB
    bf16*  w1b_all = (bf16*)(ws + 133564928);          // 12.6 MB
    bf16*  w2b_all = (bf16*)(ws + 146147840);          // 12.6 MB
    float* hout    = (float*)(ws + 158730752);         // 8.6 MB

    prep_cvt_kernel<<<8576, 256, 0, stream>>>(input, targets, sos, W_emb,
                                              Wm, Wpi_m, Wmu_m, Wsg_m, Wpi_v, Wmu_v, Wsg_v,
                                              bm, bpi_m, bmu_m, bsg_m, bpi_v, bmu_v, bsg_v,
                                              Wqkv, Wo, W1, W2,
                                              pe, xin, wemb, whead, bhead,
                                              wqb_all, wob_all, w1b_all, w2b_all);
    // x = XIN @ Wemb^T + b + pe   -> xf (f32) + xb (bf16)
    gemm_bt<4, 1><<<dim3(8, 32, 1), 256, 0, stream>>>(xin, wemb, xf, xb, b_emb, nullptr, pe,
                                                      4096, 1024, 576, 576, 576, 1024, 0, 0);
    for (int l = 0; l < 6; ++l) {
        const bf16* wqb = wqb_all + (size_t)l * 3145728;
        const bf16* wob = wob_all + (size_t)l * 1048576;
        const bf16* w1b = w1b_all + (size_t)l * 1048576;
        const bf16* w2b = w2b_all + (size_t)l * 1048576;
        // qkv = x @ Wqkv^T + b  (bf16 out) -- 768 blocks, single-buffer, 3 blocks/CU
        gemm_bt<0, 0><<<dim3(24, 32, 1), 256, 0, stream>>>(xb, wqb, nullptr, qkvb, bqkv + l * 3072,
                                                           nullptr, nullptr, 4096, 3072, 1024, 1024, 1024, 3072, 0, 0);
        attn_fused<<<512, 256, 0, stream>>>(qkvb, ob);
        // go = o @ Wo^T + bo (bf16); residual folded into ln_res
        gemm_bt<0, 1><<<dim3(8, 32, 1), 256, 0, stream>>>(ob, wob, nullptr, tmpb, bo + l * 1024,
                                                          nullptr, nullptr, 4096, 1024, 1024, 1024, 1024, 1024, 0, 0);
        ln_res_kernel<<<4096, 256, 0, stream>>>(tmpb, xf, g1 + l * 1024, be1 + l * 1024, xf, xb);
        // t1 = relu(x @ W1^T + b1) (bf16, reuse ob)
        gemm_bt<1, 1><<<dim3(8, 32, 1), 256, 0, stream>>>(xb, w1b, nullptr, ob, b1 + l * 1024,
                                                          nullptr, nullptr, 4096, 1024, 1024, 1024, 1024, 1024, 0, 0);
        // go = t1 @ W2^T + b2 (bf16); residual folded into ln_res
        gemm_bt<0, 1><<<dim3(8, 32, 1), 256, 0, stream>>>(ob, w2b, nullptr, tmpb, b2 + l * 1024,
                                                          nullptr, nullptr, 4096, 1024, 1024, 1024, 1024, 1024, 0, 0);
        ln_res_kernel<<<4096, 256, 0, stream>>>(tmpb, xf, g2 + l * 1024, be2 + l * 1024, xf, xb);
    }
    // heads: per-batch M=127 rows of x -> hout (B,127,529) -- 160 blocks, dbuf
    gemm_bt<3, 1><<<dim3(5, 1, 32), 256, 0, stream>>>(xb, whead, hout, nullptr, bhead, nullptr, nullptr,
                                                      127, 529, 1024, 1024, 1024, 529, 131072LL, 67183LL);
    finalize_kernel<<<4064, 256, 0, stream>>>(hout, out);
}

// Round 9
// 773.891 us; speedup vs baseline: 1.3332x; 1.0551x over previous
//
#include <hip/hip_runtime.h>
#include <hip/hip_bf16.h>

typedef __hip_bfloat16 bf16;
typedef __attribute__((ext_vector_type(8))) short bfrag8;   // 8 bf16 (4 VGPR) MFMA A/B frag
typedef __attribute__((ext_vector_type(4))) float facc4;    // MFMA C/D frag
typedef __attribute__((ext_vector_type(4))) unsigned short us4;
typedef __attribute__((ext_vector_type(8))) unsigned short us8;
typedef __attribute__((ext_vector_type(4))) float f32x4;    // true clang vector (for nontemporal)

#define AS1C const __attribute__((address_space(1))) void
#define AS3  __attribute__((address_space(3))) void

__device__ __forceinline__ void gload_lds16(const void* src, void* dst) {
    __builtin_amdgcn_global_load_lds((AS1C*)src, (AS3*)dst, 16, 0, 0);
}

__device__ __forceinline__ unsigned short f2bf(float f) {   // RNE, finite inputs
    unsigned u = __float_as_uint(f);
    unsigned r = u + 0x7FFFu + ((u >> 16) & 1u);
    return (unsigned short)(r >> 16);
}
__device__ __forceinline__ float bf2f(unsigned short u) {   // exact
    return __uint_as_float((unsigned)u << 16);
}

// ------- merged prep+cvt kernel: weight cvt FIRST (heavy), tiny prep fills tail -------
// bid [0,4608): weight fp32->bf16, 768 blocks/layer (384 qkv, 128 wo/w1/w2), 4 iters/thread
// bid [4608,5120): pe | [5120,9216): xin | [9216,10240): wemb | [10240,10880): whead
__global__ void prep_cvt_kernel(const float* __restrict__ input, const float* __restrict__ targets,
                                const float* __restrict__ sos, const float* __restrict__ W_emb,
                                const float* __restrict__ Wm, const float* __restrict__ Wpi_m,
                                const float* __restrict__ Wmu_m, const float* __restrict__ Wsg_m,
                                const float* __restrict__ Wpi_v, const float* __restrict__ Wmu_v,
                                const float* __restrict__ Wsg_v,
                                const float* __restrict__ bm, const float* __restrict__ bpi_m,
                                const float* __restrict__ bmu_m, const float* __restrict__ bsg_m,
                                const float* __restrict__ bpi_v, const float* __restrict__ bmu_v,
                                const float* __restrict__ bsg_v,
                                const float* __restrict__ Wqkv, const float* __restrict__ Wo,
                                const float* __restrict__ W1, const float* __restrict__ W2,
                                float* __restrict__ pe, bf16* __restrict__ xin,
                                bf16* __restrict__ wemb, bf16* __restrict__ whead,
                                float* __restrict__ bhead,
                                bf16* __restrict__ wqb, bf16* __restrict__ wob,
                                bf16* __restrict__ w1b, bf16* __restrict__ w2b) {
    int bid = blockIdx.x;
    if (bid < 4608) {                                    // weight cvt (NT loads, 16B stores)
        int l = bid / 768;
        int s = bid - l * 768;
        const float* src; bf16* dst;
        if (s < 384)      { src = Wqkv + (size_t)l * 3145728; dst = wqb + (size_t)l * 3145728; }
        else if (s < 512) { src = Wo + (size_t)l * 1048576; dst = wob + (size_t)l * 1048576; s -= 384; }
        else if (s < 640) { src = W1 + (size_t)l * 1048576; dst = w1b + (size_t)l * 1048576; s -= 512; }
        else              { src = W2 + (size_t)l * 1048576; dst = w2b + (size_t)l * 1048576; s -= 640; }
        size_t pbase = (size_t)s * 1024 + threadIdx.x;
#pragma unroll
        for (int it = 0; it < 4; ++it) {
            size_t o = (pbase + it * 256) * 8;           // 8 floats per pair
            const f32x4* p = (const f32x4*)(src + o);
            f32x4 v1 = __builtin_nontemporal_load(p);
            f32x4 v2 = __builtin_nontemporal_load(p + 1);
            us8 w8;
            w8[0] = f2bf(v1.x); w8[1] = f2bf(v1.y); w8[2] = f2bf(v1.z); w8[3] = f2bf(v1.w);
            w8[4] = f2bf(v2.x); w8[5] = f2bf(v2.y); w8[6] = f2bf(v2.z); w8[7] = f2bf(v2.w);
            *(us8*)(dst + o) = w8;
        }
    } else if (bid < 5120) {                             // pe [128][1024]
        int idx = (bid - 4608) * 256 + threadIdx.x;
        int s = idx >> 10, c = idx & 1023;
        int i = c >> 1;
        float div = expf(-9.210340371976184f * (float)(2 * i) * (1.f / 1024.f));
        float a = (float)s * div;
        pe[idx] = (c & 1) ? cosf(a) : sinf(a);
    } else if (bid < 5120 + 4096) {                      // xin row (b*128+s), pad K->576
        int row = bid - 5120;
        int b = row >> 7, s = row & 127;
        for (int c = threadIdx.x; c < 576; c += 256) {
            float v = 0.f;
            if (c < 512) v = input[b * 512 + c];
            else if (c < 545) {
                int j = c - 512;
                v = (s == 0) ? sos[j] : targets[((size_t)b * 127 + (s - 1)) * 33 + j];
            }
            xin[(size_t)row * 576 + c] = __float2bfloat16(v);
        }
    } else if (bid < 5120 + 4096 + 1024) {               // wemb row, pad 545->576
        int row = bid - (5120 + 4096);
        for (int c = threadIdx.x; c < 576; c += 256)
            wemb[(size_t)row * 576 + c] = __float2bfloat16(c < 545 ? W_emb[(size_t)row * 545 + c] : 0.f);
    } else {                                             // whead row (640 = 529 real + pad)
        int r = bid - (5120 + 4096 + 1024);
        const float* wsrc = nullptr; const float* bsrc = nullptr; int off = 0;
        if (r == 0)        { wsrc = Wm;    bsrc = bm;    off = 0; }
        else if (r < 9)    { wsrc = Wpi_m; bsrc = bpi_m; off = r - 1; }
        else if (r < 137)  { wsrc = Wmu_m; bsrc = bmu_m; off = r - 9; }
        else if (r < 265)  { wsrc = Wsg_m; bsrc = bsg_m; off = r - 137; }
        else if (r < 273)  { wsrc = Wpi_v; bsrc = bpi_v; off = r - 265; }
        else if (r < 401)  { wsrc = Wmu_v; bsrc = bmu_v; off = r - 273; }
        else if (r < 529)  { wsrc = Wsg_v; bsrc = bsg_v; off = r - 401; }
        for (int c = threadIdx.x; c < 1024; c += 256)
            whead[(size_t)r * 1024 + c] = __float2bfloat16(wsrc ? wsrc[(size_t)off * 1024 + c] : 0.f);
        if (threadIdx.x == 0 && wsrc) bhead[r] = bsrc[off];
    }
}

// ---------------- main GEMM: C[M,N] = A[M,K] @ B[N,K]^T (+epilogue) ----------------
// 128x128 tile, BK=64, 4 waves. Operand-swapped MFMA (C^T frags -> vectorized epilogue).
// DBUF=1: simple prefetch dbuf for grid-limited (<=256-block) launches.
// DBUF=0: single-buffer, 3 blocks/CU (cross-block overlap regime) for QKV (768 blocks).
// EPI: 0 bias->bf16 | 1 bias+relu->bf16 | 3 bias->f32 scalar (odd ldc) | 4 bias+pe->bf16
template<int EPI, int DBUF>
__global__ __launch_bounds__(256, DBUF ? 2 : 3) void gemm_bt(
    const bf16* __restrict__ A, const bf16* __restrict__ Bw,
    float* __restrict__ Cf, bf16* __restrict__ Cb,
    const float* __restrict__ bias, const float* __restrict__ pe,
    int M, int N, int K, int lda, int ldb, int ldc, long long Az, long long Cz)
{
    __shared__ __align__(16) bf16 sA[DBUF ? 2 : 1][128 * 64];
    __shared__ __align__(16) bf16 sB[DBUF ? 2 : 1][128 * 64];
    const int t = threadIdx.x;
    const int w = t >> 6, la = t & 63;
    const int wm = (w >> 1) * 64, wn = (w & 1) * 64;
    const int m0 = blockIdx.y * 128, n0 = blockIdx.x * 128;
    const int z = blockIdx.z;
    A += (long long)z * Az;

    const int c0 = w * 64 + la;
    facc4 zero4 = {0.f, 0.f, 0.f, 0.f};
    facc4 acc[4][4];
#pragma unroll
    for (int mi = 0; mi < 4; ++mi)
#pragma unroll
        for (int ni = 0; ni < 4; ++ni) acc[mi][ni] = zero4;

    auto stage = [&](int buf, int kt) {                 // 8 gload_lds (4 A + 4 B)
#pragma unroll
        for (int i = 0; i < 4; ++i) {
            int c = i * 256 + c0;
            int r = c >> 3;
            int bc = ((c & 7) * 16) ^ ((r & 7) << 4);   // pre-swizzled source byte col
            gload_lds16(A + (size_t)(m0 + r) * lda + kt + (bc >> 1),
                        (char*)sA[buf] + (size_t)(i * 256 + c0) * 16);
            gload_lds16(Bw + (size_t)(n0 + r) * ldb + kt + (bc >> 1),
                        (char*)sB[buf] + (size_t)(i * 256 + c0) * 16);
        }
    };
    auto compute = [&](int buf) {
#pragma unroll
        for (int ks = 0; ks < 2; ++ks) {
            bfrag8 af[4], bfv[4];
            const int koffb = (ks * 32 + (la >> 4) * 8) * 2;
#pragma unroll
            for (int i = 0; i < 4; ++i) {
                int rowa = wm + i * 16 + (la & 15);
                af[i] = *(const bfrag8*)((const char*)sA[buf] + rowa * 128 + (koffb ^ ((rowa & 7) << 4)));
                int rowb = wn + i * 16 + (la & 15);
                bfv[i] = *(const bfrag8*)((const char*)sB[buf] + rowb * 128 + (koffb ^ ((rowb & 7) << 4)));
            }
#pragma unroll
            for (int mi = 0; mi < 4; ++mi)
#pragma unroll
                for (int ni = 0; ni < 4; ++ni)     // swapped operands -> C^T fragment
                    acc[mi][ni] = __builtin_amdgcn_mfma_f32_16x16x32_bf16(bfv[ni], af[mi], acc[mi][ni], 0, 0, 0);
        }
    };

    const int nk = K >> 6;
    if constexpr (DBUF) {
        stage(0, 0);
        __syncthreads();
        int cur = 0;
        for (int kt = 0; kt < nk; ++kt) {
            if (kt + 1 < nk) stage(cur ^ 1, (kt + 1) << 6);
            compute(cur);
            __syncthreads();        // drains stage(k+1) vmcnt; frees cur
            cur ^= 1;
        }
    } else {
        for (int kt = 0; kt < nk; ++kt) {
            stage(0, kt << 6);
            __syncthreads();
            compute(0);
            __syncthreads();
        }
    }
    // epilogue: thread holds C[row][colb..colb+3]
#pragma unroll
    for (int mi = 0; mi < 4; ++mi) {
        int row = m0 + wm + mi * 16 + (la & 15);
#pragma unroll
        for (int ni = 0; ni < 4; ++ni) {
            int colb = n0 + wn + ni * 16 + (la >> 4) * 4;
            if constexpr (EPI == 3) {               // scalar path (odd ldc / edge guards)
                if (row >= M) continue;
#pragma unroll
                for (int j = 0; j < 4; ++j) {
                    int col = colb + j;
                    if (col < N)
                        Cf[(size_t)z * Cz + (size_t)row * ldc + col] = acc[mi][ni][j] + bias[col];
                }
            } else {
                float4 bv = *(const float4*)(bias + colb);
                facc4 v = acc[mi][ni];
                v[0] += bv.x; v[1] += bv.y; v[2] += bv.z; v[3] += bv.w;
                size_t cidx = (size_t)row * ldc + colb;
                if constexpr (EPI == 0) {
                    us4 o; o.x = f2bf(v[0]); o.y = f2bf(v[1]); o.z = f2bf(v[2]); o.w = f2bf(v[3]);
                    *(us4*)(Cb + cidx) = o;
                } else if constexpr (EPI == 1) {
                    us4 o;
                    o.x = f2bf(v[0] > 0.f ? v[0] : 0.f); o.y = f2bf(v[1] > 0.f ? v[1] : 0.f);
                    o.z = f2bf(v[2] > 0.f ? v[2] : 0.f); o.w = f2bf(v[3] > 0.f ? v[3] : 0.f);
                    *(us4*)(Cb + cidx) = o;
                } else {                            // EPI == 4: bias + pe -> bf16
                    float4 p = *(const float4*)(pe + (size_t)(row & 127) * 1024 + colb);
                    us4 o;
                    o.x = f2bf(v[0] + p.x); o.y = f2bf(v[1] + p.y);
                    o.z = f2bf(v[2] + p.z); o.w = f2bf(v[3] + p.w);
                    *(us4*)(Cb + cidx) = o;
                }
            }
        }
    }
}

// ---------------- fused attention: one block per (b,h) ----------------
// S=128, D=64. Swapped QK^T keeps S rows lane-local -> in-register causal softmax.
__global__ __launch_bounds__(256) void attn_fused(const bf16* __restrict__ qkv, bf16* __restrict__ obf)
{
    __shared__ __align__(16) char lds[65536];
    char* sQ  = lds;            // [128] rows x 128B, swizzled
    char* sK  = lds + 16384;    // [128] rows x 128B (dead after QK^T -> red arrays)
    char* sS  = lds + 32768;    // [128] rows x 256B bf16 (P)
    char* sVT = lds;            // [64] rows x 256B (V transposed), overlaps sQ
    float* redm = (float*)(lds + 16384);            // [2][128] row max per col-half
    float* reds = (float*)(lds + 16384 + 1024);     // [2][128] row sum per col-half

    const int t = threadIdx.x, w = t >> 6, la = t & 63;
    const int b = blockIdx.x >> 4, h = blockIdx.x & 15;
    const size_t base = (size_t)b * 128 * 3072 + (size_t)h * 64;

    // phase 1: stage Q, K (swizzled via pre-swizzled source)
#pragma unroll
    for (int i = 0; i < 4; ++i) {
        int c = i * 256 + w * 64 + la;
        int r = c >> 3;
        int bc = ((c & 7) * 16) ^ ((r & 7) << 4);
        gload_lds16(qkv + base + (size_t)r * 3072 + (bc >> 1),
                    sQ + (size_t)(i * 256 + w * 64) * 16);
        gload_lds16(qkv + base + 1024 + (size_t)r * 3072 + (bc >> 1),
                    sK + (size_t)(i * 256 + w * 64) * 16);
    }
    __syncthreads();

    // phase 2: S = Q K^T (swapped mfma -> thread holds S[q][kb..kb+3], fp32)
    const int wm = (w >> 1) * 64, wn = (w & 1) * 64;
    facc4 zero4 = {0.f, 0.f, 0.f, 0.f};
    facc4 acc[4][4];
#pragma unroll
    for (int mi = 0; mi < 4; ++mi)
#pragma unroll
        for (int ni = 0; ni < 4; ++ni) acc[mi][ni] = zero4;
#pragma unroll
    for (int ks = 0; ks < 2; ++ks) {
        bfrag8 af[4], bfv[4];
        const int koffb = (ks * 32 + (la >> 4) * 8) * 2;
#pragma unroll
        for (int i = 0; i < 4; ++i) {
            int rowa = wm + i * 16 + (la & 15);
            af[i] = *(const bfrag8*)(sQ + rowa * 128 + (koffb ^ ((rowa & 7) << 4)));
            int rowb = wn + i * 16 + (la & 15);
            bfv[i] = *(const bfrag8*)(sK + rowb * 128 + (koffb ^ ((rowb & 7) << 4)));
        }
#pragma unroll
        for (int mi = 0; mi < 4; ++mi)
#pragma unroll
            for (int ni = 0; ni < 4; ++ni)
                acc[mi][ni] = __builtin_amdgcn_mfma_f32_16x16x32_bf16(bfv[ni], af[mi], acc[mi][ni], 0, 0, 0);
    }
    __syncthreads();        // all waves done reading sQ/sK

    // phase 3a: stage V transposed into sVT (overlaps softmax VALU below)
#pragma unroll
    for (int i = 0; i < 4; ++i) {
        int c = i * 256 + t;
        int r = c >> 3;             // key index s'
        int d0 = (c & 7) * 8;
        bfrag8 vv = *(const bfrag8*)(qkv + base + 2048 + (size_t)r * 3072 + d0);
#pragma unroll
        for (int j = 0; j < 8; ++j) {
            int d = d0 + j;
            *(short*)(sVT + d * 256 + ((2 * r) ^ ((d & 7) << 4))) = vv[j];
        }
    }

    // phase 3b: in-register causal softmax
    const int colh = (w & 1) * 128;
    float tmp4[4];
#pragma unroll
    for (int mi = 0; mi < 4; ++mi) {            // pass 1: scale, mask, wave-half max
        int q = wm + mi * 16 + (la & 15);
        float mx = -1e30f;
#pragma unroll
        for (int ni = 0; ni < 4; ++ni) {
            int kb = wn + ni * 16 + (la >> 4) * 4;
#pragma unroll
            for (int j = 0; j < 4; ++j) {
                float s = acc[mi][ni][j] * 0.125f;
                acc[mi][ni][j] = s;
                if (kb + j <= q) mx = fmaxf(mx, s);
            }
        }
        mx = fmaxf(mx, __shfl_xor(mx, 16));     // reduce over la>>4 (the k-axis lanes)
        mx = fmaxf(mx, __shfl_xor(mx, 32));
        tmp4[mi] = mx;
    }
    if ((la >> 4) == 0) {
#pragma unroll
        for (int mi = 0; mi < 4; ++mi) redm[colh + wm + mi * 16 + la] = tmp4[mi];
    }
    __syncthreads();
#pragma unroll
    for (int mi = 0; mi < 4; ++mi) {            // pass 2: exp, wave-half sum
        int q = wm + mi * 16 + (la & 15);
        float m = fmaxf(redm[q], redm[128 + q]);
        float sm = 0.f;
#pragma unroll
        for (int ni = 0; ni < 4; ++ni) {
            int kb = wn + ni * 16 + (la >> 4) * 4;
#pragma unroll
            for (int j = 0; j < 4; ++j) {
                float e = (kb + j <= q) ? __expf(acc[mi][ni][j] - m) : 0.f;
                acc[mi][ni][j] = e;
                sm += e;
            }
        }
        sm += __shfl_xor(sm, 16);
        sm += __shfl_xor(sm, 32);
        tmp4[mi] = sm;
    }
    __syncthreads();
    if ((la >> 4) == 0) {
#pragma unroll
        for (int mi = 0; mi < 4; ++mi) reds[colh + wm + mi * 16 + la] = tmp4[mi];
    }
    __syncthreads();
#pragma unroll
    for (int mi = 0; mi < 4; ++mi) {            // pass 3: normalize, pack P -> sS
        int q = wm + mi * 16 + (la & 15);
        float inv = 1.f / (reds[q] + reds[128 + q]);
#pragma unroll
        for (int ni = 0; ni < 4; ++ni) {
            int kb = wn + ni * 16 + (la >> 4) * 4;
            us4 sv;
            sv.x = f2bf(acc[mi][ni][0] * inv); sv.y = f2bf(acc[mi][ni][1] * inv);
            sv.z = f2bf(acc[mi][ni][2] * inv); sv.w = f2bf(acc[mi][ni][3] * inv);
            *(us4*)(sS + q * 256 + ((2 * kb) ^ ((q & 7) << 4))) = sv;
        }
    }
    __syncthreads();                             // sS + sVT complete before PV

    // phase 4: O = P V  (wave tile 64M x 32N, K=128; swapped mfma -> packed O stores)
    const int wm2 = (w >> 1) * 64, wn2 = (w & 1) * 32;
    facc4 a2[4][2];
#pragma unroll
    for (int mi = 0; mi < 4; ++mi) { a2[mi][0] = zero4; a2[mi][1] = zero4; }
#pragma unroll
    for (int ks = 0; ks < 4; ++ks) {
        bfrag8 pa[4], vb[2];
        const int koffb = (ks * 32 + (la >> 4) * 8) * 2;
#pragma unroll
        for (int mi = 0; mi < 4; ++mi) {
            int rowa = wm2 + mi * 16 + (la & 15);
            pa[mi] = *(const bfrag8*)(sS + rowa * 256 + (koffb ^ ((rowa & 7) << 4)));
        }
#pragma unroll
        for (int ni = 0; ni < 2; ++ni) {
            int rowb = wn2 + ni * 16 + (la & 15);
            vb[ni] = *(const bfrag8*)(sVT + rowb * 256 + (koffb ^ ((rowb & 7) << 4)));
        }
#pragma unroll
        for (int mi = 0; mi < 4; ++mi)
#pragma unroll
            for (int ni = 0; ni < 2; ++ni)
                a2[mi][ni] = __builtin_amdgcn_mfma_f32_16x16x32_bf16(vb[ni], pa[mi], a2[mi][ni], 0, 0, 0);
    }
#pragma unroll
    for (int mi = 0; mi < 4; ++mi) {
        int s = wm2 + mi * 16 + (la & 15);
#pragma unroll
        for (int ni = 0; ni < 2; ++ni) {
            int db = wn2 + ni * 16 + (la >> 4) * 4;
            us4 ov;
            ov.x = f2bf(a2[mi][ni][0]); ov.y = f2bf(a2[mi][ni][1]);
            ov.z = f2bf(a2[mi][ni][2]); ov.w = f2bf(a2[mi][ni][3]);
            *(us4*)(obf + ((size_t)(b * 128 + s)) * 1024 + h * 64 + db) = ov;
        }
    }
}

// ------- fused residual + LayerNorm, all-bf16 stream: t = res + go; LN(t) -> xb -------
// LN renormalizes every half-layer, so the bf16 carrier never accumulates more than
// one add of rounding error. In-place res==xb_out is safe (element-owned).
__global__ __launch_bounds__(256) void ln_res_kernel(const bf16* __restrict__ go,
                                                     const bf16* __restrict__ res,
                                                     const float* __restrict__ g, const float* __restrict__ be,
                                                     bf16* __restrict__ xb_out)
{
    const int row = blockIdx.x, t = threadIdx.x;
    size_t o = (size_t)row * 1024 + t * 4;
    us4 gv4 = *(const us4*)(go + o);
    us4 rv4 = *(const us4*)(res + o);
    float t0 = bf2f(rv4.x) + bf2f(gv4.x);
    float t1 = bf2f(rv4.y) + bf2f(gv4.y);
    float t2 = bf2f(rv4.z) + bf2f(gv4.z);
    float t3 = bf2f(rv4.w) + bf2f(gv4.w);
    float s = t0 + t1 + t2 + t3;
    float q = t0 * t0 + t1 * t1 + t2 * t2 + t3 * t3;
#pragma unroll
    for (int off = 32; off; off >>= 1) {
        s += __shfl_xor(s, off);
        q += __shfl_xor(q, off);
    }
    __shared__ float ssum[4], sqs[4];
    if ((t & 63) == 0) { ssum[t >> 6] = s; sqs[t >> 6] = q; }
    __syncthreads();
    s = ssum[0] + ssum[1] + ssum[2] + ssum[3];
    q = sqs[0] + sqs[1] + sqs[2] + sqs[3];
    float mean = s * (1.f / 1024.f);
    float var = q * (1.f / 1024.f) - mean * mean;
    float rstd = rsqrtf(var + 1e-5f);
    float4 gv = *(const float4*)(g + t * 4);
    float4 bv = *(const float4*)(be + t * 4);
    float o0 = (t0 - mean) * rstd * gv.x + bv.x;
    float o1 = (t1 - mean) * rstd * gv.y + bv.y;
    float o2 = (t2 - mean) * rstd * gv.z + bv.z;
    float o3 = (t3 - mean) * rstd * gv.w + bv.w;
    us4 obv; obv.x = f2bf(o0); obv.y = f2bf(o1); obv.z = f2bf(o2); obv.w = f2bf(o3);
    *(us4*)(xb_out + o) = obv;
}

// ---------------- MDN finalize / scatter ----------------
__global__ void finalize_kernel(const float* __restrict__ hout, float* __restrict__ out) {
    const size_t O_PI_M = 0, O_MU_M = 32512, O_VAR_M = 552704, O_PI_V = 1072896,
                 O_MU_V = 1105408, O_VAR_V = 1625600, O_MASK = 2145792;
    int rm = blockIdx.x;                    // b*127+m, 4064 rows
    const float* hrow = hout + (size_t)rm * 529;
    int t = threadIdx.x;
    if (t < 128) {
        out[O_MU_M  + (size_t)rm * 128 + t] = hrow[9 + t];
        out[O_VAR_M + (size_t)rm * 128 + t] = expf(hrow[137 + t]);
        out[O_MU_V  + (size_t)rm * 128 + t] = hrow[273 + t];
        out[O_VAR_V + (size_t)rm * 128 + t] = expf(hrow[401 + t]);
    } else if (t == 128) {
        out[O_MASK + rm] = hrow[0];
    } else if (t == 129 || t == 130) {
        int boff = (t == 129) ? 1 : 265;
        size_t oo = ((t == 129) ? O_PI_M : O_PI_V) + (size_t)rm * 8;
        float v[8], mx = -1e30f;
#pragma unroll
        for (int j = 0; j < 8; ++j) { v[j] = hrow[boff + j]; mx = fmaxf(mx, v[j]); }
        float sm = 0.f;
#pragma unroll
        for (int j = 0; j < 8; ++j) { v[j] = expf(v[j] - mx); sm += v[j]; }
        float inv = 1.f / sm;
#pragma unroll
        for (int j = 0; j < 8; ++j) out[oo + j] = v[j] * inv;
    }
}

// ---------------- launcher ----------------
extern "C" void kernel_launch(void* const* d_in, const int* in_sizes, int n_in,
                              void* d_out, int out_size, void* d_ws, size_t ws_size,
                              hipStream_t stream) {
    (void)in_sizes; (void)n_in; (void)out_size; (void)ws_size;
    const float* input   = (const float*)d_in[0];
    const float* targets = (const float*)d_in[1];
    const float* W_emb   = (const float*)d_in[2];
    const float* b_emb   = (const float*)d_in[3];
    const float* sos     = (const float*)d_in[4];
    const float* Wqkv    = (const float*)d_in[5];
    const float* bqkv    = (const float*)d_in[6];
    const float* Wo      = (const float*)d_in[7];
    const float* bo      = (const float*)d_in[8];
    const float* W1      = (const float*)d_in[9];
    const float* b1      = (const float*)d_in[10];
    const float* W2      = (const float*)d_in[11];
    const float* b2      = (const float*)d_in[12];
    const float* g1      = (const float*)d_in[13];
    const float* be1     = (const float*)d_in[14];
    const float* g2      = (const float*)d_in[15];
    const float* be2     = (const float*)d_in[16];
    const float* Wm      = (const float*)d_in[17];
    const float* bm      = (const float*)d_in[18];
    const float* Wpi_m   = (const float*)d_in[19];
    const float* bpi_m   = (const float*)d_in[20];
    const float* Wmu_m   = (const float*)d_in[21];
    const float* bmu_m   = (const float*)d_in[22];
    const float* Wsg_m   = (const float*)d_in[23];
    const float* bsg_m   = (const float*)d_in[24];
    const float* Wpi_v   = (const float*)d_in[25];
    const float* bpi_v   = (const float*)d_in[26];
    const float* Wmu_v   = (const float*)d_in[27];
    const float* bmu_v   = (const float*)d_in[28];
    const float* Wsg_v   = (const float*)d_in[29];
    const float* bsg_v   = (const float*)d_in[30];
    float* out = (float*)d_out;

    char* ws = (char*)d_ws;                            // ~167 MB total (xf slot now unused)
    float* pe      = (float*)(ws + 0);                 // 0.5 MB
    bf16*  xin     = (bf16*)(ws + 524288);             // 4.72 MB
    bf16*  wemb    = (bf16*)(ws + 5242880);            // 1.18 MB
    bf16*  whead   = (bf16*)(ws + 6422528);            // 1.31 MB (640 rows)
    float* bhead   = (float*)(ws + 7733248);           // 2.5 KB
    bf16*  xb      = (bf16*)(ws + 24513024);           // 8.4 MB (bf16 residual stream + GEMM input)
    bf16*  qkvb    = (bf16*)(ws + 32901632);           // 25.2 MB
    bf16*  ob      = (bf16*)(ws + 58067456);           // 8.4 MB (attn out, reused as FF hidden)
    bf16*  tmpb    = (bf16*)(ws + 66456064);           // 8.4 MB (gemm-out bf16, pre-LN)
    bf16*  wqb_all = (bf16*)(ws + 83233280);           // 37.7 MB (6 layers)
    bf16*  wob_all = (bf16*)(ws + 120982016);          // 12.6 MB
    bf16*  w1b_all = (bf16*)(ws + 133564928);          // 12.6 MB
    bf16*  w2b_all = (bf16*)(ws + 146147840);          // 12.6 MB
    float* hout    = (float*)(ws + 158730752);         // 8.6 MB

    prep_cvt_kernel<<<10880, 256, 0, stream>>>(input, targets, sos, W_emb,
                                               Wm, Wpi_m, Wmu_m, Wsg_m, Wpi_v, Wmu_v, Wsg_v,
                                               bm, bpi_m, bmu_m, bsg_m, bpi_v, bmu_v, bsg_v,
                                               Wqkv, Wo, W1, W2,
                                               pe, xin, wemb, whead, bhead,
                                               wqb_all, wob_all, w1b_all, w2b_all);
    // x = XIN @ Wemb^T + b + pe -> xb (bf16 residual stream)
    gemm_bt<4, 1><<<dim3(8, 32, 1), 256, 0, stream>>>(xin, wemb, nullptr, xb, b_emb, pe,
                                                      4096, 1024, 576, 576, 576, 1024, 0, 0);
    for (int l = 0; l < 6; ++l) {
        const bf16* wqb = wqb_all + (size_t)l * 3145728;
        const bf16* wob = wob_all + (size_t)l * 1048576;
        const bf16* w1b = w1b_all + (size_t)l * 1048576;
        const bf16* w2b = w2b_all + (size_t)l * 1048576;
        // qkv = x @ Wqkv^T + b  (bf16 out) -- 768 blocks, single-buffer, 3 blocks/CU
        gemm_bt<0, 0><<<dim3(24, 32, 1), 256, 0, stream>>>(xb, wqb, nullptr, qkvb, bqkv + l * 3072,
                                                           nullptr, 4096, 3072, 1024, 1024, 1024, 3072, 0, 0);
        attn_fused<<<512, 256, 0, stream>>>(qkvb, ob);
        // go = o @ Wo^T + bo (bf16); residual folded into ln_res
        gemm_bt<0, 1><<<dim3(8, 32, 1), 256, 0, stream>>>(ob, wob, nullptr, tmpb, bo + l * 1024,
                                                          nullptr, 4096, 1024, 1024, 1024, 1024, 1024, 0, 0);
        ln_res_kernel<<<4096, 256, 0, stream>>>(tmpb, xb, g1 + l * 1024, be1 + l * 1024, xb);
        // t1 = relu(x @ W1^T + b1) (bf16, reuse ob)
        gemm_bt<1, 1><<<dim3(8, 32, 1), 256, 0, stream>>>(xb, w1b, nullptr, ob, b1 + l * 1024,
                                                          nullptr, 4096, 1024, 1024, 1024, 1024, 1024, 0, 0);
        // go = t1 @ W2^T + b2 (bf16); residual folded into ln_res
        gemm_bt<0, 1><<<dim3(8, 32, 1), 256, 0, stream>>>(ob, w2b, nullptr, tmpb, b2 + l * 1024,
                                                          nullptr, 4096, 1024, 1024, 1024, 1024, 1024, 0, 0);
        ln_res_kernel<<<4096, 256, 0, stream>>>(tmpb, xb, g2 + l * 1024, be2 + l * 1024, xb);
    }
    // heads: per-batch M=127 rows of x -> hout (B,127,529) -- 160 blocks, dbuf
    gemm_bt<3, 1><<<dim3(5, 1, 32), 256, 0, stream>>>(xb, whead, hout, nullptr, bhead, nullptr,
                                                      127, 529, 1024, 1024, 1024, 529, 131072LL, 67183LL);
    finalize_kernel<<<4064, 256, 0, stream>>>(hout, out);
}

// Round 10
// 766.386 us; speedup vs baseline: 1.3462x; 1.0098x over previous
//
#include <hip/hip_runtime.h>
#include <hip/hip_bf16.h>

typedef __hip_bfloat16 bf16;
typedef __attribute__((ext_vector_type(8))) short bfrag8;   // 8 bf16 (4 VGPR) MFMA A/B frag
typedef __attribute__((ext_vector_type(4))) float facc4;    // MFMA C/D frag
typedef __attribute__((ext_vector_type(4))) unsigned short us4;
typedef __attribute__((ext_vector_type(8))) unsigned short us8;
typedef __attribute__((ext_vector_type(4))) float f32x4;    // true clang vector (for nontemporal)

#define AS1C const __attribute__((address_space(1))) void
#define AS3  __attribute__((address_space(3))) void

__device__ __forceinline__ void gload_lds16(const void* src, void* dst) {
    __builtin_amdgcn_global_load_lds((AS1C*)src, (AS3*)dst, 16, 0, 0);
}

__device__ __forceinline__ unsigned short f2bf(float f) {   // RNE, finite inputs
    unsigned u = __float_as_uint(f);
    unsigned r = u + 0x7FFFu + ((u >> 16) & 1u);
    return (unsigned short)(r >> 16);
}
__device__ __forceinline__ float bf2f(unsigned short u) {   // exact
    return __uint_as_float((unsigned)u << 16);
}

// ------- merged prep+cvt: weights first (heavy), DENSE vectorized tail -------
// [0,4608): weight cvt | [4608,4736): pe | [4736,5888): xin | [5888,6176): wemb
// [6176,6496): whead | 6496: bhead
__global__ void prep_cvt_kernel(const float* __restrict__ input, const float* __restrict__ targets,
                                const float* __restrict__ sos, const float* __restrict__ W_emb,
                                const float* __restrict__ Wm, const float* __restrict__ Wpi_m,
                                const float* __restrict__ Wmu_m, const float* __restrict__ Wsg_m,
                                const float* __restrict__ Wpi_v, const float* __restrict__ Wmu_v,
                                const float* __restrict__ Wsg_v,
                                const float* __restrict__ bm, const float* __restrict__ bpi_m,
                                const float* __restrict__ bmu_m, const float* __restrict__ bsg_m,
                                const float* __restrict__ bpi_v, const float* __restrict__ bmu_v,
                                const float* __restrict__ bsg_v,
                                const float* __restrict__ Wqkv, const float* __restrict__ Wo,
                                const float* __restrict__ W1, const float* __restrict__ W2,
                                float* __restrict__ pe, bf16* __restrict__ xin,
                                bf16* __restrict__ wemb, bf16* __restrict__ whead,
                                float* __restrict__ bhead,
                                bf16* __restrict__ wqb, bf16* __restrict__ wob,
                                bf16* __restrict__ w1b, bf16* __restrict__ w2b) {
    int bid = blockIdx.x;
    int t = threadIdx.x;
    if (bid < 4608) {                                    // weight cvt (NT loads, 16B stores)
        int l = bid / 768;
        int s = bid - l * 768;
        const float* src; bf16* dst;
        if (s < 384)      { src = Wqkv + (size_t)l * 3145728; dst = wqb + (size_t)l * 3145728; }
        else if (s < 512) { src = Wo + (size_t)l * 1048576; dst = wob + (size_t)l * 1048576; s -= 384; }
        else if (s < 640) { src = W1 + (size_t)l * 1048576; dst = w1b + (size_t)l * 1048576; s -= 512; }
        else              { src = W2 + (size_t)l * 1048576; dst = w2b + (size_t)l * 1048576; s -= 640; }
        size_t pbase = (size_t)s * 1024 + t;
#pragma unroll
        for (int it = 0; it < 4; ++it) {
            size_t o = (pbase + it * 256) * 8;           // 8 floats per pair
            const f32x4* p = (const f32x4*)(src + o);
            f32x4 v1 = __builtin_nontemporal_load(p);
            f32x4 v2 = __builtin_nontemporal_load(p + 1);
            us8 w8;
            w8[0] = f2bf(v1.x); w8[1] = f2bf(v1.y); w8[2] = f2bf(v1.z); w8[3] = f2bf(v1.w);
            w8[4] = f2bf(v2.x); w8[5] = f2bf(v2.y); w8[6] = f2bf(v2.z); w8[7] = f2bf(v2.w);
            *(us8*)(dst + o) = w8;
        }
    } else if (bid < 4736) {                             // pe [128][1024]: block=row s, 4 elems/thread
        int s = bid - 4608;
        float4 v;
#pragma unroll
        for (int j = 0; j < 4; ++j) {
            int c = t * 4 + j;
            int i = c >> 1;
            float div = expf(-9.210340371976184f * (float)(2 * i) * (1.f / 1024.f));
            float a = (float)s * div;
            v[j] = (c & 1) ? cosf(a) : sinf(a);
        }
        *(float4*)(pe + (size_t)s * 1024 + t * 4) = v;
    } else if (bid < 5888) {                             // xin: 294912 us8-chunks (4096 rows x 72)
        int chunk = (bid - 4736) * 256 + t;
        int row = chunk / 72;
        int cc = chunk - row * 72;
        int b = row >> 7, s = row & 127;
        us8 w8;
        if (cc < 64) {                                   // cond region: input[b][cc*8..+7]
            const float* p = input + (size_t)b * 512 + cc * 8;
            float4 v1 = *(const float4*)p;
            float4 v2 = *(const float4*)(p + 4);
            w8[0] = f2bf(v1.x); w8[1] = f2bf(v1.y); w8[2] = f2bf(v1.z); w8[3] = f2bf(v1.w);
            w8[4] = f2bf(v2.x); w8[5] = f2bf(v2.y); w8[6] = f2bf(v2.z); w8[7] = f2bf(v2.w);
        } else {                                         // token region: cols 512..575
#pragma unroll
            for (int j = 0; j < 8; ++j) {
                int col = cc * 8 + j;
                float v = 0.f;
                if (col < 545) {
                    int jj = col - 512;
                    v = (s == 0) ? sos[jj] : targets[((size_t)b * 127 + (s - 1)) * 33 + jj];
                }
                w8[j] = f2bf(v);
            }
        }
        *(us8*)(xin + (size_t)row * 576 + cc * 8) = w8;
    } else if (bid < 6176) {                             // wemb: 73728 chunks (1024 rows x 72), pad 545->576
        int chunk = (bid - 5888) * 256 + t;
        int row = chunk / 72;
        int cc = chunk - row * 72;
        us8 w8;
#pragma unroll
        for (int j = 0; j < 8; ++j) {
            int col = cc * 8 + j;
            w8[j] = f2bf(col < 545 ? W_emb[(size_t)row * 545 + col] : 0.f);
        }
        *(us8*)(wemb + (size_t)row * 576 + cc * 8) = w8;
    } else if (bid < 6496) {                             // whead: 81920 chunks (640 rows x 128)
        int chunk = (bid - 6176) * 256 + t;
        int r = chunk >> 7;
        int cc = chunk & 127;
        const float* wsrc = nullptr; int off = 0;
        if (r == 0)        { wsrc = Wm;    off = 0; }
        else if (r < 9)    { wsrc = Wpi_m; off = r - 1; }
        else if (r < 137)  { wsrc = Wmu_m; off = r - 9; }
        else if (r < 265)  { wsrc = Wsg_m; off = r - 137; }
        else if (r < 273)  { wsrc = Wpi_v; off = r - 265; }
        else if (r < 401)  { wsrc = Wmu_v; off = r - 273; }
        else if (r < 529)  { wsrc = Wsg_v; off = r - 401; }
        us8 w8;
        if (wsrc) {
            const float* p = wsrc + (size_t)off * 1024 + cc * 8;
            float4 v1 = *(const float4*)p;
            float4 v2 = *(const float4*)(p + 4);
            w8[0] = f2bf(v1.x); w8[1] = f2bf(v1.y); w8[2] = f2bf(v1.z); w8[3] = f2bf(v1.w);
            w8[4] = f2bf(v2.x); w8[5] = f2bf(v2.y); w8[6] = f2bf(v2.z); w8[7] = f2bf(v2.w);
        } else {
#pragma unroll
            for (int j = 0; j < 8; ++j) w8[j] = 0;
        }
        *(us8*)(whead + (size_t)r * 1024 + cc * 8) = w8;
    } else {                                             // bhead: 529 scalars
        if (t < 529) {
            const float* bsrc; int off;
            if (t == 0)       { bsrc = bm;    off = 0; }
            else if (t < 9)   { bsrc = bpi_m; off = t - 1; }
            else if (t < 137) { bsrc = bmu_m; off = t - 9; }
            else if (t < 265) { bsrc = bsg_m; off = t - 137; }
            else if (t < 273) { bsrc = bpi_v; off = t - 265; }
            else if (t < 401) { bsrc = bmu_v; off = t - 273; }
            else              { bsrc = bsg_v; off = t - 401; }
            bhead[t] = bsrc[off];
        }
    }
}

// ---------------- main GEMM: C[M,N] = A[M,K] @ B[N,K]^T (+epilogue) ----------------
// 128x128 tile, BK=64. Operand-swapped MFMA (C^T frags -> vectorized epilogue).
// CFG=0: 256t (4 waves, 64x64/wave), single-buffer, 3 blocks/CU -- big grids (QKV, 768 blocks).
// CFG=1: 512t (8 waves, 32x64/wave), dbuf prefetch -- grid-limited (<=256-block) launches:
//        1 block/CU but 2 waves/SIMD (vs 1 at 256t) for latency hiding. Same per-wave
//        compute:staging ratio (16 MFMA : 4 chunks per k-tile).
// EPI: 0 bias->bf16 | 1 bias+relu->bf16 | 3 bias->f32 scalar (odd ldc) | 4 bias+pe->bf16
template<int EPI, int CFG>
__global__ __launch_bounds__(CFG ? 512 : 256, CFG ? 2 : 3) void gemm_bt(
    const bf16* __restrict__ A, const bf16* __restrict__ Bw,
    float* __restrict__ Cf, bf16* __restrict__ Cb,
    const float* __restrict__ bias, const float* __restrict__ pe,
    int M, int N, int K, int lda, int ldb, int ldc, long long Az, long long Cz)
{
    constexpr int NT = CFG ? 512 : 256;     // threads
    constexpr int NB = CFG ? 2 : 1;         // LDS buffers
    constexpr int MI = CFG ? 2 : 4;         // per-wave M fragments (wave M-tile = MI*16)
    constexpr int NCH = 1024 / NT;          // staging chunks per thread per array
    __shared__ __align__(16) bf16 sA[NB][128 * 64];
    __shared__ __align__(16) bf16 sB[NB][128 * 64];
    const int t = threadIdx.x;
    const int w = t >> 6, la = t & 63;
    const int wm = CFG ? (w >> 1) * 32 : (w >> 1) * 64;
    const int wn = (w & 1) * 64;
    const int m0 = blockIdx.y * 128, n0 = blockIdx.x * 128;
    const int z = blockIdx.z;
    A += (long long)z * Az;

    facc4 zero4 = {0.f, 0.f, 0.f, 0.f};
    facc4 acc[MI][4];
#pragma unroll
    for (int mi = 0; mi < MI; ++mi)
#pragma unroll
        for (int ni = 0; ni < 4; ++ni) acc[mi][ni] = zero4;

    auto stage = [&](int buf, int kt) {
#pragma unroll
        for (int i = 0; i < NCH; ++i) {
            int c = i * NT + t;
            int r = c >> 3;
            int bc = ((c & 7) * 16) ^ ((r & 7) << 4);   // pre-swizzled source byte col
            gload_lds16(A + (size_t)(m0 + r) * lda + kt + (bc >> 1),
                        (char*)sA[buf] + (size_t)c * 16);
            gload_lds16(Bw + (size_t)(n0 + r) * ldb + kt + (bc >> 1),
                        (char*)sB[buf] + (size_t)c * 16);
        }
    };
    auto compute = [&](int buf) {
#pragma unroll
        for (int ks = 0; ks < 2; ++ks) {
            bfrag8 af[MI], bfv[4];
            const int koffb = (ks * 32 + (la >> 4) * 8) * 2;
#pragma unroll
            for (int i = 0; i < MI; ++i) {
                int rowa = wm + i * 16 + (la & 15);
                af[i] = *(const bfrag8*)((const char*)sA[buf] + rowa * 128 + (koffb ^ ((rowa & 7) << 4)));
            }
#pragma unroll
            for (int i = 0; i < 4; ++i) {
                int rowb = wn + i * 16 + (la & 15);
                bfv[i] = *(const bfrag8*)((const char*)sB[buf] + rowb * 128 + (koffb ^ ((rowb & 7) << 4)));
            }
#pragma unroll
            for (int mi = 0; mi < MI; ++mi)
#pragma unroll
                for (int ni = 0; ni < 4; ++ni)     // swapped operands -> C^T fragment
                    acc[mi][ni] = __builtin_amdgcn_mfma_f32_16x16x32_bf16(bfv[ni], af[mi], acc[mi][ni], 0, 0, 0);
        }
    };

    const int nk = K >> 6;
    if constexpr (CFG) {
        stage(0, 0);
        __syncthreads();
        int cur = 0;
        for (int kt = 0; kt < nk; ++kt) {
            if (kt + 1 < nk) stage(cur ^ 1, (kt + 1) << 6);
            compute(cur);
            __syncthreads();        // drains stage(k+1) vmcnt; frees cur
            cur ^= 1;
        }
    } else {
        for (int kt = 0; kt < nk; ++kt) {
            stage(0, kt << 6);
            __syncthreads();
            compute(0);
            __syncthreads();
        }
    }
    // epilogue: thread holds C[row][colb..colb+3]
#pragma unroll
    for (int mi = 0; mi < MI; ++mi) {
        int row = m0 + wm + mi * 16 + (la & 15);
#pragma unroll
        for (int ni = 0; ni < 4; ++ni) {
            int colb = n0 + wn + ni * 16 + (la >> 4) * 4;
            if constexpr (EPI == 3) {               // scalar path (odd ldc / edge guards)
                if (row >= M) continue;
#pragma unroll
                for (int j = 0; j < 4; ++j) {
                    int col = colb + j;
                    if (col < N)
                        Cf[(size_t)z * Cz + (size_t)row * ldc + col] = acc[mi][ni][j] + bias[col];
                }
            } else {
                float4 bv = *(const float4*)(bias + colb);
                facc4 v = acc[mi][ni];
                v[0] += bv.x; v[1] += bv.y; v[2] += bv.z; v[3] += bv.w;
                size_t cidx = (size_t)row * ldc + colb;
                if constexpr (EPI == 0) {
                    us4 o; o.x = f2bf(v[0]); o.y = f2bf(v[1]); o.z = f2bf(v[2]); o.w = f2bf(v[3]);
                    *(us4*)(Cb + cidx) = o;
                } else if constexpr (EPI == 1) {
                    us4 o;
                    o.x = f2bf(v[0] > 0.f ? v[0] : 0.f); o.y = f2bf(v[1] > 0.f ? v[1] : 0.f);
                    o.z = f2bf(v[2] > 0.f ? v[2] : 0.f); o.w = f2bf(v[3] > 0.f ? v[3] : 0.f);
                    *(us4*)(Cb + cidx) = o;
                } else {                            // EPI == 4: bias + pe -> bf16
                    float4 p = *(const float4*)(pe + (size_t)(row & 127) * 1024 + colb);
                    us4 o;
                    o.x = f2bf(v[0] + p.x); o.y = f2bf(v[1] + p.y);
                    o.z = f2bf(v[2] + p.z); o.w = f2bf(v[3] + p.w);
                    *(us4*)(Cb + cidx) = o;
                }
            }
        }
    }
}

// ---------------- fused attention: one block per (b,h) ----------------
// S=128, D=64. Swapped QK^T keeps S rows lane-local -> in-register causal softmax.
__global__ __launch_bounds__(256) void attn_fused(const bf16* __restrict__ qkv, bf16* __restrict__ obf)
{
    __shared__ __align__(16) char lds[65536];
    char* sQ  = lds;            // [128] rows x 128B, swizzled
    char* sK  = lds + 16384;    // [128] rows x 128B (dead after QK^T -> red arrays)
    char* sS  = lds + 32768;    // [128] rows x 256B bf16 (P)
    char* sVT = lds;            // [64] rows x 256B (V transposed), overlaps sQ
    float* redm = (float*)(lds + 16384);            // [2][128] row max per col-half
    float* reds = (float*)(lds + 16384 + 1024);     // [2][128] row sum per col-half

    const int t = threadIdx.x, w = t >> 6, la = t & 63;
    const int b = blockIdx.x >> 4, h = blockIdx.x & 15;
    const size_t base = (size_t)b * 128 * 3072 + (size_t)h * 64;

    // phase 1: stage Q, K (swizzled via pre-swizzled source)
#pragma unroll
    for (int i = 0; i < 4; ++i) {
        int c = i * 256 + w * 64 + la;
        int r = c >> 3;
        int bc = ((c & 7) * 16) ^ ((r & 7) << 4);
        gload_lds16(qkv + base + (size_t)r * 3072 + (bc >> 1),
                    sQ + (size_t)(i * 256 + w * 64) * 16);
        gload_lds16(qkv + base + 1024 + (size_t)r * 3072 + (bc >> 1),
                    sK + (size_t)(i * 256 + w * 64) * 16);
    }
    __syncthreads();

    // phase 2: S = Q K^T (swapped mfma -> thread holds S[q][kb..kb+3], fp32)
    const int wm = (w >> 1) * 64, wn = (w & 1) * 64;
    facc4 zero4 = {0.f, 0.f, 0.f, 0.f};
    facc4 acc[4][4];
#pragma unroll
    for (int mi = 0; mi < 4; ++mi)
#pragma unroll
        for (int ni = 0; ni < 4; ++ni) acc[mi][ni] = zero4;
#pragma unroll
    for (int ks = 0; ks < 2; ++ks) {
        bfrag8 af[4], bfv[4];
        const int koffb = (ks * 32 + (la >> 4) * 8) * 2;
#pragma unroll
        for (int i = 0; i < 4; ++i) {
            int rowa = wm + i * 16 + (la & 15);
            af[i] = *(const bfrag8*)(sQ + rowa * 128 + (koffb ^ ((rowa & 7) << 4)));
            int rowb = wn + i * 16 + (la & 15);
            bfv[i] = *(const bfrag8*)(sK + rowb * 128 + (koffb ^ ((rowb & 7) << 4)));
        }
#pragma unroll
        for (int mi = 0; mi < 4; ++mi)
#pragma unroll
            for (int ni = 0; ni < 4; ++ni)
                acc[mi][ni] = __builtin_amdgcn_mfma_f32_16x16x32_bf16(bfv[ni], af[mi], acc[mi][ni], 0, 0, 0);
    }
    __syncthreads();        // all waves done reading sQ/sK

    // phase 3a: stage V transposed into sVT (overlaps softmax VALU below)
#pragma unroll
    for (int i = 0; i < 4; ++i) {
        int c = i * 256 + t;
        int r = c >> 3;             // key index s'
        int d0 = (c & 7) * 8;
        bfrag8 vv = *(const bfrag8*)(qkv + base + 2048 + (size_t)r * 3072 + d0);
#pragma unroll
        for (int j = 0; j < 8; ++j) {
            int d = d0 + j;
            *(short*)(sVT + d * 256 + ((2 * r) ^ ((d & 7) << 4))) = vv[j];
        }
    }

    // phase 3b: in-register causal softmax
    const int colh = (w & 1) * 128;
    float tmp4[4];
#pragma unroll
    for (int mi = 0; mi < 4; ++mi) {            // pass 1: scale, mask, wave-half max
        int q = wm + mi * 16 + (la & 15);
        float mx = -1e30f;
#pragma unroll
        for (int ni = 0; ni < 4; ++ni) {
            int kb = wn + ni * 16 + (la >> 4) * 4;
#pragma unroll
            for (int j = 0; j < 4; ++j) {
                float s = acc[mi][ni][j] * 0.125f;
                acc[mi][ni][j] = s;
                if (kb + j <= q) mx = fmaxf(mx, s);
            }
        }
        mx = fmaxf(mx, __shfl_xor(mx, 16));     // reduce over la>>4 (the k-axis lanes)
        mx = fmaxf(mx, __shfl_xor(mx, 32));
        tmp4[mi] = mx;
    }
    if ((la >> 4) == 0) {
#pragma unroll
        for (int mi = 0; mi < 4; ++mi) redm[colh + wm + mi * 16 + la] = tmp4[mi];
    }
    __syncthreads();
#pragma unroll
    for (int mi = 0; mi < 4; ++mi) {            // pass 2: exp, wave-half sum
        int q = wm + mi * 16 + (la & 15);
        float m = fmaxf(redm[q], redm[128 + q]);
        float sm = 0.f;
#pragma unroll
        for (int ni = 0; ni < 4; ++ni) {
            int kb = wn + ni * 16 + (la >> 4) * 4;
#pragma unroll
            for (int j = 0; j < 4; ++j) {
                float e = (kb + j <= q) ? __expf(acc[mi][ni][j] - m) : 0.f;
                acc[mi][ni][j] = e;
                sm += e;
            }
        }
        sm += __shfl_xor(sm, 16);
        sm += __shfl_xor(sm, 32);
        tmp4[mi] = sm;
    }
    __syncthreads();
    if ((la >> 4) == 0) {
#pragma unroll
        for (int mi = 0; mi < 4; ++mi) reds[colh + wm + mi * 16 + la] = tmp4[mi];
    }
    __syncthreads();
#pragma unroll
    for (int mi = 0; mi < 4; ++mi) {            // pass 3: normalize, pack P -> sS
        int q = wm + mi * 16 + (la & 15);
        float inv = 1.f / (reds[q] + reds[128 + q]);
#pragma unroll
        for (int ni = 0; ni < 4; ++ni) {
            int kb = wn + ni * 16 + (la >> 4) * 4;
            us4 sv;
            sv.x = f2bf(acc[mi][ni][0] * inv); sv.y = f2bf(acc[mi][ni][1] * inv);
            sv.z = f2bf(acc[mi][ni][2] * inv); sv.w = f2bf(acc[mi][ni][3] * inv);
            *(us4*)(sS + q * 256 + ((2 * kb) ^ ((q & 7) << 4))) = sv;
        }
    }
    __syncthreads();                             // sS + sVT complete before PV

    // phase 4: O = P V  (wave tile 64M x 32N, K=128; swapped mfma -> packed O stores)
    const int wm2 = (w >> 1) * 64, wn2 = (w & 1) * 32;
    facc4 a2[4][2];
#pragma unroll
    for (int mi = 0; mi < 4; ++mi) { a2[mi][0] = zero4; a2[mi][1] = zero4; }
#pragma unroll
    for (int ks = 0; ks < 4; ++ks) {
        bfrag8 pa[4], vb[2];
        const int koffb = (ks * 32 + (la >> 4) * 8) * 2;
#pragma unroll
        for (int mi = 0; mi < 4; ++mi) {
            int rowa = wm2 + mi * 16 + (la & 15);
            pa[mi] = *(const bfrag8*)(sS + rowa * 256 + (koffb ^ ((rowa & 7) << 4)));
        }
#pragma unroll
        for (int ni = 0; ni < 2; ++ni) {
            int rowb = wn2 + ni * 16 + (la & 15);
            vb[ni] = *(const bfrag8*)(sVT + rowb * 256 + (koffb ^ ((rowb & 7) << 4)));
        }
#pragma unroll
        for (int mi = 0; mi < 4; ++mi)
#pragma unroll
            for (int ni = 0; ni < 2; ++ni)
                a2[mi][ni] = __builtin_amdgcn_mfma_f32_16x16x32_bf16(vb[ni], pa[mi], a2[mi][ni], 0, 0, 0);
    }
#pragma unroll
    for (int mi = 0; mi < 4; ++mi) {
        int s = wm2 + mi * 16 + (la & 15);
#pragma unroll
        for (int ni = 0; ni < 2; ++ni) {
            int db = wn2 + ni * 16 + (la >> 4) * 4;
            us4 ov;
            ov.x = f2bf(a2[mi][ni][0]); ov.y = f2bf(a2[mi][ni][1]);
            ov.z = f2bf(a2[mi][ni][2]); ov.w = f2bf(a2[mi][ni][3]);
            *(us4*)(obf + ((size_t)(b * 128 + s)) * 1024 + h * 64 + db) = ov;
        }
    }
}

// ------- fused residual + LayerNorm, all-bf16 stream: t = res + go; LN(t) -> xb -------
__global__ __launch_bounds__(256) void ln_res_kernel(const bf16* __restrict__ go,
                                                     const bf16* __restrict__ res,
                                                     const float* __restrict__ g, const float* __restrict__ be,
                                                     bf16* __restrict__ xb_out)
{
    const int row = blockIdx.x, t = threadIdx.x;
    size_t o = (size_t)row * 1024 + t * 4;
    us4 gv4 = *(const us4*)(go + o);
    us4 rv4 = *(const us4*)(res + o);
    float t0 = bf2f(rv4.x) + bf2f(gv4.x);
    float t1 = bf2f(rv4.y) + bf2f(gv4.y);
    float t2 = bf2f(rv4.z) + bf2f(gv4.z);
    float t3 = bf2f(rv4.w) + bf2f(gv4.w);
    float s = t0 + t1 + t2 + t3;
    float q = t0 * t0 + t1 * t1 + t2 * t2 + t3 * t3;
#pragma unroll
    for (int off = 32; off; off >>= 1) {
        s += __shfl_xor(s, off);
        q += __shfl_xor(q, off);
    }
    __shared__ float ssum[4], sqs[4];
    if ((t & 63) == 0) { ssum[t >> 6] = s; sqs[t >> 6] = q; }
    __syncthreads();
    s = ssum[0] + ssum[1] + ssum[2] + ssum[3];
    q = sqs[0] + sqs[1] + sqs[2] + sqs[3];
    float mean = s * (1.f / 1024.f);
    float var = q * (1.f / 1024.f) - mean * mean;
    float rstd = rsqrtf(var + 1e-5f);
    float4 gv = *(const float4*)(g + t * 4);
    float4 bv = *(const float4*)(be + t * 4);
    float o0 = (t0 - mean) * rstd * gv.x + bv.x;
    float o1 = (t1 - mean) * rstd * gv.y + bv.y;
    float o2 = (t2 - mean) * rstd * gv.z + bv.z;
    float o3 = (t3 - mean) * rstd * gv.w + bv.w;
    us4 obv; obv.x = f2bf(o0); obv.y = f2bf(o1); obv.z = f2bf(o2); obv.w = f2bf(o3);
    *(us4*)(xb_out + o) = obv;
}

// ---------------- MDN finalize / scatter ----------------
__global__ void finalize_kernel(const float* __restrict__ hout, float* __restrict__ out) {
    const size_t O_PI_M = 0, O_MU_M = 32512, O_VAR_M = 552704, O_PI_V = 1072896,
                 O_MU_V = 1105408, O_VAR_V = 1625600, O_MASK = 2145792;
    int rm = blockIdx.x;                    // b*127+m, 4064 rows
    const float* hrow = hout + (size_t)rm * 529;
    int t = threadIdx.x;
    if (t < 128) {
        out[O_MU_M  + (size_t)rm * 128 + t] = hrow[9 + t];
        out[O_VAR_M + (size_t)rm * 128 + t] = expf(hrow[137 + t]);
        out[O_MU_V  + (size_t)rm * 128 + t] = hrow[273 + t];
        out[O_VAR_V + (size_t)rm * 128 + t] = expf(hrow[401 + t]);
    } else if (t == 128) {
        out[O_MASK + rm] = hrow[0];
    } else if (t == 129 || t == 130) {
        int boff = (t == 129) ? 1 : 265;
        size_t oo = ((t == 129) ? O_PI_M : O_PI_V) + (size_t)rm * 8;
        float v[8], mx = -1e30f;
#pragma unroll
        for (int j = 0; j < 8; ++j) { v[j] = hrow[boff + j]; mx = fmaxf(mx, v[j]); }
        float sm = 0.f;
#pragma unroll
        for (int j = 0; j < 8; ++j) { v[j] = expf(v[j] - mx); sm += v[j]; }
        float inv = 1.f / sm;
#pragma unroll
        for (int j = 0; j < 8; ++j) out[oo + j] = v[j] * inv;
    }
}

// ---------------- launcher ----------------
extern "C" void kernel_launch(void* const* d_in, const int* in_sizes, int n_in,
                              void* d_out, int out_size, void* d_ws, size_t ws_size,
                              hipStream_t stream) {
    (void)in_sizes; (void)n_in; (void)out_size; (void)ws_size;
    const float* input   = (const float*)d_in[0];
    const float* targets = (const float*)d_in[1];
    const float* W_emb   = (const float*)d_in[2];
    const float* b_emb   = (const float*)d_in[3];
    const float* sos     = (const float*)d_in[4];
    const float* Wqkv    = (const float*)d_in[5];
    const float* bqkv    = (const float*)d_in[6];
    const float* Wo      = (const float*)d_in[7];
    const float* bo      = (const float*)d_in[8];
    const float* W1      = (const float*)d_in[9];
    const float* b1      = (const float*)d_in[10];
    const float* W2      = (const float*)d_in[11];
    const float* b2      = (const float*)d_in[12];
    const float* g1      = (const float*)d_in[13];
    const float* be1     = (const float*)d_in[14];
    const float* g2      = (const float*)d_in[15];
    const float* be2     = (const float*)d_in[16];
    const float* Wm      = (const float*)d_in[17];
    const float* bm      = (const float*)d_in[18];
    const float* Wpi_m   = (const float*)d_in[19];
    const float* bpi_m   = (const float*)d_in[20];
    const float* Wmu_m   = (const float*)d_in[21];
    const float* bmu_m   = (const float*)d_in[22];
    const float* Wsg_m   = (const float*)d_in[23];
    const float* bsg_m   = (const float*)d_in[24];
    const float* Wpi_v   = (const float*)d_in[25];
    const float* bpi_v   = (const float*)d_in[26];
    const float* Wmu_v   = (const float*)d_in[27];
    const float* bmu_v   = (const float*)d_in[28];
    const float* Wsg_v   = (const float*)d_in[29];
    const float* bsg_v   = (const float*)d_in[30];
    float* out = (float*)d_out;

    char* ws = (char*)d_ws;                            // ~167 MB total
    float* pe      = (float*)(ws + 0);                 // 0.5 MB
    bf16*  xin     = (bf16*)(ws + 524288);             // 4.72 MB
    bf16*  wemb    = (bf16*)(ws + 5242880);            // 1.18 MB
    bf16*  whead   = (bf16*)(ws + 6422528);            // 1.31 MB (640 rows)
    float* bhead   = (float*)(ws + 7733248);           // 2.5 KB
    bf16*  xb      = (bf16*)(ws + 24513024);           // 8.4 MB (bf16 residual stream + GEMM input)
    bf16*  qkvb    = (bf16*)(ws + 32901632);           // 25.2 MB
    bf16*  ob      = (bf16*)(ws + 58067456);           // 8.4 MB (attn out, reused as FF hidden)
    bf16*  tmpb    = (bf16*)(ws + 66456064);           // 8.4 MB (gemm-out bf16, pre-LN)
    bf16*  wqb_all = (bf16*)(ws + 83233280);           // 37.7 MB (6 layers)
    bf16*  wob_all = (bf16*)(ws + 120982016);          // 12.6 MB
    bf16*  w1b_all = (bf16*)(ws + 133564928);          // 12.6 MB
    bf16*  w2b_all = (bf16*)(ws + 146147840);          // 12.6 MB
    float* hout    = (float*)(ws + 158730752);         // 8.6 MB

    prep_cvt_kernel<<<6497, 256, 0, stream>>>(input, targets, sos, W_emb,
                                              Wm, Wpi_m, Wmu_m, Wsg_m, Wpi_v, Wmu_v, Wsg_v,
                                              bm, bpi_m, bmu_m, bsg_m, bpi_v, bmu_v, bsg_v,
                                              Wqkv, Wo, W1, W2,
                                              pe, xin, wemb, whead, bhead,
                                              wqb_all, wob_all, w1b_all, w2b_all);
    // x = XIN @ Wemb^T + b + pe -> xb (bf16 residual stream)
    gemm_bt<4, 1><<<dim3(8, 32, 1), 512, 0, stream>>>(xin, wemb, nullptr, xb, b_emb, pe,
                                                      4096, 1024, 576, 576, 576, 1024, 0, 0);
    for (int l = 0; l < 6; ++l) {
        const bf16* wqb = wqb_all + (size_t)l * 3145728;
        const bf16* wob = wob_all + (size_t)l * 1048576;
        const bf16* w1b = w1b_all + (size_t)l * 1048576;
        const bf16* w2b = w2b_all + (size_t)l * 1048576;
        // qkv = x @ Wqkv^T + b  (bf16 out) -- 768 blocks, single-buffer, 3 blocks/CU
        gemm_bt<0, 0><<<dim3(24, 32, 1), 256, 0, stream>>>(xb, wqb, nullptr, qkvb, bqkv + l * 3072,
                                                           nullptr, 4096, 3072, 1024, 1024, 1024, 3072, 0, 0);
        attn_fused<<<512, 256, 0, stream>>>(qkvb, ob);
        // go = o @ Wo^T + bo (bf16); residual folded into ln_res -- 8-wave dbuf
        gemm_bt<0, 1><<<dim3(8, 32, 1), 512, 0, stream>>>(ob, wob, nullptr, tmpb, bo + l * 1024,
                                                          nullptr, 4096, 1024, 1024, 1024, 1024, 1024, 0, 0);
        ln_res_kernel<<<4096, 256, 0, stream>>>(tmpb, xb, g1 + l * 1024, be1 + l * 1024, xb);
        // t1 = relu(x @ W1^T + b1) (bf16, reuse ob)
        gemm_bt<1, 1><<<dim3(8, 32, 1), 512, 0, stream>>>(xb, w1b, nullptr, ob, b1 + l * 1024,
                                                          nullptr, 4096, 1024, 1024, 1024, 1024, 1024, 0, 0);
        // go = t1 @ W2^T + b2 (bf16); residual folded into ln_res
        gemm_bt<0, 1><<<dim3(8, 32, 1), 512, 0, stream>>>(ob, w2b, nullptr, tmpb, b2 + l * 1024,
                                                          nullptr, 4096, 1024, 1024, 1024, 1024, 1024, 0, 0);
        ln_res_kernel<<<4096, 256, 0, stream>>>(tmpb, xb, g2 + l * 1024, be2 + l * 1024, xb);
    }
    // heads: per-batch M=127 rows of x -> hout (B,127,529) -- 160 blocks, 8-wave dbuf
    gemm_bt<3, 1><<<dim3(5, 1, 32), 512, 0, stream>>>(xb, whead, hout, nullptr, bhead, nullptr,
                                                      127, 529, 1024, 1024, 1024, 529, 131072LL, 67183LL);
    finalize_kernel<<<4064, 256, 0, stream>>>(hout, out);
}

// Round 11
// 741.205 us; speedup vs baseline: 1.3920x; 1.0340x over previous
//
#include <hip/hip_runtime.h>
#include <hip/hip_bf16.h>

typedef __hip_bfloat16 bf16;
typedef __attribute__((ext_vector_type(8))) short bfrag8;   // 8 bf16 (4 VGPR) MFMA A/B frag
typedef __attribute__((ext_vector_type(4))) float facc4;    // MFMA C/D frag
typedef __attribute__((ext_vector_type(4))) unsigned short us4;
typedef __attribute__((ext_vector_type(8))) unsigned short us8;
typedef __attribute__((ext_vector_type(4))) float f32x4;    // true clang vector (for nontemporal)

#define AS1C const __attribute__((address_space(1))) void
#define AS3  __attribute__((address_space(3))) void

__device__ __forceinline__ void gload_lds16(const void* src, void* dst) {
    __builtin_amdgcn_global_load_lds((AS1C*)src, (AS3*)dst, 16, 0, 0);
}

__device__ __forceinline__ unsigned short f2bf(float f) {   // RNE, finite inputs
    unsigned u = __float_as_uint(f);
    unsigned r = u + 0x7FFFu + ((u >> 16) & 1u);
    return (unsigned short)(r >> 16);
}
__device__ __forceinline__ float bf2f(unsigned short u) {   // exact
    return __uint_as_float((unsigned)u << 16);
}

// ------- merged prep+cvt: weights first (heavy), DENSE vectorized tail -------
// [0,4608): weight cvt | [4608,4736): pe | [4736,5888): xin | [5888,6176): wemb
// [6176,6496): whead | 6496: bhead
__global__ void prep_cvt_kernel(const float* __restrict__ input, const float* __restrict__ targets,
                                const float* __restrict__ sos, const float* __restrict__ W_emb,
                                const float* __restrict__ Wm, const float* __restrict__ Wpi_m,
                                const float* __restrict__ Wmu_m, const float* __restrict__ Wsg_m,
                                const float* __restrict__ Wpi_v, const float* __restrict__ Wmu_v,
                                const float* __restrict__ Wsg_v,
                                const float* __restrict__ bm, const float* __restrict__ bpi_m,
                                const float* __restrict__ bmu_m, const float* __restrict__ bsg_m,
                                const float* __restrict__ bpi_v, const float* __restrict__ bmu_v,
                                const float* __restrict__ bsg_v,
                                const float* __restrict__ Wqkv, const float* __restrict__ Wo,
                                const float* __restrict__ W1, const float* __restrict__ W2,
                                float* __restrict__ pe, bf16* __restrict__ xin,
                                bf16* __restrict__ wemb, bf16* __restrict__ whead,
                                float* __restrict__ bhead,
                                bf16* __restrict__ wqb, bf16* __restrict__ wob,
                                bf16* __restrict__ w1b, bf16* __restrict__ w2b) {
    int bid = blockIdx.x;
    int t = threadIdx.x;
    if (bid < 4608) {                                    // weight cvt (NT loads, 16B stores)
        int l = bid / 768;
        int s = bid - l * 768;
        const float* src; bf16* dst;
        if (s < 384)      { src = Wqkv + (size_t)l * 3145728; dst = wqb + (size_t)l * 3145728; }
        else if (s < 512) { src = Wo + (size_t)l * 1048576; dst = wob + (size_t)l * 1048576; s -= 384; }
        else if (s < 640) { src = W1 + (size_t)l * 1048576; dst = w1b + (size_t)l * 1048576; s -= 512; }
        else              { src = W2 + (size_t)l * 1048576; dst = w2b + (size_t)l * 1048576; s -= 640; }
        size_t pbase = (size_t)s * 1024 + t;
#pragma unroll
        for (int it = 0; it < 4; ++it) {
            size_t o = (pbase + it * 256) * 8;           // 8 floats per pair
            const f32x4* p = (const f32x4*)(src + o);
            f32x4 v1 = __builtin_nontemporal_load(p);
            f32x4 v2 = __builtin_nontemporal_load(p + 1);
            us8 w8;
            w8[0] = f2bf(v1.x); w8[1] = f2bf(v1.y); w8[2] = f2bf(v1.z); w8[3] = f2bf(v1.w);
            w8[4] = f2bf(v2.x); w8[5] = f2bf(v2.y); w8[6] = f2bf(v2.z); w8[7] = f2bf(v2.w);
            *(us8*)(dst + o) = w8;
        }
    } else if (bid < 4736) {                             // pe [128][1024]: block=row s, 4 elems/thread
        int s = bid - 4608;
        float4 v;
#pragma unroll
        for (int j = 0; j < 4; ++j) {
            int c = t * 4 + j;
            int i = c >> 1;
            float div = expf(-9.210340371976184f * (float)(2 * i) * (1.f / 1024.f));
            float a = (float)s * div;
            v[j] = (c & 1) ? cosf(a) : sinf(a);
        }
        *(float4*)(pe + (size_t)s * 1024 + t * 4) = v;
    } else if (bid < 5888) {                             // xin: 294912 us8-chunks (4096 rows x 72)
        int chunk = (bid - 4736) * 256 + t;
        int row = chunk / 72;
        int cc = chunk - row * 72;
        int b = row >> 7, s = row & 127;
        us8 w8;
        if (cc < 64) {                                   // cond region: input[b][cc*8..+7]
            const float* p = input + (size_t)b * 512 + cc * 8;
            float4 v1 = *(const float4*)p;
            float4 v2 = *(const float4*)(p + 4);
            w8[0] = f2bf(v1.x); w8[1] = f2bf(v1.y); w8[2] = f2bf(v1.z); w8[3] = f2bf(v1.w);
            w8[4] = f2bf(v2.x); w8[5] = f2bf(v2.y); w8[6] = f2bf(v2.z); w8[7] = f2bf(v2.w);
        } else {                                         // token region: cols 512..575
#pragma unroll
            for (int j = 0; j < 8; ++j) {
                int col = cc * 8 + j;
                float v = 0.f;
                if (col < 545) {
                    int jj = col - 512;
                    v = (s == 0) ? sos[jj] : targets[((size_t)b * 127 + (s - 1)) * 33 + jj];
                }
                w8[j] = f2bf(v);
            }
        }
        *(us8*)(xin + (size_t)row * 576 + cc * 8) = w8;
    } else if (bid < 6176) {                             // wemb: 73728 chunks (1024 rows x 72), pad 545->576
        int chunk = (bid - 5888) * 256 + t;
        int row = chunk / 72;
        int cc = chunk - row * 72;
        us8 w8;
#pragma unroll
        for (int j = 0; j < 8; ++j) {
            int col = cc * 8 + j;
            w8[j] = f2bf(col < 545 ? W_emb[(size_t)row * 545 + col] : 0.f);
        }
        *(us8*)(wemb + (size_t)row * 576 + cc * 8) = w8;
    } else if (bid < 6496) {                             // whead: 81920 chunks (640 rows x 128)
        int chunk = (bid - 6176) * 256 + t;
        int r = chunk >> 7;
        int cc = chunk & 127;
        const float* wsrc = nullptr; int off = 0;
        if (r == 0)        { wsrc = Wm;    off = 0; }
        else if (r < 9)    { wsrc = Wpi_m; off = r - 1; }
        else if (r < 137)  { wsrc = Wmu_m; off = r - 9; }
        else if (r < 265)  { wsrc = Wsg_m; off = r - 137; }
        else if (r < 273)  { wsrc = Wpi_v; off = r - 265; }
        else if (r < 401)  { wsrc = Wmu_v; off = r - 273; }
        else if (r < 529)  { wsrc = Wsg_v; off = r - 401; }
        us8 w8;
        if (wsrc) {
            const float* p = wsrc + (size_t)off * 1024 + cc * 8;
            float4 v1 = *(const float4*)p;
            float4 v2 = *(const float4*)(p + 4);
            w8[0] = f2bf(v1.x); w8[1] = f2bf(v1.y); w8[2] = f2bf(v1.z); w8[3] = f2bf(v1.w);
            w8[4] = f2bf(v2.x); w8[5] = f2bf(v2.y); w8[6] = f2bf(v2.z); w8[7] = f2bf(v2.w);
        } else {
#pragma unroll
            for (int j = 0; j < 8; ++j) w8[j] = 0;
        }
        *(us8*)(whead + (size_t)r * 1024 + cc * 8) = w8;
    } else {                                             // bhead: 529 scalars
        if (t < 529) {
            const float* bsrc; int off;
            if (t == 0)       { bsrc = bm;    off = 0; }
            else if (t < 9)   { bsrc = bpi_m; off = t - 1; }
            else if (t < 137) { bsrc = bmu_m; off = t - 9; }
            else if (t < 265) { bsrc = bsg_m; off = t - 137; }
            else if (t < 273) { bsrc = bpi_v; off = t - 265; }
            else if (t < 401) { bsrc = bmu_v; off = t - 273; }
            else              { bsrc = bsg_v; off = t - 401; }
            bhead[t] = bsrc[off];
        }
    }
}

// ---------------- main GEMM: C[M,N] = A[M,K] @ B[N,K]^T (+epilogue) ----------------
// 128x128 tile. Operand-swapped MFMA (C^T frags -> vectorized epilogue).
// CFG=0: 256t, BK=64, single-buffer, 3 blocks/CU -- big grids (QKV, 768 blocks).
// CFG=1: 512t, BK=64, dbuf -- grid-limited launches with K%128!=0 (embed, K=576).
// CFG=2: 512t, BK=128, dbuf, 128KB LDS -- grid-limited (1 block/CU, LDS free) K%128==0:
//        2x compute per barrier + half the barrier drains (the per-barrier prefetch
//        drain was the round-10 bottleneck; m132's occupancy objection doesn't apply
//        at grid-capped 1 block/CU).
// EPI: 0 bias->bf16 | 1 bias+relu->bf16 | 3 bias->f32 scalar (odd ldc) | 4 bias+pe->bf16
template<int EPI, int CFG>
__global__ __launch_bounds__(CFG ? 512 : 256, CFG ? 2 : 3) void gemm_bt(
    const bf16* __restrict__ A, const bf16* __restrict__ Bw,
    float* __restrict__ Cf, bf16* __restrict__ Cb,
    const float* __restrict__ bias, const float* __restrict__ pe,
    int M, int N, int K, int lda, int ldb, int ldc, long long Az, long long Cz)
{
    constexpr int NT  = CFG ? 512 : 256;    // threads
    constexpr int NB  = CFG ? 2 : 1;        // LDS buffers
    constexpr int MI  = CFG ? 2 : 4;        // per-wave M fragments
    constexpr int BK  = (CFG == 2) ? 128 : 64;
    constexpr int RB  = BK * 2;             // row bytes in LDS
    constexpr int CPR = BK / 8;             // 16B chunks per row
    constexpr int NCH = (128 * CPR) / NT;   // staging chunks per thread per array
    constexpr int KS  = BK / 32;            // 32-wide k-slices per tile
    __shared__ __align__(16) bf16 sA[NB][128 * BK];
    __shared__ __align__(16) bf16 sB[NB][128 * BK];
    const int t = threadIdx.x;
    const int w = t >> 6, la = t & 63;
    const int wm = CFG ? (w >> 1) * 32 : (w >> 1) * 64;
    const int wn = (w & 1) * 64;
    const int m0 = blockIdx.y * 128, n0 = blockIdx.x * 128;
    const int z = blockIdx.z;
    A += (long long)z * Az;

    facc4 zero4 = {0.f, 0.f, 0.f, 0.f};
    facc4 acc[MI][4];
#pragma unroll
    for (int mi = 0; mi < MI; ++mi)
#pragma unroll
        for (int ni = 0; ni < 4; ++ni) acc[mi][ni] = zero4;

    auto stage = [&](int buf, int kt) {
#pragma unroll
        for (int i = 0; i < NCH; ++i) {
            int c = i * NT + t;
            int r = c / CPR;
            int cc = c - r * CPR;
            int bc = (cc * 16) ^ ((r & 7) << 4);        // pre-swizzled source byte col
            gload_lds16(A + (size_t)(m0 + r) * lda + kt + (bc >> 1),
                        (char*)sA[buf] + (size_t)c * 16);
            gload_lds16(Bw + (size_t)(n0 + r) * ldb + kt + (bc >> 1),
                        (char*)sB[buf] + (size_t)c * 16);
        }
    };
    auto compute = [&](int buf) {
#pragma unroll
        for (int ks = 0; ks < KS; ++ks) {
            bfrag8 af[MI], bfv[4];
            const int koffb = (ks * 32 + (la >> 4) * 8) * 2;
#pragma unroll
            for (int i = 0; i < MI; ++i) {
                int rowa = wm + i * 16 + (la & 15);
                af[i] = *(const bfrag8*)((const char*)sA[buf] + rowa * RB + (koffb ^ ((rowa & 7) << 4)));
            }
#pragma unroll
            for (int i = 0; i < 4; ++i) {
                int rowb = wn + i * 16 + (la & 15);
                bfv[i] = *(const bfrag8*)((const char*)sB[buf] + rowb * RB + (koffb ^ ((rowb & 7) << 4)));
            }
#pragma unroll
            for (int mi = 0; mi < MI; ++mi)
#pragma unroll
                for (int ni = 0; ni < 4; ++ni)     // swapped operands -> C^T fragment
                    acc[mi][ni] = __builtin_amdgcn_mfma_f32_16x16x32_bf16(bfv[ni], af[mi], acc[mi][ni], 0, 0, 0);
        }
    };

    const int nk = K / BK;
    if constexpr (CFG) {
        stage(0, 0);
        __syncthreads();
        int cur = 0;
        for (int kt = 0; kt < nk; ++kt) {
            if (kt + 1 < nk) stage(cur ^ 1, (kt + 1) * BK);
            compute(cur);
            __syncthreads();        // drains stage(k+1) vmcnt; frees cur
            cur ^= 1;
        }
    } else {
        for (int kt = 0; kt < nk; ++kt) {
            stage(0, kt * BK);
            __syncthreads();
            compute(0);
            __syncthreads();
        }
    }
    // epilogue: thread holds C[row][colb..colb+3]
#pragma unroll
    for (int mi = 0; mi < MI; ++mi) {
        int row = m0 + wm + mi * 16 + (la & 15);
#pragma unroll
        for (int ni = 0; ni < 4; ++ni) {
            int colb = n0 + wn + ni * 16 + (la >> 4) * 4;
            if constexpr (EPI == 3) {               // scalar path (odd ldc / edge guards)
                if (row >= M) continue;
#pragma unroll
                for (int j = 0; j < 4; ++j) {
                    int col = colb + j;
                    if (col < N)
                        Cf[(size_t)z * Cz + (size_t)row * ldc + col] = acc[mi][ni][j] + bias[col];
                }
            } else {
                float4 bv = *(const float4*)(bias + colb);
                facc4 v = acc[mi][ni];
                v[0] += bv.x; v[1] += bv.y; v[2] += bv.z; v[3] += bv.w;
                size_t cidx = (size_t)row * ldc + colb;
                if constexpr (EPI == 0) {
                    us4 o; o.x = f2bf(v[0]); o.y = f2bf(v[1]); o.z = f2bf(v[2]); o.w = f2bf(v[3]);
                    *(us4*)(Cb + cidx) = o;
                } else if constexpr (EPI == 1) {
                    us4 o;
                    o.x = f2bf(v[0] > 0.f ? v[0] : 0.f); o.y = f2bf(v[1] > 0.f ? v[1] : 0.f);
                    o.z = f2bf(v[2] > 0.f ? v[2] : 0.f); o.w = f2bf(v[3] > 0.f ? v[3] : 0.f);
                    *(us4*)(Cb + cidx) = o;
                } else {                            // EPI == 4: bias + pe -> bf16
                    float4 p = *(const float4*)(pe + (size_t)(row & 127) * 1024 + colb);
                    us4 o;
                    o.x = f2bf(v[0] + p.x); o.y = f2bf(v[1] + p.y);
                    o.z = f2bf(v[2] + p.z); o.w = f2bf(v[3] + p.w);
                    *(us4*)(Cb + cidx) = o;
                }
            }
        }
    }
}

// ---------------- fused attention: one block per (b,h) ----------------
// S=128, D=64. Swapped QK^T keeps S rows lane-local -> in-register causal softmax.
__global__ __launch_bounds__(256) void attn_fused(const bf16* __restrict__ qkv, bf16* __restrict__ obf)
{
    __shared__ __align__(16) char lds[65536];
    char* sQ  = lds;            // [128] rows x 128B, swizzled
    char* sK  = lds + 16384;    // [128] rows x 128B (dead after QK^T -> red arrays)
    char* sS  = lds + 32768;    // [128] rows x 256B bf16 (P)
    char* sVT = lds;            // [64] rows x 256B (V transposed), overlaps sQ
    float* redm = (float*)(lds + 16384);            // [2][128] row max per col-half
    float* reds = (float*)(lds + 16384 + 1024);     // [2][128] row sum per col-half

    const int t = threadIdx.x, w = t >> 6, la = t & 63;
    const int b = blockIdx.x >> 4, h = blockIdx.x & 15;
    const size_t base = (size_t)b * 128 * 3072 + (size_t)h * 64;

    // phase 1: stage Q, K (swizzled via pre-swizzled source)
#pragma unroll
    for (int i = 0; i < 4; ++i) {
        int c = i * 256 + w * 64 + la;
        int r = c >> 3;
        int bc = ((c & 7) * 16) ^ ((r & 7) << 4);
        gload_lds16(qkv + base + (size_t)r * 3072 + (bc >> 1),
                    sQ + (size_t)(i * 256 + w * 64) * 16);
        gload_lds16(qkv + base + 1024 + (size_t)r * 3072 + (bc >> 1),
                    sK + (size_t)(i * 256 + w * 64) * 16);
    }
    __syncthreads();

    // phase 2: S = Q K^T (swapped mfma -> thread holds S[q][kb..kb+3], fp32)
    const int wm = (w >> 1) * 64, wn = (w & 1) * 64;
    facc4 zero4 = {0.f, 0.f, 0.f, 0.f};
    facc4 acc[4][4];
#pragma unroll
    for (int mi = 0; mi < 4; ++mi)
#pragma unroll
        for (int ni = 0; ni < 4; ++ni) acc[mi][ni] = zero4;
#pragma unroll
    for (int ks = 0; ks < 2; ++ks) {
        bfrag8 af[4], bfv[4];
        const int koffb = (ks * 32 + (la >> 4) * 8) * 2;
#pragma unroll
        for (int i = 0; i < 4; ++i) {
            int rowa = wm + i * 16 + (la & 15);
            af[i] = *(const bfrag8*)(sQ + rowa * 128 + (koffb ^ ((rowa & 7) << 4)));
            int rowb = wn + i * 16 + (la & 15);
            bfv[i] = *(const bfrag8*)(sK + rowb * 128 + (koffb ^ ((rowb & 7) << 4)));
        }
#pragma unroll
        for (int mi = 0; mi < 4; ++mi)
#pragma unroll
            for (int ni = 0; ni < 4; ++ni)
                acc[mi][ni] = __builtin_amdgcn_mfma_f32_16x16x32_bf16(bfv[ni], af[mi], acc[mi][ni], 0, 0, 0);
    }
    __syncthreads();        // all waves done reading sQ/sK

    // phase 3a: stage V transposed into sVT (overlaps softmax VALU below)
#pragma unroll
    for (int i = 0; i < 4; ++i) {
        int c = i * 256 + t;
        int r = c >> 3;             // key index s'
        int d0 = (c & 7) * 8;
        bfrag8 vv = *(const bfrag8*)(qkv + base + 2048 + (size_t)r * 3072 + d0);
#pragma unroll
        for (int j = 0; j < 8; ++j) {
            int d = d0 + j;
            *(short*)(sVT + d * 256 + ((2 * r) ^ ((d & 7) << 4))) = vv[j];
        }
    }

    // phase 3b: in-register causal softmax
    const int colh = (w & 1) * 128;
    float tmp4[4];
#pragma unroll
    for (int mi = 0; mi < 4; ++mi) {            // pass 1: scale, mask, wave-half max
        int q = wm + mi * 16 + (la & 15);
        float mx = -1e30f;
#pragma unroll
        for (int ni = 0; ni < 4; ++ni) {
            int kb = wn + ni * 16 + (la >> 4) * 4;
#pragma unroll
            for (int j = 0; j < 4; ++j) {
                float s = acc[mi][ni][j] * 0.125f;
                acc[mi][ni][j] = s;
                if (kb + j <= q) mx = fmaxf(mx, s);
            }
        }
        mx = fmaxf(mx, __shfl_xor(mx, 16));     // reduce over la>>4 (the k-axis lanes)
        mx = fmaxf(mx, __shfl_xor(mx, 32));
        tmp4[mi] = mx;
    }
    if ((la >> 4) == 0) {
#pragma unroll
        for (int mi = 0; mi < 4; ++mi) redm[colh + wm + mi * 16 + la] = tmp4[mi];
    }
    __syncthreads();
#pragma unroll
    for (int mi = 0; mi < 4; ++mi) {            // pass 2: exp, wave-half sum
        int q = wm + mi * 16 + (la & 15);
        float m = fmaxf(redm[q], redm[128 + q]);
        float sm = 0.f;
#pragma unroll
        for (int ni = 0; ni < 4; ++ni) {
            int kb = wn + ni * 16 + (la >> 4) * 4;
#pragma unroll
            for (int j = 0; j < 4; ++j) {
                float e = (kb + j <= q) ? __expf(acc[mi][ni][j] - m) : 0.f;
                acc[mi][ni][j] = e;
                sm += e;
            }
        }
        sm += __shfl_xor(sm, 16);
        sm += __shfl_xor(sm, 32);
        tmp4[mi] = sm;
    }
    __syncthreads();
    if ((la >> 4) == 0) {
#pragma unroll
        for (int mi = 0; mi < 4; ++mi) reds[colh + wm + mi * 16 + la] = tmp4[mi];
    }
    __syncthreads();
#pragma unroll
    for (int mi = 0; mi < 4; ++mi) {            // pass 3: normalize, pack P -> sS
        int q = wm + mi * 16 + (la & 15);
        float inv = 1.f / (reds[q] + reds[128 + q]);
#pragma unroll
        for (int ni = 0; ni < 4; ++ni) {
            int kb = wn + ni * 16 + (la >> 4) * 4;
            us4 sv;
            sv.x = f2bf(acc[mi][ni][0] * inv); sv.y = f2bf(acc[mi][ni][1] * inv);
            sv.z = f2bf(acc[mi][ni][2] * inv); sv.w = f2bf(acc[mi][ni][3] * inv);
            *(us4*)(sS + q * 256 + ((2 * kb) ^ ((q & 7) << 4))) = sv;
        }
    }
    __syncthreads();                             // sS + sVT complete before PV

    // phase 4: O = P V  (wave tile 64M x 32N, K=128; swapped mfma -> packed O stores)
    const int wm2 = (w >> 1) * 64, wn2 = (w & 1) * 32;
    facc4 a2[4][2];
#pragma unroll
    for (int mi = 0; mi < 4; ++mi) { a2[mi][0] = zero4; a2[mi][1] = zero4; }
#pragma unroll
    for (int ks = 0; ks < 4; ++ks) {
        bfrag8 pa[4], vb[2];
        const int koffb = (ks * 32 + (la >> 4) * 8) * 2;
#pragma unroll
        for (int mi = 0; mi < 4; ++mi) {
            int rowa = wm2 + mi * 16 + (la & 15);
            pa[mi] = *(const bfrag8*)(sS + rowa * 256 + (koffb ^ ((rowa & 7) << 4)));
        }
#pragma unroll
        for (int ni = 0; ni < 2; ++ni) {
            int rowb = wn2 + ni * 16 + (la & 15);
            vb[ni] = *(const bfrag8*)(sVT + rowb * 256 + (koffb ^ ((rowb & 7) << 4)));
        }
#pragma unroll
        for (int mi = 0; mi < 4; ++mi)
#pragma unroll
            for (int ni = 0; ni < 2; ++ni)
                a2[mi][ni] = __builtin_amdgcn_mfma_f32_16x16x32_bf16(vb[ni], pa[mi], a2[mi][ni], 0, 0, 0);
    }
#pragma unroll
    for (int mi = 0; mi < 4; ++mi) {
        int s = wm2 + mi * 16 + (la & 15);
#pragma unroll
        for (int ni = 0; ni < 2; ++ni) {
            int db = wn2 + ni * 16 + (la >> 4) * 4;
            us4 ov;
            ov.x = f2bf(a2[mi][ni][0]); ov.y = f2bf(a2[mi][ni][1]);
            ov.z = f2bf(a2[mi][ni][2]); ov.w = f2bf(a2[mi][ni][3]);
            *(us4*)(obf + ((size_t)(b * 128 + s)) * 1024 + h * 64 + db) = ov;
        }
    }
}

// ------- fused residual + LayerNorm, all-bf16 stream: t = res + go; LN(t) -> xb -------
__global__ __launch_bounds__(256) void ln_res_kernel(const bf16* __restrict__ go,
                                                     const bf16* __restrict__ res,
                                                     const float* __restrict__ g, const float* __restrict__ be,
                                                     bf16* __restrict__ xb_out)
{
    const int row = blockIdx.x, t = threadIdx.x;
    size_t o = (size_t)row * 1024 + t * 4;
    us4 gv4 = *(const us4*)(go + o);
    us4 rv4 = *(const us4*)(res + o);
    float t0 = bf2f(rv4.x) + bf2f(gv4.x);
    float t1 = bf2f(rv4.y) + bf2f(gv4.y);
    float t2 = bf2f(rv4.z) + bf2f(gv4.z);
    float t3 = bf2f(rv4.w) + bf2f(gv4.w);
    float s = t0 + t1 + t2 + t3;
    float q = t0 * t0 + t1 * t1 + t2 * t2 + t3 * t3;
#pragma unroll
    for (int off = 32; off; off >>= 1) {
        s += __shfl_xor(s, off);
        q += __shfl_xor(q, off);
    }
    __shared__ float ssum[4], sqs[4];
    if ((t & 63) == 0) { ssum[t >> 6] = s; sqs[t >> 6] = q; }
    __syncthreads();
    s = ssum[0] + ssum[1] + ssum[2] + ssum[3];
    q = sqs[0] + sqs[1] + sqs[2] + sqs[3];
    float mean = s * (1.f / 1024.f);
    float var = q * (1.f / 1024.f) - mean * mean;
    float rstd = rsqrtf(var + 1e-5f);
    float4 gv = *(const float4*)(g + t * 4);
    float4 bv = *(const float4*)(be + t * 4);
    float o0 = (t0 - mean) * rstd * gv.x + bv.x;
    float o1 = (t1 - mean) * rstd * gv.y + bv.y;
    float o2 = (t2 - mean) * rstd * gv.z + bv.z;
    float o3 = (t3 - mean) * rstd * gv.w + bv.w;
    us4 obv; obv.x = f2bf(o0); obv.y = f2bf(o1); obv.z = f2bf(o2); obv.w = f2bf(o3);
    *(us4*)(xb_out + o) = obv;
}

// ---------------- MDN finalize / scatter ----------------
__global__ void finalize_kernel(const float* __restrict__ hout, float* __restrict__ out) {
    const size_t O_PI_M = 0, O_MU_M = 32512, O_VAR_M = 552704, O_PI_V = 1072896,
                 O_MU_V = 1105408, O_VAR_V = 1625600, O_MASK = 2145792;
    int rm = blockIdx.x;                    // b*127+m, 4064 rows
    const float* hrow = hout + (size_t)rm * 529;
    int t = threadIdx.x;
    if (t < 128) {
        out[O_MU_M  + (size_t)rm * 128 + t] = hrow[9 + t];
        out[O_VAR_M + (size_t)rm * 128 + t] = expf(hrow[137 + t]);
        out[O_MU_V  + (size_t)rm * 128 + t] = hrow[273 + t];
        out[O_VAR_V + (size_t)rm * 128 + t] = expf(hrow[401 + t]);
    } else if (t == 128) {
        out[O_MASK + rm] = hrow[0];
    } else if (t == 129 || t == 130) {
        int boff = (t == 129) ? 1 : 265;
        size_t oo = ((t == 129) ? O_PI_M : O_PI_V) + (size_t)rm * 8;
        float v[8], mx = -1e30f;
#pragma unroll
        for (int j = 0; j < 8; ++j) { v[j] = hrow[boff + j]; mx = fmaxf(mx, v[j]); }
        float sm = 0.f;
#pragma unroll
        for (int j = 0; j < 8; ++j) { v[j] = expf(v[j] - mx); sm += v[j]; }
        float inv = 1.f / sm;
#pragma unroll
        for (int j = 0; j < 8; ++j) out[oo + j] = v[j] * inv;
    }
}

// ---------------- launcher ----------------
extern "C" void kernel_launch(void* const* d_in, const int* in_sizes, int n_in,
                              void* d_out, int out_size, void* d_ws, size_t ws_size,
                              hipStream_t stream) {
    (void)in_sizes; (void)n_in; (void)out_size; (void)ws_size;
    const float* input   = (const float*)d_in[0];
    const float* targets = (const float*)d_in[1];
    const float* W_emb   = (const float*)d_in[2];
    const float* b_emb   = (const float*)d_in[3];
    const float* sos     = (const float*)d_in[4];
    const float* Wqkv    = (const float*)d_in[5];
    const float* bqkv    = (const float*)d_in[6];
    const float* Wo      = (const float*)d_in[7];
    const float* bo      = (const float*)d_in[8];
    const float* W1      = (const float*)d_in[9];
    const float* b1      = (const float*)d_in[10];
    const float* W2      = (const float*)d_in[11];
    const float* b2      = (const float*)d_in[12];
    const float* g1      = (const float*)d_in[13];
    const float* be1     = (const float*)d_in[14];
    const float* g2      = (const float*)d_in[15];
    const float* be2     = (const float*)d_in[16];
    const float* Wm      = (const float*)d_in[17];
    const float* bm      = (const float*)d_in[18];
    const float* Wpi_m   = (const float*)d_in[19];
    const float* bpi_m   = (const float*)d_in[20];
    const float* Wmu_m   = (const float*)d_in[21];
    const float* bmu_m   = (const float*)d_in[22];
    const float* Wsg_m   = (const float*)d_in[23];
    const float* bsg_m   = (const float*)d_in[24];
    const float* Wpi_v   = (const float*)d_in[25];
    const float* bpi_v   = (const float*)d_in[26];
    const float* Wmu_v   = (const float*)d_in[27];
    const float* bmu_v   = (const float*)d_in[28];
    const float* Wsg_v   = (const float*)d_in[29];
    const float* bsg_v   = (const float*)d_in[30];
    float* out = (float*)d_out;

    char* ws = (char*)d_ws;                            // ~167 MB total
    float* pe      = (float*)(ws + 0);                 // 0.5 MB
    bf16*  xin     = (bf16*)(ws + 524288);             // 4.72 MB
    bf16*  wemb    = (bf16*)(ws + 5242880);            // 1.18 MB
    bf16*  whead   = (bf16*)(ws + 6422528);            // 1.31 MB (640 rows)
    float* bhead   = (float*)(ws + 7733248);           // 2.5 KB
    bf16*  xb      = (bf16*)(ws + 24513024);           // 8.4 MB (bf16 residual stream + GEMM input)
    bf16*  qkvb    = (bf16*)(ws + 32901632);           // 25.2 MB
    bf16*  ob      = (bf16*)(ws + 58067456);           // 8.4 MB (attn out, reused as FF hidden)
    bf16*  tmpb    = (bf16*)(ws + 66456064);           // 8.4 MB (gemm-out bf16, pre-LN)
    bf16*  wqb_all = (bf16*)(ws + 83233280);           // 37.7 MB (6 layers)
    bf16*  wob_all = (bf16*)(ws + 120982016);          // 12.6 MB
    bf16*  w1b_all = (bf16*)(ws + 133564928);          // 12.6 MB
    bf16*  w2b_all = (bf16*)(ws + 146147840);          // 12.6 MB
    float* hout    = (float*)(ws + 158730752);         // 8.6 MB

    prep_cvt_kernel<<<6497, 256, 0, stream>>>(input, targets, sos, W_emb,
                                              Wm, Wpi_m, Wmu_m, Wsg_m, Wpi_v, Wmu_v, Wsg_v,
                                              bm, bpi_m, bmu_m, bsg_m, bpi_v, bmu_v, bsg_v,
                                              Wqkv, Wo, W1, W2,
                                              pe, xin, wemb, whead, bhead,
                                              wqb_all, wob_all, w1b_all, w2b_all);
    // x = XIN @ Wemb^T + b + pe -> xb (bf16 residual stream); K=576 -> BK64 CFG=1
    gemm_bt<4, 1><<<dim3(8, 32, 1), 512, 0, stream>>>(xin, wemb, nullptr, xb, b_emb, pe,
                                                      4096, 1024, 576, 576, 576, 1024, 0, 0);
    for (int l = 0; l < 6; ++l) {
        const bf16* wqb = wqb_all + (size_t)l * 3145728;
        const bf16* wob = wob_all + (size_t)l * 1048576;
        const bf16* w1b = w1b_all + (size_t)l * 1048576;
        const bf16* w2b = w2b_all + (size_t)l * 1048576;
        // qkv = x @ Wqkv^T + b  (bf16 out) -- 768 blocks, single-buffer, 3 blocks/CU
        gemm_bt<0, 0><<<dim3(24, 32, 1), 256, 0, stream>>>(xb, wqb, nullptr, qkvb, bqkv + l * 3072,
                                                           nullptr, 4096, 3072, 1024, 1024, 1024, 3072, 0, 0);
        attn_fused<<<512, 256, 0, stream>>>(qkvb, ob);
        // go = o @ Wo^T + bo (bf16); residual folded into ln_res -- BK128 dbuf
        gemm_bt<0, 2><<<dim3(8, 32, 1), 512, 0, stream>>>(ob, wob, nullptr, tmpb, bo + l * 1024,
                                                          nullptr, 4096, 1024, 1024, 1024, 1024, 1024, 0, 0);
        ln_res_kernel<<<4096, 256, 0, stream>>>(tmpb, xb, g1 + l * 1024, be1 + l * 1024, xb);
        // t1 = relu(x @ W1^T + b1) (bf16, reuse ob)
        gemm_bt<1, 2><<<dim3(8, 32, 1), 512, 0, stream>>>(xb, w1b, nullptr, ob, b1 + l * 1024,
                                                          nullptr, 4096, 1024, 1024, 1024, 1024, 1024, 0, 0);
        // go = t1 @ W2^T + b2 (bf16); residual folded into ln_res
        gemm_bt<0, 2><<<dim3(8, 32, 1), 512, 0, stream>>>(ob, w2b, nullptr, tmpb, b2 + l * 1024,
                                                          nullptr, 4096, 1024, 1024, 1024, 1024, 1024, 0, 0);
        ln_res_kernel<<<4096, 256, 0, stream>>>(tmpb, xb, g2 + l * 1024, be2 + l * 1024, xb);
    }
    // heads: per-batch M=127 rows of x -> hout (B,127,529) -- 160 blocks, BK128 dbuf
    gemm_bt<3, 2><<<dim3(5, 1, 32), 512, 0, stream>>>(xb, whead, hout, nullptr, bhead, nullptr,
                                                      127, 529, 1024, 1024, 1024, 529, 131072LL, 67183LL);
    finalize_kernel<<<4064, 256, 0, stream>>>(hout, out);
}

// Round 12
// 732.444 us; speedup vs baseline: 1.4086x; 1.0120x over previous
//
#include <hip/hip_runtime.h>
#include <hip/hip_bf16.h>

typedef __hip_bfloat16 bf16;
typedef __attribute__((ext_vector_type(8))) short bfrag8;   // 8 bf16 (4 VGPR) MFMA A/B frag
typedef __attribute__((ext_vector_type(4))) float facc4;    // MFMA C/D frag
typedef __attribute__((ext_vector_type(4))) unsigned short us4;
typedef __attribute__((ext_vector_type(8))) unsigned short us8;
typedef __attribute__((ext_vector_type(4))) float f32x4;    // true clang vector (for nontemporal)

#define AS1C const __attribute__((address_space(1))) void
#define AS3  __attribute__((address_space(3))) void

__device__ __forceinline__ void gload_lds16(const void* src, void* dst) {
    __builtin_amdgcn_global_load_lds((AS1C*)src, (AS3*)dst, 16, 0, 0);
}

__device__ __forceinline__ unsigned short f2bf(float f) {   // RNE, finite inputs
    unsigned u = __float_as_uint(f);
    unsigned r = u + 0x7FFFu + ((u >> 16) & 1u);
    return (unsigned short)(r >> 16);
}
__device__ __forceinline__ float bf2f(unsigned short u) {   // exact
    return __uint_as_float((unsigned)u << 16);
}

// ------- merged prep+cvt: weights first (heavy), DENSE vectorized tail -------
// [0,4608): weight cvt | [4608,4736): pe | [4736,5888): xin | [5888,6176): wemb
// [6176,6496): whead | 6496: bhead
__global__ void prep_cvt_kernel(const float* __restrict__ input, const float* __restrict__ targets,
                                const float* __restrict__ sos, const float* __restrict__ W_emb,
                                const float* __restrict__ Wm, const float* __restrict__ Wpi_m,
                                const float* __restrict__ Wmu_m, const float* __restrict__ Wsg_m,
                                const float* __restrict__ Wpi_v, const float* __restrict__ Wmu_v,
                                const float* __restrict__ Wsg_v,
                                const float* __restrict__ bm, const float* __restrict__ bpi_m,
                                const float* __restrict__ bmu_m, const float* __restrict__ bsg_m,
                                const float* __restrict__ bpi_v, const float* __restrict__ bmu_v,
                                const float* __restrict__ bsg_v,
                                const float* __restrict__ Wqkv, const float* __restrict__ Wo,
                                const float* __restrict__ W1, const float* __restrict__ W2,
                                float* __restrict__ pe, bf16* __restrict__ xin,
                                bf16* __restrict__ wemb, bf16* __restrict__ whead,
                                float* __restrict__ bhead,
                                bf16* __restrict__ wqb, bf16* __restrict__ wob,
                                bf16* __restrict__ w1b, bf16* __restrict__ w2b) {
    int bid = blockIdx.x;
    int t = threadIdx.x;
    if (bid < 4608) {                                    // weight cvt (NT loads, 16B stores)
        int l = bid / 768;
        int s = bid - l * 768;
        const float* src; bf16* dst;
        if (s < 384)      { src = Wqkv + (size_t)l * 3145728; dst = wqb + (size_t)l * 3145728; }
        else if (s < 512) { src = Wo + (size_t)l * 1048576; dst = wob + (size_t)l * 1048576; s -= 384; }
        else if (s < 640) { src = W1 + (size_t)l * 1048576; dst = w1b + (size_t)l * 1048576; s -= 512; }
        else              { src = W2 + (size_t)l * 1048576; dst = w2b + (size_t)l * 1048576; s -= 640; }
        size_t pbase = (size_t)s * 1024 + t;
#pragma unroll
        for (int it = 0; it < 4; ++it) {
            size_t o = (pbase + it * 256) * 8;           // 8 floats per pair
            const f32x4* p = (const f32x4*)(src + o);
            f32x4 v1 = __builtin_nontemporal_load(p);
            f32x4 v2 = __builtin_nontemporal_load(p + 1);
            us8 w8;
            w8[0] = f2bf(v1.x); w8[1] = f2bf(v1.y); w8[2] = f2bf(v1.z); w8[3] = f2bf(v1.w);
            w8[4] = f2bf(v2.x); w8[5] = f2bf(v2.y); w8[6] = f2bf(v2.z); w8[7] = f2bf(v2.w);
            *(us8*)(dst + o) = w8;
        }
    } else if (bid < 4736) {                             // pe [128][1024]: block=row s, 4 elems/thread
        int s = bid - 4608;
        float4 v;
#pragma unroll
        for (int j = 0; j < 4; ++j) {
            int c = t * 4 + j;
            int i = c >> 1;
            float div = expf(-9.210340371976184f * (float)(2 * i) * (1.f / 1024.f));
            float a = (float)s * div;
            v[j] = (c & 1) ? cosf(a) : sinf(a);
        }
        *(float4*)(pe + (size_t)s * 1024 + t * 4) = v;
    } else if (bid < 5888) {                             // xin: 294912 us8-chunks (4096 rows x 72)
        int chunk = (bid - 4736) * 256 + t;
        int row = chunk / 72;
        int cc = chunk - row * 72;
        int b = row >> 7, s = row & 127;
        us8 w8;
        if (cc < 64) {                                   // cond region: input[b][cc*8..+7]
            const float* p = input + (size_t)b * 512 + cc * 8;
            float4 v1 = *(const float4*)p;
            float4 v2 = *(const float4*)(p + 4);
            w8[0] = f2bf(v1.x); w8[1] = f2bf(v1.y); w8[2] = f2bf(v1.z); w8[3] = f2bf(v1.w);
            w8[4] = f2bf(v2.x); w8[5] = f2bf(v2.y); w8[6] = f2bf(v2.z); w8[7] = f2bf(v2.w);
        } else {                                         // token region: cols 512..575
#pragma unroll
            for (int j = 0; j < 8; ++j) {
                int col = cc * 8 + j;
                float v = 0.f;
                if (col < 545) {
                    int jj = col - 512;
                    v = (s == 0) ? sos[jj] : targets[((size_t)b * 127 + (s - 1)) * 33 + jj];
                }
                w8[j] = f2bf(v);
            }
        }
        *(us8*)(xin + (size_t)row * 576 + cc * 8) = w8;
    } else if (bid < 6176) {                             // wemb: 73728 chunks (1024 rows x 72), pad 545->576
        int chunk = (bid - 5888) * 256 + t;
        int row = chunk / 72;
        int cc = chunk - row * 72;
        us8 w8;
#pragma unroll
        for (int j = 0; j < 8; ++j) {
            int col = cc * 8 + j;
            w8[j] = f2bf(col < 545 ? W_emb[(size_t)row * 545 + col] : 0.f);
        }
        *(us8*)(wemb + (size_t)row * 576 + cc * 8) = w8;
    } else if (bid < 6496) {                             // whead: 81920 chunks (640 rows x 128)
        int chunk = (bid - 6176) * 256 + t;
        int r = chunk >> 7;
        int cc = chunk & 127;
        const float* wsrc = nullptr; int off = 0;
        if (r == 0)        { wsrc = Wm;    off = 0; }
        else if (r < 9)    { wsrc = Wpi_m; off = r - 1; }
        else if (r < 137)  { wsrc = Wmu_m; off = r - 9; }
        else if (r < 265)  { wsrc = Wsg_m; off = r - 137; }
        else if (r < 273)  { wsrc = Wpi_v; off = r - 265; }
        else if (r < 401)  { wsrc = Wmu_v; off = r - 273; }
        else if (r < 529)  { wsrc = Wsg_v; off = r - 401; }
        us8 w8;
        if (wsrc) {
            const float* p = wsrc + (size_t)off * 1024 + cc * 8;
            float4 v1 = *(const float4*)p;
            float4 v2 = *(const float4*)(p + 4);
            w8[0] = f2bf(v1.x); w8[1] = f2bf(v1.y); w8[2] = f2bf(v1.z); w8[3] = f2bf(v1.w);
            w8[4] = f2bf(v2.x); w8[5] = f2bf(v2.y); w8[6] = f2bf(v2.z); w8[7] = f2bf(v2.w);
        } else {
#pragma unroll
            for (int j = 0; j < 8; ++j) w8[j] = 0;
        }
        *(us8*)(whead + (size_t)r * 1024 + cc * 8) = w8;
    } else {                                             // bhead: 529 scalars
        if (t < 529) {
            const float* bsrc; int off;
            if (t == 0)       { bsrc = bm;    off = 0; }
            else if (t < 9)   { bsrc = bpi_m; off = t - 1; }
            else if (t < 137) { bsrc = bmu_m; off = t - 9; }
            else if (t < 265) { bsrc = bsg_m; off = t - 137; }
            else if (t < 273) { bsrc = bpi_v; off = t - 265; }
            else if (t < 401) { bsrc = bmu_v; off = t - 273; }
            else              { bsrc = bsg_v; off = t - 401; }
            bhead[t] = bsrc[off];
        }
    }
}

// ---------------- main GEMM: C[M,N] = A[M,K] @ B[N,K]^T (+epilogue) ----------------
// 128x128 tile. Operand-swapped MFMA (C^T frags -> vectorized epilogue).
// CFG=0: 256t, BK=64, single-buffer, 4 blocks/CU (bumped from 3; VGPR est ~116 <= 128)
//        -- big grids (QKV, 768 blocks), cross-block overlap regime.
// CFG=1: 512t, BK=64, dbuf -- grid-limited launches with K%128!=0 (embed, K=576).
// CFG=2: 512t, BK=128, dbuf, 128KB LDS -- grid-limited (1 block/CU) K%128==0.
// EPI: 0 bias->bf16 | 1 bias+relu->bf16 | 3 bias->f32 scalar (odd ldc) | 4 bias+pe->bf16
template<int EPI, int CFG>
__global__ __launch_bounds__(CFG ? 512 : 256, CFG ? 2 : 4) void gemm_bt(
    const bf16* __restrict__ A, const bf16* __restrict__ Bw,
    float* __restrict__ Cf, bf16* __restrict__ Cb,
    const float* __restrict__ bias, const float* __restrict__ pe,
    int M, int N, int K, int lda, int ldb, int ldc, long long Az, long long Cz)
{
    constexpr int NT  = CFG ? 512 : 256;    // threads
    constexpr int NB  = CFG ? 2 : 1;        // LDS buffers
    constexpr int MI  = CFG ? 2 : 4;        // per-wave M fragments
    constexpr int BK  = (CFG == 2) ? 128 : 64;
    constexpr int RB  = BK * 2;             // row bytes in LDS
    constexpr int CPR = BK / 8;             // 16B chunks per row
    constexpr int NCH = (128 * CPR) / NT;   // staging chunks per thread per array
    constexpr int KS  = BK / 32;            // 32-wide k-slices per tile
    __shared__ __align__(16) bf16 sA[NB][128 * BK];
    __shared__ __align__(16) bf16 sB[NB][128 * BK];
    const int t = threadIdx.x;
    const int w = t >> 6, la = t & 63;
    const int wm = CFG ? (w >> 1) * 32 : (w >> 1) * 64;
    const int wn = (w & 1) * 64;
    const int m0 = blockIdx.y * 128, n0 = blockIdx.x * 128;
    const int z = blockIdx.z;
    A += (long long)z * Az;

    facc4 zero4 = {0.f, 0.f, 0.f, 0.f};
    facc4 acc[MI][4];
#pragma unroll
    for (int mi = 0; mi < MI; ++mi)
#pragma unroll
        for (int ni = 0; ni < 4; ++ni) acc[mi][ni] = zero4;

    auto stage = [&](int buf, int kt) {
#pragma unroll
        for (int i = 0; i < NCH; ++i) {
            int c = i * NT + t;
            int r = c / CPR;
            int cc = c - r * CPR;
            int bc = (cc * 16) ^ ((r & 7) << 4);        // pre-swizzled source byte col
            gload_lds16(A + (size_t)(m0 + r) * lda + kt + (bc >> 1),
                        (char*)sA[buf] + (size_t)c * 16);
            gload_lds16(Bw + (size_t)(n0 + r) * ldb + kt + (bc >> 1),
                        (char*)sB[buf] + (size_t)c * 16);
        }
    };
    auto compute = [&](int buf) {
#pragma unroll
        for (int ks = 0; ks < KS; ++ks) {
            bfrag8 af[MI], bfv[4];
            const int koffb = (ks * 32 + (la >> 4) * 8) * 2;
#pragma unroll
            for (int i = 0; i < MI; ++i) {
                int rowa = wm + i * 16 + (la & 15);
                af[i] = *(const bfrag8*)((const char*)sA[buf] + rowa * RB + (koffb ^ ((rowa & 7) << 4)));
            }
#pragma unroll
            for (int i = 0; i < 4; ++i) {
                int rowb = wn + i * 16 + (la & 15);
                bfv[i] = *(const bfrag8*)((const char*)sB[buf] + rowb * RB + (koffb ^ ((rowb & 7) << 4)));
            }
#pragma unroll
            for (int mi = 0; mi < MI; ++mi)
#pragma unroll
                for (int ni = 0; ni < 4; ++ni)     // swapped operands -> C^T fragment
                    acc[mi][ni] = __builtin_amdgcn_mfma_f32_16x16x32_bf16(bfv[ni], af[mi], acc[mi][ni], 0, 0, 0);
        }
    };

    const int nk = K / BK;
    if constexpr (CFG) {
        stage(0, 0);
        __syncthreads();
        int cur = 0;
        for (int kt = 0; kt < nk; ++kt) {
            if (kt + 1 < nk) stage(cur ^ 1, (kt + 1) * BK);
            compute(cur);
            __syncthreads();        // drains stage(k+1) vmcnt; frees cur
            cur ^= 1;
        }
    } else {
        for (int kt = 0; kt < nk; ++kt) {
            stage(0, kt * BK);
            __syncthreads();
            compute(0);
            __syncthreads();
        }
    }
    // epilogue: thread holds C[row][colb..colb+3]
#pragma unroll
    for (int mi = 0; mi < MI; ++mi) {
        int row = m0 + wm + mi * 16 + (la & 15);
#pragma unroll
        for (int ni = 0; ni < 4; ++ni) {
            int colb = n0 + wn + ni * 16 + (la >> 4) * 4;
            if constexpr (EPI == 3) {               // scalar path (odd ldc / edge guards)
                if (row >= M) continue;
#pragma unroll
                for (int j = 0; j < 4; ++j) {
                    int col = colb + j;
                    if (col < N)
                        Cf[(size_t)z * Cz + (size_t)row * ldc + col] = acc[mi][ni][j] + bias[col];
                }
            } else {
                float4 bv = *(const float4*)(bias + colb);
                facc4 v = acc[mi][ni];
                v[0] += bv.x; v[1] += bv.y; v[2] += bv.z; v[3] += bv.w;
                size_t cidx = (size_t)row * ldc + colb;
                if constexpr (EPI == 0) {
                    us4 o; o.x = f2bf(v[0]); o.y = f2bf(v[1]); o.z = f2bf(v[2]); o.w = f2bf(v[3]);
                    *(us4*)(Cb + cidx) = o;
                } else if constexpr (EPI == 1) {
                    us4 o;
                    o.x = f2bf(v[0] > 0.f ? v[0] : 0.f); o.y = f2bf(v[1] > 0.f ? v[1] : 0.f);
                    o.z = f2bf(v[2] > 0.f ? v[2] : 0.f); o.w = f2bf(v[3] > 0.f ? v[3] : 0.f);
                    *(us4*)(Cb + cidx) = o;
                } else {                            // EPI == 4: bias + pe -> bf16
                    float4 p = *(const float4*)(pe + (size_t)(row & 127) * 1024 + colb);
                    us4 o;
                    o.x = f2bf(v[0] + p.x); o.y = f2bf(v[1] + p.y);
                    o.z = f2bf(v[2] + p.z); o.w = f2bf(v[3] + p.w);
                    *(us4*)(Cb + cidx) = o;
                }
            }
        }
    }
}

// ---------------- fused attention: one block per (b,h) ----------------
// S=128, D=64. Swapped QK^T keeps S rows lane-local -> in-register causal softmax.
// ONE-PASS per half: max + exp-sum in a single sweep; halves combined analytically
// (tot = s0*e^{m0-M} + s1*e^{m1-M}; P = acc*e^{m_half-M}/tot). 4 barriers total.
__global__ __launch_bounds__(256) void attn_fused(const bf16* __restrict__ qkv, bf16* __restrict__ obf)
{
    __shared__ __align__(16) char lds[65536];
    char* sQ  = lds;            // [128] rows x 128B, swizzled
    char* sK  = lds + 16384;    // [128] rows x 128B (dead after QK^T -> red arrays)
    char* sS  = lds + 32768;    // [128] rows x 256B bf16 (P)
    char* sVT = lds;            // [64] rows x 256B (V transposed), overlaps sQ
    float* redm = (float*)(lds + 16384);            // [2][128] row max per col-half
    float* reds = (float*)(lds + 16384 + 1024);     // [2][128] row exp-sum per col-half

    const int t = threadIdx.x, w = t >> 6, la = t & 63;
    const int b = blockIdx.x >> 4, h = blockIdx.x & 15;
    const size_t base = (size_t)b * 128 * 3072 + (size_t)h * 64;

    // phase 1: stage Q, K (swizzled via pre-swizzled source)
#pragma unroll
    for (int i = 0; i < 4; ++i) {
        int c = i * 256 + w * 64 + la;
        int r = c >> 3;
        int bc = ((c & 7) * 16) ^ ((r & 7) << 4);
        gload_lds16(qkv + base + (size_t)r * 3072 + (bc >> 1),
                    sQ + (size_t)(i * 256 + w * 64) * 16);
        gload_lds16(qkv + base + 1024 + (size_t)r * 3072 + (bc >> 1),
                    sK + (size_t)(i * 256 + w * 64) * 16);
    }
    __syncthreads();

    // phase 2: S = Q K^T (swapped mfma -> thread holds S[q][kb..kb+3], fp32)
    const int wm = (w >> 1) * 64, wn = (w & 1) * 64;
    facc4 zero4 = {0.f, 0.f, 0.f, 0.f};
    facc4 acc[4][4];
#pragma unroll
    for (int mi = 0; mi < 4; ++mi)
#pragma unroll
        for (int ni = 0; ni < 4; ++ni) acc[mi][ni] = zero4;
#pragma unroll
    for (int ks = 0; ks < 2; ++ks) {
        bfrag8 af[4], bfv[4];
        const int koffb = (ks * 32 + (la >> 4) * 8) * 2;
#pragma unroll
        for (int i = 0; i < 4; ++i) {
            int rowa = wm + i * 16 + (la & 15);
            af[i] = *(const bfrag8*)(sQ + rowa * 128 + (koffb ^ ((rowa & 7) << 4)));
            int rowb = wn + i * 16 + (la & 15);
            bfv[i] = *(const bfrag8*)(sK + rowb * 128 + (koffb ^ ((rowb & 7) << 4)));
        }
#pragma unroll
        for (int mi = 0; mi < 4; ++mi)
#pragma unroll
            for (int ni = 0; ni < 4; ++ni)
                acc[mi][ni] = __builtin_amdgcn_mfma_f32_16x16x32_bf16(bfv[ni], af[mi], acc[mi][ni], 0, 0, 0);
    }
    __syncthreads();        // all waves done reading sQ/sK

    // phase 3a: stage V transposed into sVT (overlaps softmax VALU below)
#pragma unroll
    for (int i = 0; i < 4; ++i) {
        int c = i * 256 + t;
        int r = c >> 3;             // key index s'
        int d0 = (c & 7) * 8;
        bfrag8 vv = *(const bfrag8*)(qkv + base + 2048 + (size_t)r * 3072 + d0);
#pragma unroll
        for (int j = 0; j < 8; ++j) {
            int d = d0 + j;
            *(short*)(sVT + d * 256 + ((2 * r) ^ ((d & 7) << 4))) = vv[j];
        }
    }

    // phase 3b: in-register causal softmax (one sweep per half)
    const int colh = (w & 1) * 128;
    float tmpm[4], tmps[4];
#pragma unroll
    for (int mi = 0; mi < 4; ++mi) {
        int q = wm + mi * 16 + (la & 15);
        float mx = -1e30f;
#pragma unroll
        for (int ni = 0; ni < 4; ++ni) {
            int kb = wn + ni * 16 + (la >> 4) * 4;
#pragma unroll
            for (int j = 0; j < 4; ++j) {
                float s = acc[mi][ni][j] * 0.125f;
                acc[mi][ni][j] = s;
                if (kb + j <= q) mx = fmaxf(mx, s);
            }
        }
        mx = fmaxf(mx, __shfl_xor(mx, 16));     // reduce over la>>4 (the k-axis lanes)
        mx = fmaxf(mx, __shfl_xor(mx, 32));
        float sm = 0.f;
#pragma unroll
        for (int ni = 0; ni < 4; ++ni) {
            int kb = wn + ni * 16 + (la >> 4) * 4;
#pragma unroll
            for (int j = 0; j < 4; ++j) {
                float e = (kb + j <= q) ? __expf(acc[mi][ni][j] - mx) : 0.f;
                acc[mi][ni][j] = e;
                sm += e;
            }
        }
        sm += __shfl_xor(sm, 16);
        sm += __shfl_xor(sm, 32);
        tmpm[mi] = mx; tmps[mi] = sm;
    }
    if ((la >> 4) == 0) {
#pragma unroll
        for (int mi = 0; mi < 4; ++mi) {
            redm[colh + wm + mi * 16 + la] = tmpm[mi];
            reds[colh + wm + mi * 16 + la] = tmps[mi];
        }
    }
    __syncthreads();
#pragma unroll
    for (int mi = 0; mi < 4; ++mi) {            // combine halves, normalize, pack P -> sS
        int q = wm + mi * 16 + (la & 15);
        float m0 = redm[q], m1 = redm[128 + q];
        float M = fmaxf(m0, m1);
        float tot = reds[q] * __expf(m0 - M) + reds[128 + q] * __expf(m1 - M);
        float sc = __expf(tmpm[mi] - M) / tot;
#pragma unroll
        for (int ni = 0; ni < 4; ++ni) {
            int kb = wn + ni * 16 + (la >> 4) * 4;
            us4 sv;
            sv.x = f2bf(acc[mi][ni][0] * sc); sv.y = f2bf(acc[mi][ni][1] * sc);
            sv.z = f2bf(acc[mi][ni][2] * sc); sv.w = f2bf(acc[mi][ni][3] * sc);
            *(us4*)(sS + q * 256 + ((2 * kb) ^ ((q & 7) << 4))) = sv;
        }
    }
    __syncthreads();                             // sS + sVT complete before PV

    // phase 4: O = P V  (wave tile 64M x 32N, K=128; swapped mfma -> packed O stores)
    const int wm2 = (w >> 1) * 64, wn2 = (w & 1) * 32;
    facc4 a2[4][2];
#pragma unroll
    for (int mi = 0; mi < 4; ++mi) { a2[mi][0] = zero4; a2[mi][1] = zero4; }
#pragma unroll
    for (int ks = 0; ks < 4; ++ks) {
        bfrag8 pa[4], vb[2];
        const int koffb = (ks * 32 + (la >> 4) * 8) * 2;
#pragma unroll
        for (int mi = 0; mi < 4; ++mi) {
            int rowa = wm2 + mi * 16 + (la & 15);
            pa[mi] = *(const bfrag8*)(sS + rowa * 256 + (koffb ^ ((rowa & 7) << 4)));
        }
#pragma unroll
        for (int ni = 0; ni < 2; ++ni) {
            int rowb = wn2 + ni * 16 + (la & 15);
            vb[ni] = *(const bfrag8*)(sVT + rowb * 256 + (koffb ^ ((rowb & 7) << 4)));
        }
#pragma unroll
        for (int mi = 0; mi < 4; ++mi)
#pragma unroll
            for (int ni = 0; ni < 2; ++ni)
                a2[mi][ni] = __builtin_amdgcn_mfma_f32_16x16x32_bf16(vb[ni], pa[mi], a2[mi][ni], 0, 0, 0);
    }
#pragma unroll
    for (int mi = 0; mi < 4; ++mi) {
        int s = wm2 + mi * 16 + (la & 15);
#pragma unroll
        for (int ni = 0; ni < 2; ++ni) {
            int db = wn2 + ni * 16 + (la >> 4) * 4;
            us4 ov;
            ov.x = f2bf(a2[mi][ni][0]); ov.y = f2bf(a2[mi][ni][1]);
            ov.z = f2bf(a2[mi][ni][2]); ov.w = f2bf(a2[mi][ni][3]);
            *(us4*)(obf + ((size_t)(b * 128 + s)) * 1024 + h * 64 + db) = ov;
        }
    }
}

// ------- fused residual + LayerNorm, all-bf16 stream: t = res + go; LN(t) -> xb -------
// 2 rows per block, 16B us8 I/O (G13). In-place res==xb_out safe (element-owned).
__global__ __launch_bounds__(256) void ln_res_kernel(const bf16* __restrict__ go,
                                                     const bf16* __restrict__ res,
                                                     const float* __restrict__ g, const float* __restrict__ be,
                                                     bf16* __restrict__ xb_out)
{
    const int t = threadIdx.x;
    const int row = blockIdx.x * 2 + (t >> 7);   // 2 rows/block, 128 threads (2 waves) each
    const int ct = t & 127;
    size_t o = (size_t)row * 1024 + ct * 8;
    us8 gv8 = *(const us8*)(go + o);
    us8 rv8 = *(const us8*)(res + o);
    float v[8];
    float s = 0.f, q = 0.f;
#pragma unroll
    for (int j = 0; j < 8; ++j) {
        v[j] = bf2f(rv8[j]) + bf2f(gv8[j]);
        s += v[j];
        q += v[j] * v[j];
    }
#pragma unroll
    for (int off = 32; off; off >>= 1) {
        s += __shfl_xor(s, off);
        q += __shfl_xor(q, off);
    }
    __shared__ float ssum[4], sqs[4];
    if ((t & 63) == 0) { ssum[t >> 6] = s; sqs[t >> 6] = q; }
    __syncthreads();
    int rb = (t >> 7) * 2;
    s = ssum[rb] + ssum[rb + 1];
    q = sqs[rb] + sqs[rb + 1];
    float mean = s * (1.f / 1024.f);
    float var = q * (1.f / 1024.f) - mean * mean;
    float rstd = rsqrtf(var + 1e-5f);
    float4 g1v = *(const float4*)(g + ct * 8);
    float4 g2v = *(const float4*)(g + ct * 8 + 4);
    float4 b1v = *(const float4*)(be + ct * 8);
    float4 b2v = *(const float4*)(be + ct * 8 + 4);
    float ga[8] = {g1v.x, g1v.y, g1v.z, g1v.w, g2v.x, g2v.y, g2v.z, g2v.w};
    float ba[8] = {b1v.x, b1v.y, b1v.z, b1v.w, b2v.x, b2v.y, b2v.z, b2v.w};
    us8 ob;
#pragma unroll
    for (int j = 0; j < 8; ++j)
        ob[j] = f2bf((v[j] - mean) * rstd * ga[j] + ba[j]);
    *(us8*)(xb_out + o) = ob;
}

// ---------------- MDN finalize / scatter ----------------
__global__ void finalize_kernel(const float* __restrict__ hout, float* __restrict__ out) {
    const size_t O_PI_M = 0, O_MU_M = 32512, O_VAR_M = 552704, O_PI_V = 1072896,
                 O_MU_V = 1105408, O_VAR_V = 1625600, O_MASK = 2145792;
    int rm = blockIdx.x;                    // b*127+m, 4064 rows
    const float* hrow = hout + (size_t)rm * 529;
    int t = threadIdx.x;
    if (t < 128) {
        out[O_MU_M  + (size_t)rm * 128 + t] = hrow[9 + t];
        out[O_VAR_M + (size_t)rm * 128 + t] = expf(hrow[137 + t]);
        out[O_MU_V  + (size_t)rm * 128 + t] = hrow[273 + t];
        out[O_VAR_V + (size_t)rm * 128 + t] = expf(hrow[401 + t]);
    } else if (t == 128) {
        out[O_MASK + rm] = hrow[0];
    } else if (t == 129 || t == 130) {
        int boff = (t == 129) ? 1 : 265;
        size_t oo = ((t == 129) ? O_PI_M : O_PI_V) + (size_t)rm * 8;
        float v[8], mx = -1e30f;
#pragma unroll
        for (int j = 0; j < 8; ++j) { v[j] = hrow[boff + j]; mx = fmaxf(mx, v[j]); }
        float sm = 0.f;
#pragma unroll
        for (int j = 0; j < 8; ++j) { v[j] = expf(v[j] - mx); sm += v[j]; }
        float inv = 1.f / sm;
#pragma unroll
        for (int j = 0; j < 8; ++j) out[oo + j] = v[j] * inv;
    }
}

// ---------------- launcher ----------------
extern "C" void kernel_launch(void* const* d_in, const int* in_sizes, int n_in,
                              void* d_out, int out_size, void* d_ws, size_t ws_size,
                              hipStream_t stream) {
    (void)in_sizes; (void)n_in; (void)out_size; (void)ws_size;
    const float* input   = (const float*)d_in[0];
    const float* targets = (const float*)d_in[1];
    const float* W_emb   = (const float*)d_in[2];
    const float* b_emb   = (const float*)d_in[3];
    const float* sos     = (const float*)d_in[4];
    const float* Wqkv    = (const float*)d_in[5];
    const float* bqkv    = (const float*)d_in[6];
    const float* Wo      = (const float*)d_in[7];
    const float* bo      = (const float*)d_in[8];
    const float* W1      = (const float*)d_in[9];
    const float* b1      = (const float*)d_in[10];
    const float* W2      = (const float*)d_in[11];
    const float* b2      = (const float*)d_in[12];
    const float* g1      = (const float*)d_in[13];
    const float* be1     = (const float*)d_in[14];
    const float* g2      = (const float*)d_in[15];
    const float* be2     = (const float*)d_in[16];
    const float* Wm      = (const float*)d_in[17];
    const float* bm      = (const float*)d_in[18];
    const float* Wpi_m   = (const float*)d_in[19];
    const float* bpi_m   = (const float*)d_in[20];
    const float* Wmu_m   = (const float*)d_in[21];
    const float* bmu_m   = (const float*)d_in[22];
    const float* Wsg_m   = (const float*)d_in[23];
    const float* bsg_m   = (const float*)d_in[24];
    const float* Wpi_v   = (const float*)d_in[25];
    const float* bpi_v   = (const float*)d_in[26];
    const float* Wmu_v   = (const float*)d_in[27];
    const float* bmu_v   = (const float*)d_in[28];
    const float* Wsg_v   = (const float*)d_in[29];
    const float* bsg_v   = (const float*)d_in[30];
    float* out = (float*)d_out;

    char* ws = (char*)d_ws;                            // ~167 MB total
    float* pe      = (float*)(ws + 0);                 // 0.5 MB
    bf16*  xin     = (bf16*)(ws + 524288);             // 4.72 MB
    bf16*  wemb    = (bf16*)(ws + 5242880);            // 1.18 MB
    bf16*  whead   = (bf16*)(ws + 6422528);            // 1.31 MB (640 rows)
    float* bhead   = (float*)(ws + 7733248);           // 2.5 KB
    bf16*  xb      = (bf16*)(ws + 24513024);           // 8.4 MB (bf16 residual stream + GEMM input)
    bf16*  qkvb    = (bf16*)(ws + 32901632);           // 25.2 MB
    bf16*  ob      = (bf16*)(ws + 58067456);           // 8.4 MB (attn out, reused as FF hidden)
    bf16*  tmpb    = (bf16*)(ws + 66456064);           // 8.4 MB (gemm-out bf16, pre-LN)
    bf16*  wqb_all = (bf16*)(ws + 83233280);           // 37.7 MB (6 layers)
    bf16*  wob_all = (bf16*)(ws + 120982016);          // 12.6 MB
    bf16*  w1b_all = (bf16*)(ws + 133564928);          // 12.6 MB
    bf16*  w2b_all = (bf16*)(ws + 146147840);          // 12.6 MB
    float* hout    = (float*)(ws + 158730752);         // 8.6 MB

    prep_cvt_kernel<<<6497, 256, 0, stream>>>(input, targets, sos, W_emb,
                                              Wm, Wpi_m, Wmu_m, Wsg_m, Wpi_v, Wmu_v, Wsg_v,
                                              bm, bpi_m, bmu_m, bsg_m, bpi_v, bmu_v, bsg_v,
                                              Wqkv, Wo, W1, W2,
                                              pe, xin, wemb, whead, bhead,
                                              wqb_all, wob_all, w1b_all, w2b_all);
    // x = XIN @ Wemb^T + b + pe -> xb (bf16 residual stream); K=576 -> BK64 CFG=1
    gemm_bt<4, 1><<<dim3(8, 32, 1), 512, 0, stream>>>(xin, wemb, nullptr, xb, b_emb, pe,
                                                      4096, 1024, 576, 576, 576, 1024, 0, 0);
    for (int l = 0; l < 6; ++l) {
        const bf16* wqb = wqb_all + (size_t)l * 3145728;
        const bf16* wob = wob_all + (size_t)l * 1048576;
        const bf16* w1b = w1b_all + (size_t)l * 1048576;
        const bf16* w2b = w2b_all + (size_t)l * 1048576;
        // qkv = x @ Wqkv^T + b  (bf16 out) -- 768 blocks, single-buffer, 4 blocks/CU
        gemm_bt<0, 0><<<dim3(24, 32, 1), 256, 0, stream>>>(xb, wqb, nullptr, qkvb, bqkv + l * 3072,
                                                           nullptr, 4096, 3072, 1024, 1024, 1024, 3072, 0, 0);
        attn_fused<<<512, 256, 0, stream>>>(qkvb, ob);
        // go = o @ Wo^T + bo (bf16); residual folded into ln_res -- BK128 dbuf
        gemm_bt<0, 2><<<dim3(8, 32, 1), 512, 0, stream>>>(ob, wob, nullptr, tmpb, bo + l * 1024,
                                                          nullptr, 4096, 1024, 1024, 1024, 1024, 1024, 0, 0);
        ln_res_kernel<<<2048, 256, 0, stream>>>(tmpb, xb, g1 + l * 1024, be1 + l * 1024, xb);
        // t1 = relu(x @ W1^T + b1) (bf16, reuse ob)
        gemm_bt<1, 2><<<dim3(8, 32, 1), 512, 0, stream>>>(xb, w1b, nullptr, ob, b1 + l * 1024,
                                                          nullptr, 4096, 1024, 1024, 1024, 1024, 1024, 0, 0);
        // go = t1 @ W2^T + b2 (bf16); residual folded into ln_res
        gemm_bt<0, 2><<<dim3(8, 32, 1), 512, 0, stream>>>(ob, w2b, nullptr, tmpb, b2 + l * 1024,
                                                          nullptr, 4096, 1024, 1024, 1024, 1024, 1024, 0, 0);
        ln_res_kernel<<<2048, 256, 0, stream>>>(tmpb, xb, g2 + l * 1024, be2 + l * 1024, xb);
    }
    // heads: per-batch M=127 rows of x -> hout (B,127,529) -- 160 blocks, BK128 dbuf
    gemm_bt<3, 2><<<dim3(5, 1, 32), 512, 0, stream>>>(xb, whead, hout, nullptr, bhead, nullptr,
                                                      127, 529, 1024, 1024, 1024, 529, 131072LL, 67183LL);
    finalize_kernel<<<4064, 256, 0, stream>>>(hout, out);
}

// Round 13
// 708.045 us; speedup vs baseline: 1.4572x; 1.0345x over previous
//
#include <hip/hip_runtime.h>
#include <hip/hip_bf16.h>

typedef __hip_bfloat16 bf16;
typedef __attribute__((ext_vector_type(8))) short bfrag8;   // 8 bf16 (4 VGPR) MFMA A/B frag
typedef __attribute__((ext_vector_type(4))) float facc4;    // MFMA C/D frag
typedef __attribute__((ext_vector_type(4))) unsigned short us4;
typedef __attribute__((ext_vector_type(8))) unsigned short us8;
typedef __attribute__((ext_vector_type(4))) float f32x4;    // true clang vector (for nontemporal)

#define AS1C const __attribute__((address_space(1))) void
#define AS3  __attribute__((address_space(3))) void

__device__ __forceinline__ void gload_lds16(const void* src, void* dst) {
    __builtin_amdgcn_global_load_lds((AS1C*)src, (AS3*)dst, 16, 0, 0);
}

__device__ __forceinline__ unsigned short f2bf(float f) {   // RNE, finite inputs
    unsigned u = __float_as_uint(f);
    unsigned r = u + 0x7FFFu + ((u >> 16) & 1u);
    return (unsigned short)(r >> 16);
}
__device__ __forceinline__ float bf2f(unsigned short u) {   // exact
    return __uint_as_float((unsigned)u << 16);
}

// ------- merged prep+cvt: weights first (heavy), DENSE vectorized tail -------
__global__ void prep_cvt_kernel(const float* __restrict__ input, const float* __restrict__ targets,
                                const float* __restrict__ sos, const float* __restrict__ W_emb,
                                const float* __restrict__ Wm, const float* __restrict__ Wpi_m,
                                const float* __restrict__ Wmu_m, const float* __restrict__ Wsg_m,
                                const float* __restrict__ Wpi_v, const float* __restrict__ Wmu_v,
                                const float* __restrict__ Wsg_v,
                                const float* __restrict__ bm, const float* __restrict__ bpi_m,
                                const float* __restrict__ bmu_m, const float* __restrict__ bsg_m,
                                const float* __restrict__ bpi_v, const float* __restrict__ bmu_v,
                                const float* __restrict__ bsg_v,
                                const float* __restrict__ Wqkv, const float* __restrict__ Wo,
                                const float* __restrict__ W1, const float* __restrict__ W2,
                                float* __restrict__ pe, bf16* __restrict__ xin,
                                bf16* __restrict__ wemb, bf16* __restrict__ whead,
                                float* __restrict__ bhead,
                                bf16* __restrict__ wqb, bf16* __restrict__ wob,
                                bf16* __restrict__ w1b, bf16* __restrict__ w2b) {
    int bid = blockIdx.x;
    int t = threadIdx.x;
    if (bid < 4608) {                                    // weight cvt (NT loads, 16B stores)
        int l = bid / 768;
        int s = bid - l * 768;
        const float* src; bf16* dst;
        if (s < 384)      { src = Wqkv + (size_t)l * 3145728; dst = wqb + (size_t)l * 3145728; }
        else if (s < 512) { src = Wo + (size_t)l * 1048576; dst = wob + (size_t)l * 1048576; s -= 384; }
        else if (s < 640) { src = W1 + (size_t)l * 1048576; dst = w1b + (size_t)l * 1048576; s -= 512; }
        else              { src = W2 + (size_t)l * 1048576; dst = w2b + (size_t)l * 1048576; s -= 640; }
        size_t pbase = (size_t)s * 1024 + t;
#pragma unroll
        for (int it = 0; it < 4; ++it) {
            size_t o = (pbase + it * 256) * 8;           // 8 floats per pair
            const f32x4* p = (const f32x4*)(src + o);
            f32x4 v1 = __builtin_nontemporal_load(p);
            f32x4 v2 = __builtin_nontemporal_load(p + 1);
            us8 w8;
            w8[0] = f2bf(v1.x); w8[1] = f2bf(v1.y); w8[2] = f2bf(v1.z); w8[3] = f2bf(v1.w);
            w8[4] = f2bf(v2.x); w8[5] = f2bf(v2.y); w8[6] = f2bf(v2.z); w8[7] = f2bf(v2.w);
            *(us8*)(dst + o) = w8;
        }
    } else if (bid < 4736) {                             // pe [128][1024]
        int s = bid - 4608;
        float4 v;
#pragma unroll
        for (int j = 0; j < 4; ++j) {
            int c = t * 4 + j;
            int i = c >> 1;
            float div = expf(-9.210340371976184f * (float)(2 * i) * (1.f / 1024.f));
            float a = (float)s * div;
            v[j] = (c & 1) ? cosf(a) : sinf(a);
        }
        *(float4*)(pe + (size_t)s * 1024 + t * 4) = v;
    } else if (bid < 5888) {                             // xin: 294912 us8-chunks (4096 rows x 72)
        int chunk = (bid - 4736) * 256 + t;
        int row = chunk / 72;
        int cc = chunk - row * 72;
        int b = row >> 7, s = row & 127;
        us8 w8;
        if (cc < 64) {
            const float* p = input + (size_t)b * 512 + cc * 8;
            float4 v1 = *(const float4*)p;
            float4 v2 = *(const float4*)(p + 4);
            w8[0] = f2bf(v1.x); w8[1] = f2bf(v1.y); w8[2] = f2bf(v1.z); w8[3] = f2bf(v1.w);
            w8[4] = f2bf(v2.x); w8[5] = f2bf(v2.y); w8[6] = f2bf(v2.z); w8[7] = f2bf(v2.w);
        } else {
#pragma unroll
            for (int j = 0; j < 8; ++j) {
                int col = cc * 8 + j;
                float v = 0.f;
                if (col < 545) {
                    int jj = col - 512;
                    v = (s == 0) ? sos[jj] : targets[((size_t)b * 127 + (s - 1)) * 33 + jj];
                }
                w8[j] = f2bf(v);
            }
        }
        *(us8*)(xin + (size_t)row * 576 + cc * 8) = w8;
    } else if (bid < 6176) {                             // wemb: pad 545->576
        int chunk = (bid - 5888) * 256 + t;
        int row = chunk / 72;
        int cc = chunk - row * 72;
        us8 w8;
#pragma unroll
        for (int j = 0; j < 8; ++j) {
            int col = cc * 8 + j;
            w8[j] = f2bf(col < 545 ? W_emb[(size_t)row * 545 + col] : 0.f);
        }
        *(us8*)(wemb + (size_t)row * 576 + cc * 8) = w8;
    } else if (bid < 6496) {                             // whead: 640 rows x 128 chunks
        int chunk = (bid - 6176) * 256 + t;
        int r = chunk >> 7;
        int cc = chunk & 127;
        const float* wsrc = nullptr; int off = 0;
        if (r == 0)        { wsrc = Wm;    off = 0; }
        else if (r < 9)    { wsrc = Wpi_m; off = r - 1; }
        else if (r < 137)  { wsrc = Wmu_m; off = r - 9; }
        else if (r < 265)  { wsrc = Wsg_m; off = r - 137; }
        else if (r < 273)  { wsrc = Wpi_v; off = r - 265; }
        else if (r < 401)  { wsrc = Wmu_v; off = r - 273; }
        else if (r < 529)  { wsrc = Wsg_v; off = r - 401; }
        us8 w8;
        if (wsrc) {
            const float* p = wsrc + (size_t)off * 1024 + cc * 8;
            float4 v1 = *(const float4*)p;
            float4 v2 = *(const float4*)(p + 4);
            w8[0] = f2bf(v1.x); w8[1] = f2bf(v1.y); w8[2] = f2bf(v1.z); w8[3] = f2bf(v1.w);
            w8[4] = f2bf(v2.x); w8[5] = f2bf(v2.y); w8[6] = f2bf(v2.z); w8[7] = f2bf(v2.w);
        } else {
#pragma unroll
            for (int j = 0; j < 8; ++j) w8[j] = 0;
        }
        *(us8*)(whead + (size_t)r * 1024 + cc * 8) = w8;
    } else {                                             // bhead: 529 scalars
        if (t < 529) {
            const float* bsrc; int off;
            if (t == 0)       { bsrc = bm;    off = 0; }
            else if (t < 9)   { bsrc = bpi_m; off = t - 1; }
            else if (t < 137) { bsrc = bmu_m; off = t - 9; }
            else if (t < 265) { bsrc = bsg_m; off = t - 137; }
            else if (t < 273) { bsrc = bpi_v; off = t - 265; }
            else if (t < 401) { bsrc = bmu_v; off = t - 273; }
            else              { bsrc = bsg_v; off = t - 401; }
            bhead[t] = bsrc[off];
        }
    }
}

// ---------------- main GEMM: C[M,N] = A[M,K] @ B[N,K]^T (+epilogue) ----------------
// 128x128 tile. Operand-swapped MFMA (C^T frags -> vectorized epilogue).
// XCD-chunked blockIdx swizzle (T1, bijective; applied when nwg%8==0): each XCD gets
// a contiguous tile chunk -> for N=1024 GEMMs the chunk's A+B panels (3.1MB) fit the
// 4MB per-XCD L2, cutting the load latency the 2-phase dbuf can't hide.
// CFG=0: 256t, BK=64, single-buffer, 4 blocks/CU -- big grids (QKV).
// CFG=1: 512t, BK=64, dbuf -- grid-limited, K%128!=0 (embed).
// CFG=2: 512t, BK=128, dbuf, 128KB LDS -- grid-limited, K%128==0.
// EPI: 0 bias->bf16 | 1 bias+relu->bf16 | 3 bias->f32 scalar (odd ldc) | 4 bias+pe->bf16
template<int EPI, int CFG>
__global__ __launch_bounds__(CFG ? 512 : 256, CFG ? 2 : 4) void gemm_bt(
    const bf16* __restrict__ A, const bf16* __restrict__ Bw,
    float* __restrict__ Cf, bf16* __restrict__ Cb,
    const float* __restrict__ bias, const float* __restrict__ pe,
    int M, int N, int K, int lda, int ldb, int ldc, long long Az, long long Cz)
{
    constexpr int NT  = CFG ? 512 : 256;    // threads
    constexpr int NB  = CFG ? 2 : 1;        // LDS buffers
    constexpr int MI  = CFG ? 2 : 4;        // per-wave M fragments
    constexpr int BK  = (CFG == 2) ? 128 : 64;
    constexpr int RB  = BK * 2;             // row bytes in LDS
    constexpr int CPR = BK / 8;             // 16B chunks per row
    constexpr int NCH = (128 * CPR) / NT;   // staging chunks per thread per array
    constexpr int KS  = BK / 32;            // 32-wide k-slices per tile
    __shared__ __align__(16) bf16 sA[NB][128 * BK];
    __shared__ __align__(16) bf16 sB[NB][128 * BK];
    const int t = threadIdx.x;
    const int w = t >> 6, la = t & 63;
    const int wm = CFG ? (w >> 1) * 32 : (w >> 1) * 64;
    const int wn = (w & 1) * 64;
    // XCD-chunked swizzle (identity when nwg not divisible by 8, e.g. heads grid)
    int nwgxy = gridDim.x * gridDim.y;
    int flat = blockIdx.y * gridDim.x + blockIdx.x;
    if ((nwgxy & 7) == 0) {
        int cpx = nwgxy >> 3;
        flat = (flat & 7) * cpx + (flat >> 3);
    }
    const int m0 = (flat / gridDim.x) * 128, n0 = (flat % gridDim.x) * 128;
    const int z = blockIdx.z;
    A += (long long)z * Az;

    facc4 zero4 = {0.f, 0.f, 0.f, 0.f};
    facc4 acc[MI][4];
#pragma unroll
    for (int mi = 0; mi < MI; ++mi)
#pragma unroll
        for (int ni = 0; ni < 4; ++ni) acc[mi][ni] = zero4;

    auto stage = [&](int buf, int kt) {
#pragma unroll
        for (int i = 0; i < NCH; ++i) {
            int c = i * NT + t;
            int r = c / CPR;
            int cc = c - r * CPR;
            int bc = (cc * 16) ^ ((r & 7) << 4);        // pre-swizzled source byte col
            gload_lds16(A + (size_t)(m0 + r) * lda + kt + (bc >> 1),
                        (char*)sA[buf] + (size_t)c * 16);
            gload_lds16(Bw + (size_t)(n0 + r) * ldb + kt + (bc >> 1),
                        (char*)sB[buf] + (size_t)c * 16);
        }
    };
    auto compute = [&](int buf) {
#pragma unroll
        for (int ks = 0; ks < KS; ++ks) {
            bfrag8 af[MI], bfv[4];
            const int koffb = (ks * 32 + (la >> 4) * 8) * 2;
#pragma unroll
            for (int i = 0; i < MI; ++i) {
                int rowa = wm + i * 16 + (la & 15);
                af[i] = *(const bfrag8*)((const char*)sA[buf] + rowa * RB + (koffb ^ ((rowa & 7) << 4)));
            }
#pragma unroll
            for (int i = 0; i < 4; ++i) {
                int rowb = wn + i * 16 + (la & 15);
                bfv[i] = *(const bfrag8*)((const char*)sB[buf] + rowb * RB + (koffb ^ ((rowb & 7) << 4)));
            }
#pragma unroll
            for (int mi = 0; mi < MI; ++mi)
#pragma unroll
                for (int ni = 0; ni < 4; ++ni)     // swapped operands -> C^T fragment
                    acc[mi][ni] = __builtin_amdgcn_mfma_f32_16x16x32_bf16(bfv[ni], af[mi], acc[mi][ni], 0, 0, 0);
        }
    };

    const int nk = K / BK;
    if constexpr (CFG) {
        stage(0, 0);
        __syncthreads();
        int cur = 0;
        for (int kt = 0; kt < nk; ++kt) {
            if (kt + 1 < nk) stage(cur ^ 1, (kt + 1) * BK);
            compute(cur);
            __syncthreads();        // drains stage(k+1) vmcnt; frees cur
            cur ^= 1;
        }
    } else {
        for (int kt = 0; kt < nk; ++kt) {
            stage(0, kt * BK);
            __syncthreads();
            compute(0);
            __syncthreads();
        }
    }
    // epilogue: thread holds C[row][colb..colb+3]
#pragma unroll
    for (int mi = 0; mi < MI; ++mi) {
        int row = m0 + wm + mi * 16 + (la & 15);
#pragma unroll
        for (int ni = 0; ni < 4; ++ni) {
            int colb = n0 + wn + ni * 16 + (la >> 4) * 4;
            if constexpr (EPI == 3) {               // scalar path (odd ldc / edge guards)
                if (row >= M) continue;
#pragma unroll
                for (int j = 0; j < 4; ++j) {
                    int col = colb + j;
                    if (col < N)
                        Cf[(size_t)z * Cz + (size_t)row * ldc + col] = acc[mi][ni][j] + bias[col];
                }
            } else {
                float4 bv = *(const float4*)(bias + colb);
                facc4 v = acc[mi][ni];
                v[0] += bv.x; v[1] += bv.y; v[2] += bv.z; v[3] += bv.w;
                size_t cidx = (size_t)row * ldc + colb;
                if constexpr (EPI == 0) {
                    us4 o; o.x = f2bf(v[0]); o.y = f2bf(v[1]); o.z = f2bf(v[2]); o.w = f2bf(v[3]);
                    *(us4*)(Cb + cidx) = o;
                } else if constexpr (EPI == 1) {
                    us4 o;
                    o.x = f2bf(v[0] > 0.f ? v[0] : 0.f); o.y = f2bf(v[1] > 0.f ? v[1] : 0.f);
                    o.z = f2bf(v[2] > 0.f ? v[2] : 0.f); o.w = f2bf(v[3] > 0.f ? v[3] : 0.f);
                    *(us4*)(Cb + cidx) = o;
                } else {                            // EPI == 4: bias + pe -> bf16
                    float4 p = *(const float4*)(pe + (size_t)(row & 127) * 1024 + colb);
                    us4 o;
                    o.x = f2bf(v[0] + p.x); o.y = f2bf(v[1] + p.y);
                    o.z = f2bf(v[2] + p.z); o.w = f2bf(v[3] + p.w);
                    *(us4*)(Cb + cidx) = o;
                }
            }
        }
    }
}

// ---------------- fused attention: one block per (b,h) ----------------
// S=128, D=64. Q kept in REGISTERS (swapped-operand A-frags are contiguous 16B global
// loads); only K (and later V^T) staged in LDS. In-register one-pass causal softmax.
// setprio(1) around MFMA clusters (T5: +4-7% on attn, m191).
__global__ __launch_bounds__(256) void attn_fused(const bf16* __restrict__ qkv, bf16* __restrict__ obf)
{
    __shared__ __align__(16) char lds[65536];
    char* sK  = lds + 16384;    // [128] rows x 128B, swizzled (dead after QK^T -> red arrays)
    char* sS  = lds + 32768;    // [128] rows x 256B bf16 (P)
    char* sVT = lds;            // [64] rows x 256B (V transposed)
    float* redm = (float*)(lds + 16384);            // [2][128] row max per col-half
    float* reds = (float*)(lds + 16384 + 1024);     // [2][128] row exp-sum per col-half

    const int t = threadIdx.x, w = t >> 6, la = t & 63;
    const int b = blockIdx.x >> 4, h = blockIdx.x & 15;
    const size_t base = (size_t)b * 128 * 3072 + (size_t)h * 64;

    const int wm = (w >> 1) * 64, wn = (w & 1) * 64;

    // phase 1: stage K into LDS; load Q fragments straight to registers
#pragma unroll
    for (int i = 0; i < 4; ++i) {
        int c = i * 256 + w * 64 + la;
        int r = c >> 3;
        int bc = ((c & 7) * 16) ^ ((r & 7) << 4);
        gload_lds16(qkv + base + 1024 + (size_t)r * 3072 + (bc >> 1),
                    sK + (size_t)(i * 256 + w * 64) * 16);
    }
    bfrag8 qf[4][2];
#pragma unroll
    for (int mi = 0; mi < 4; ++mi)
#pragma unroll
        for (int ks = 0; ks < 2; ++ks) {
            int rowa = wm + mi * 16 + (la & 15);
            int k0 = ks * 32 + (la >> 4) * 8;
            qf[mi][ks] = *(const bfrag8*)(qkv + base + (size_t)rowa * 3072 + k0);
        }
    __syncthreads();

    // phase 2: S = Q K^T (swapped mfma -> thread holds S[q][kb..kb+3], fp32)
    facc4 zero4 = {0.f, 0.f, 0.f, 0.f};
    facc4 acc[4][4];
#pragma unroll
    for (int mi = 0; mi < 4; ++mi)
#pragma unroll
        for (int ni = 0; ni < 4; ++ni) acc[mi][ni] = zero4;
    __builtin_amdgcn_s_setprio(1);
#pragma unroll
    for (int ks = 0; ks < 2; ++ks) {
        bfrag8 bfv[4];
        const int koffb = (ks * 32 + (la >> 4) * 8) * 2;
#pragma unroll
        for (int i = 0; i < 4; ++i) {
            int rowb = wn + i * 16 + (la & 15);
            bfv[i] = *(const bfrag8*)(sK + rowb * 128 + (koffb ^ ((rowb & 7) << 4)));
        }
#pragma unroll
        for (int mi = 0; mi < 4; ++mi)
#pragma unroll
            for (int ni = 0; ni < 4; ++ni)
                acc[mi][ni] = __builtin_amdgcn_mfma_f32_16x16x32_bf16(bfv[ni], qf[mi][ks], acc[mi][ni], 0, 0, 0);
    }
    __builtin_amdgcn_s_setprio(0);
    __syncthreads();        // all waves done reading sK

    // phase 3a: stage V transposed into sVT (overlaps softmax VALU below)
#pragma unroll
    for (int i = 0; i < 4; ++i) {
        int c = i * 256 + t;
        int r = c >> 3;             // key index s'
        int d0 = (c & 7) * 8;
        bfrag8 vv = *(const bfrag8*)(qkv + base + 2048 + (size_t)r * 3072 + d0);
#pragma unroll
        for (int j = 0; j < 8; ++j) {
            int d = d0 + j;
            *(short*)(sVT + d * 256 + ((2 * r) ^ ((d & 7) << 4))) = vv[j];
        }
    }

    // phase 3b: in-register causal softmax (one sweep per half)
    const int colh = (w & 1) * 128;
    float tmpm[4], tmps[4];
#pragma unroll
    for (int mi = 0; mi < 4; ++mi) {
        int q = wm + mi * 16 + (la & 15);
        float mx = -1e30f;
#pragma unroll
        for (int ni = 0; ni < 4; ++ni) {
            int kb = wn + ni * 16 + (la >> 4) * 4;
#pragma unroll
            for (int j = 0; j < 4; ++j) {
                float s = acc[mi][ni][j] * 0.125f;
                acc[mi][ni][j] = s;
                if (kb + j <= q) mx = fmaxf(mx, s);
            }
        }
        mx = fmaxf(mx, __shfl_xor(mx, 16));     // reduce over la>>4 (the k-axis lanes)
        mx = fmaxf(mx, __shfl_xor(mx, 32));
        float sm = 0.f;
#pragma unroll
        for (int ni = 0; ni < 4; ++ni) {
            int kb = wn + ni * 16 + (la >> 4) * 4;
#pragma unroll
            for (int j = 0; j < 4; ++j) {
                float e = (kb + j <= q) ? __expf(acc[mi][ni][j] - mx) : 0.f;
                acc[mi][ni][j] = e;
                sm += e;
            }
        }
        sm += __shfl_xor(sm, 16);
        sm += __shfl_xor(sm, 32);
        tmpm[mi] = mx; tmps[mi] = sm;
    }
    if ((la >> 4) == 0) {
#pragma unroll
        for (int mi = 0; mi < 4; ++mi) {
            redm[colh + wm + mi * 16 + la] = tmpm[mi];
            reds[colh + wm + mi * 16 + la] = tmps[mi];
        }
    }
    __syncthreads();
#pragma unroll
    for (int mi = 0; mi < 4; ++mi) {            // combine halves, normalize, pack P -> sS
        int q = wm + mi * 16 + (la & 15);
        float m0 = redm[q], m1 = redm[128 + q];
        float M = fmaxf(m0, m1);
        float tot = reds[q] * __expf(m0 - M) + reds[128 + q] * __expf(m1 - M);
        float sc = __expf(tmpm[mi] - M) / tot;
#pragma unroll
        for (int ni = 0; ni < 4; ++ni) {
            int kb = wn + ni * 16 + (la >> 4) * 4;
            us4 sv;
            sv.x = f2bf(acc[mi][ni][0] * sc); sv.y = f2bf(acc[mi][ni][1] * sc);
            sv.z = f2bf(acc[mi][ni][2] * sc); sv.w = f2bf(acc[mi][ni][3] * sc);
            *(us4*)(sS + q * 256 + ((2 * kb) ^ ((q & 7) << 4))) = sv;
        }
    }
    __syncthreads();                             // sS + sVT complete before PV

    // phase 4: O = P V  (wave tile 64M x 32N, K=128; swapped mfma -> packed O stores)
    const int wm2 = (w >> 1) * 64, wn2 = (w & 1) * 32;
    facc4 a2[4][2];
#pragma unroll
    for (int mi = 0; mi < 4; ++mi) { a2[mi][0] = zero4; a2[mi][1] = zero4; }
    __builtin_amdgcn_s_setprio(1);
#pragma unroll
    for (int ks = 0; ks < 4; ++ks) {
        bfrag8 pa[4], vb[2];
        const int koffb = (ks * 32 + (la >> 4) * 8) * 2;
#pragma unroll
        for (int mi = 0; mi < 4; ++mi) {
            int rowa = wm2 + mi * 16 + (la & 15);
            pa[mi] = *(const bfrag8*)(sS + rowa * 256 + (koffb ^ ((rowa & 7) << 4)));
        }
#pragma unroll
        for (int ni = 0; ni < 2; ++ni) {
            int rowb = wn2 + ni * 16 + (la & 15);
            vb[ni] = *(const bfrag8*)(sVT + rowb * 256 + (koffb ^ ((rowb & 7) << 4)));
        }
#pragma unroll
        for (int mi = 0; mi < 4; ++mi)
#pragma unroll
            for (int ni = 0; ni < 2; ++ni)
                a2[mi][ni] = __builtin_amdgcn_mfma_f32_16x16x32_bf16(vb[ni], pa[mi], a2[mi][ni], 0, 0, 0);
    }
    __builtin_amdgcn_s_setprio(0);
#pragma unroll
    for (int mi = 0; mi < 4; ++mi) {
        int s = wm2 + mi * 16 + (la & 15);
#pragma unroll
        for (int ni = 0; ni < 2; ++ni) {
            int db = wn2 + ni * 16 + (la >> 4) * 4;
            us4 ov;
            ov.x = f2bf(a2[mi][ni][0]); ov.y = f2bf(a2[mi][ni][1]);
            ov.z = f2bf(a2[mi][ni][2]); ov.w = f2bf(a2[mi][ni][3]);
            *(us4*)(obf + ((size_t)(b * 128 + s)) * 1024 + h * 64 + db) = ov;
        }
    }
}

// ------- fused residual + LayerNorm, all-bf16 stream: t = res + go; LN(t) -> xb -------
// 2 rows per block, 16B us8 I/O. In-place res==xb_out safe (element-owned).
__global__ __launch_bounds__(256) void ln_res_kernel(const bf16* __restrict__ go,
                                                     const bf16* __restrict__ res,
                                                     const float* __restrict__ g, const float* __restrict__ be,
                                                     bf16* __restrict__ xb_out)
{
    const int t = threadIdx.x;
    const int row = blockIdx.x * 2 + (t >> 7);   // 2 rows/block, 128 threads (2 waves) each
    const int ct = t & 127;
    size_t o = (size_t)row * 1024 + ct * 8;
    us8 gv8 = *(const us8*)(go + o);
    us8 rv8 = *(const us8*)(res + o);
    float v[8];
    float s = 0.f, q = 0.f;
#pragma unroll
    for (int j = 0; j < 8; ++j) {
        v[j] = bf2f(rv8[j]) + bf2f(gv8[j]);
        s += v[j];
        q += v[j] * v[j];
    }
#pragma unroll
    for (int off = 32; off; off >>= 1) {
        s += __shfl_xor(s, off);
        q += __shfl_xor(q, off);
    }
    __shared__ float ssum[4], sqs[4];
    if ((t & 63) == 0) { ssum[t >> 6] = s; sqs[t >> 6] = q; }
    __syncthreads();
    int rb = (t >> 7) * 2;
    s = ssum[rb] + ssum[rb + 1];
    q = sqs[rb] + sqs[rb + 1];
    float mean = s * (1.f / 1024.f);
    float var = q * (1.f / 1024.f) - mean * mean;
    float rstd = rsqrtf(var + 1e-5f);
    float4 g1v = *(const float4*)(g + ct * 8);
    float4 g2v = *(const float4*)(g + ct * 8 + 4);
    float4 b1v = *(const float4*)(be + ct * 8);
    float4 b2v = *(const float4*)(be + ct * 8 + 4);
    float ga[8] = {g1v.x, g1v.y, g1v.z, g1v.w, g2v.x, g2v.y, g2v.z, g2v.w};
    float ba[8] = {b1v.x, b1v.y, b1v.z, b1v.w, b2v.x, b2v.y, b2v.z, b2v.w};
    us8 ob;
#pragma unroll
    for (int j = 0; j < 8; ++j)
        ob[j] = f2bf((v[j] - mean) * rstd * ga[j] + ba[j]);
    *(us8*)(xb_out + o) = ob;
}

// ---------------- MDN finalize / scatter ----------------
__global__ void finalize_kernel(const float* __restrict__ hout, float* __restrict__ out) {
    const size_t O_PI_M = 0, O_MU_M = 32512, O_VAR_M = 552704, O_PI_V = 1072896,
                 O_MU_V = 1105408, O_VAR_V = 1625600, O_MASK = 2145792;
    int rm = blockIdx.x;                    // b*127+m, 4064 rows
    const float* hrow = hout + (size_t)rm * 529;
    int t = threadIdx.x;
    if (t < 128) {
        out[O_MU_M  + (size_t)rm * 128 + t] = hrow[9 + t];
        out[O_VAR_M + (size_t)rm * 128 + t] = expf(hrow[137 + t]);
        out[O_MU_V  + (size_t)rm * 128 + t] = hrow[273 + t];
        out[O_VAR_V + (size_t)rm * 128 + t] = expf(hrow[401 + t]);
    } else if (t == 128) {
        out[O_MASK + rm] = hrow[0];
    } else if (t == 129 || t == 130) {
        int boff = (t == 129) ? 1 : 265;
        size_t oo = ((t == 129) ? O_PI_M : O_PI_V) + (size_t)rm * 8;
        float v[8], mx = -1e30f;
#pragma unroll
        for (int j = 0; j < 8; ++j) { v[j] = hrow[boff + j]; mx = fmaxf(mx, v[j]); }
        float sm = 0.f;
#pragma unroll
        for (int j = 0; j < 8; ++j) { v[j] = expf(v[j] - mx); sm += v[j]; }
        float inv = 1.f / sm;
#pragma unroll
        for (int j = 0; j < 8; ++j) out[oo + j] = v[j] * inv;
    }
}

// ---------------- launcher ----------------
extern "C" void kernel_launch(void* const* d_in, const int* in_sizes, int n_in,
                              void* d_out, int out_size, void* d_ws, size_t ws_size,
                              hipStream_t stream) {
    (void)in_sizes; (void)n_in; (void)out_size; (void)ws_size;
    const float* input   = (const float*)d_in[0];
    const float* targets = (const float*)d_in[1];
    const float* W_emb   = (const float*)d_in[2];
    const float* b_emb   = (const float*)d_in[3];
    const float* sos     = (const float*)d_in[4];
    const float* Wqkv    = (const float*)d_in[5];
    const float* bqkv    = (const float*)d_in[6];
    const float* Wo      = (const float*)d_in[7];
    const float* bo      = (const float*)d_in[8];
    const float* W1      = (const float*)d_in[9];
    const float* b1      = (const float*)d_in[10];
    const float* W2      = (const float*)d_in[11];
    const float* b2      = (const float*)d_in[12];
    const float* g1      = (const float*)d_in[13];
    const float* be1     = (const float*)d_in[14];
    const float* g2      = (const float*)d_in[15];
    const float* be2     = (const float*)d_in[16];
    const float* Wm      = (const float*)d_in[17];
    const float* bm      = (const float*)d_in[18];
    const float* Wpi_m   = (const float*)d_in[19];
    const float* bpi_m   = (const float*)d_in[20];
    const float* Wmu_m   = (const float*)d_in[21];
    const float* bmu_m   = (const float*)d_in[22];
    const float* Wsg_m   = (const float*)d_in[23];
    const float* bsg_m   = (const float*)d_in[24];
    const float* Wpi_v   = (const float*)d_in[25];
    const float* bpi_v   = (const float*)d_in[26];
    const float* Wmu_v   = (const float*)d_in[27];
    const float* bmu_v   = (const float*)d_in[28];
    const float* Wsg_v   = (const float*)d_in[29];
    const float* bsg_v   = (const float*)d_in[30];
    float* out = (float*)d_out;

    char* ws = (char*)d_ws;                            // ~167 MB total
    float* pe      = (float*)(ws + 0);                 // 0.5 MB
    bf16*  xin     = (bf16*)(ws + 524288);             // 4.72 MB
    bf16*  wemb    = (bf16*)(ws + 5242880);            // 1.18 MB
    bf16*  whead   = (bf16*)(ws + 6422528);            // 1.31 MB (640 rows)
    float* bhead   = (float*)(ws + 7733248);           // 2.5 KB
    bf16*  xb      = (bf16*)(ws + 24513024);           // 8.4 MB (bf16 residual stream + GEMM input)
    bf16*  qkvb    = (bf16*)(ws + 32901632);           // 25.2 MB
    bf16*  ob      = (bf16*)(ws + 58067456);           // 8.4 MB (attn out, reused as FF hidden)
    bf16*  tmpb    = (bf16*)(ws + 66456064);           // 8.4 MB (gemm-out bf16, pre-LN)
    bf16*  wqb_all = (bf16*)(ws + 83233280);           // 37.7 MB (6 layers)
    bf16*  wob_all = (bf16*)(ws + 120982016);          // 12.6 MB
    bf16*  w1b_all = (bf16*)(ws + 133564928);          // 12.6 MB
    bf16*  w2b_all = (bf16*)(ws + 146147840);          // 12.6 MB
    float* hout    = (float*)(ws + 158730752);         // 8.6 MB

    prep_cvt_kernel<<<6497, 256, 0, stream>>>(input, targets, sos, W_emb,
                                              Wm, Wpi_m, Wmu_m, Wsg_m, Wpi_v, Wmu_v, Wsg_v,
                                              bm, bpi_m, bmu_m, bsg_m, bpi_v, bmu_v, bsg_v,
                                              Wqkv, Wo, W1, W2,
                                              pe, xin, wemb, whead, bhead,
                                              wqb_all, wob_all, w1b_all, w2b_all);
    // x = XIN @ Wemb^T + b + pe -> xb (bf16 residual stream); K=576 -> BK64 CFG=1
    gemm_bt<4, 1><<<dim3(8, 32, 1), 512, 0, stream>>>(xin, wemb, nullptr, xb, b_emb, pe,
                                                      4096, 1024, 576, 576, 576, 1024, 0, 0);
    for (int l = 0; l < 6; ++l) {
        const bf16* wqb = wqb_all + (size_t)l * 3145728;
        const bf16* wob = wob_all + (size_t)l * 1048576;
        const bf16* w1b = w1b_all + (size_t)l * 1048576;
        const bf16* w2b = w2b_all + (size_t)l * 1048576;
        // qkv = x @ Wqkv^T + b  (bf16 out) -- 768 blocks, single-buffer, 4 blocks/CU
        gemm_bt<0, 0><<<dim3(24, 32, 1), 256, 0, stream>>>(xb, wqb, nullptr, qkvb, bqkv + l * 3072,
                                                           nullptr, 4096, 3072, 1024, 1024, 1024, 3072, 0, 0);
        attn_fused<<<512, 256, 0, stream>>>(qkvb, ob);
        // go = o @ Wo^T + bo (bf16); residual folded into ln_res -- BK128 dbuf
        gemm_bt<0, 2><<<dim3(8, 32, 1), 512, 0, stream>>>(ob, wob, nullptr, tmpb, bo + l * 1024,
                                                          nullptr, 4096, 1024, 1024, 1024, 1024, 1024, 0, 0);
        ln_res_kernel<<<2048, 256, 0, stream>>>(tmpb, xb, g1 + l * 1024, be1 + l * 1024, xb);
        // t1 = relu(x @ W1^T + b1) (bf16, reuse ob)
        gemm_bt<1, 2><<<dim3(8, 32, 1), 512, 0, stream>>>(xb, w1b, nullptr, ob, b1 + l * 1024,
                                                          nullptr, 4096, 1024, 1024, 1024, 1024, 1024, 0, 0);
        // go = t1 @ W2^T + b2 (bf16); residual folded into ln_res
        gemm_bt<0, 2><<<dim3(8, 32, 1), 512, 0, stream>>>(ob, w2b, nullptr, tmpb, b2 + l * 1024,
                                                          nullptr, 4096, 1024, 1024, 1024, 1024, 1024, 0, 0);
        ln_res_kernel<<<2048, 256, 0, stream>>>(tmpb, xb, g2 + l * 1024, be2 + l * 1024, xb);
    }
    // heads: per-batch M=127 rows of x -> hout (B,127,529) -- grid 5/z, swizzle auto-skipped
    gemm_bt<3, 2><<<dim3(5, 1, 32), 512, 0, stream>>>(xb, whead, hout, nullptr, bhead, nullptr,
                                                      127, 529, 1024, 1024, 1024, 529, 131072LL, 67183LL);
    finalize_kernel<<<4064, 256, 0, stream>>>(hout, out);
}